// Round 3
// baseline (11002.575 us; speedup 1.0000x reference)
//
#include <hip/hip_runtime.h>
#include <math.h>

// ---------------- generator functors ----------------
struct AgF32 { const float* A; int lda;
  __device__ float operator()(int r, int k) const { return A[(size_t)r*lda + k]; } };
struct AgXrow { const float* x;  // row=bt*500+n, k=c : x[bt,c,n]
  __device__ float operator()(int r, int k) const {
    int bt = r/500, n = r - bt*500;
    return x[(size_t)bt*32000 + (size_t)k*500 + n]; } };
struct AgFlex0 { const float* Xn; const float* XG1; const float* XG2; const float* ne;
  // r global (bt*500+n), kp = d*192 + k*64 + c; all three sources [n][bt*64+c] ld 12288
  __device__ float operator()(int r, int kp) const {
    int d = kp / 192; int kc = kp - d*192; int k = kc >> 6; int c = kc & 63;
    int bt = r/500, n = r - bt*500;
    const float* s = (k==0)? Xn : (k==1)? XG1 : XG2;
    float v = s[(size_t)n*12288 + bt*64 + c];
    return ne[(size_t)r*8 + d] * v; } };
struct AgFlex1 { const float* s0; const float* XG1; const float* XG2; const float* ne;
  // r local in chunk (btl*500+n), kp = d*384 + k*128 + c
  // s0 row-major [r][128]; XG [n][btl*128+c] ld 6144; ne [r][8]
  __device__ float operator()(int r, int kp) const {
    int d = kp / 384; int kc = kp - d*384; int k = kc >> 7; int c = kc & 127;
    int btl = r/500, n = r - btl*500;
    float v = (k==0) ? s0[(size_t)r*128 + c]
                     : ((k==1)?XG1:XG2)[(size_t)n*6144 + btl*128 + c];
    return ne[(size_t)r*8 + d] * v; } };
struct AgConv { const float* hs; // local rows bnl*24+t, k = dt*128+c, pad over t
  __device__ float operator()(int r, int k) const {
    int t = r % 24; int dt = k >> 7; int c = k & 127; int t2 = t + dt - 1;
    if (t2 < 0 || t2 >= 24) return 0.f;
    return hs[(size_t)(r + (t2 - t))*128 + c]; } };
struct AgTeAdd { const float* o2f; const float* te;
  __device__ float operator()(int r, int k) const {
    return o2f[(size_t)r*128 + k] + te[(size_t)(r/500)*128 + k]; } };

struct BgF32 { const float* Bp; int ldb;
  __device__ float operator()(int k, int c) const { return Bp[(size_t)k*ldb + c]; } };
struct BgT { const float* W; int ld;   // weight [O,I] -> B[k][o]=W[o][k]
  __device__ float operator()(int k, int c) const { return W[(size_t)c*ld + k]; } };
struct BgConvW { const float* w;       // w[o,c,0,dt], k = dt*128+c
  __device__ float operator()(int k, int c) const {
    int dt = k >> 7; int cc = k & 127;
    return w[((size_t)c*128 + cc)*3 + dt]; } };
struct BgOut0 { const float* out0; int btbase;  // B[k=m][c]=out0[((btbase+c/128)*500+m)*128 + c%128]
  __device__ float operator()(int k, int c) const {
    int btl = c >> 7; int o = c & 127;
    return out0[((size_t)(btbase + btl)*500 + k)*128 + o]; } };

struct EpNone { __device__ float operator()(int, int, float a) const { return a; } };
struct EpS2   { __device__ float operator()(int r, int c, float a) const { return 2.f*a - (r==c ? 1.f : 0.f); } };
struct EpBias { const float* b;
  __device__ float operator()(int, int c, float a) const { return a + b[c]; } };
struct EpNeBias { const float* ne; const float* bp;  // + sum_d ne[r,d]*bp[d,o]
  __device__ float operator()(int r, int c, float a) const {
    float s = a;
    #pragma unroll
    for (int d=0; d<8; ++d) s += ne[(size_t)r*8 + d]*bp[d*128 + c];
    return s; } };
struct EpRes1 { const float* out1; const float* st; const float *g, *bb, *rb; float invM;
  __device__ float operator()(int r, int c, float a) const {
    float mean = st[c]*invM; float var = st[128+c]*invM - mean*mean;
    float rstd = rsqrtf(var + 1e-5f);
    float y = (out1[(size_t)r*128 + c] - mean)*rstd*g[c] + bb[c];
    y = fmaxf(y, 0.f);
    return a + rb[c] + y; } };
struct EpRes2 { const float *r2b, *rw, *rcb;
  __device__ float operator()(int, int c, float a) const {
    float s = 0.f;
    #pragma unroll
    for (int t=0; t<24; ++t) s += rw[t];
    return a + s*r2b[c] + rcb[0]; } };

// ---------------- generic generator GEMM ----------------
template<int BM, int BN, int BK, int TM, int TN, class AG, class BG, class EP>
__global__ __launch_bounds__((BM/TM)*(BN/TN))
void gemm_gen(AG ag, BG bg, EP ep, float* C, int M, int N, int K, int ldc) {
  constexpr int NT = (BM/TM)*(BN/TN);
  __shared__ float As[BK][BM+4];
  __shared__ float Bs[BK][BN+4];
  int tid = threadIdx.x;
  int tx = tid % (BN/TN), ty = tid / (BN/TN);
  int row0 = blockIdx.y*BM, col0 = blockIdx.x*BN;
  float acc[TM][TN];
  #pragma unroll
  for (int i=0;i<TM;++i)
    #pragma unroll
    for (int j=0;j<TN;++j) acc[i][j] = 0.f;
  for (int k0 = 0; k0 < K; k0 += BK) {
    for (int i = tid; i < BM*BK; i += NT) {
      int m = i / BK, kk = i - m*BK;
      float v = 0.f; int gr = row0+m, gk = k0+kk;
      if (gr < M && gk < K) v = ag(gr, gk);
      As[kk][m] = v;
    }
    for (int i = tid; i < BK*BN; i += NT) {
      int kk = i / BN, n = i - kk*BN;
      float v = 0.f; int gc = col0+n, gk = k0+kk;
      if (gc < N && gk < K) v = bg(gk, gc);
      Bs[kk][n] = v;
    }
    __syncthreads();
    #pragma unroll
    for (int kk=0; kk<BK; ++kk) {
      float a[TM], b[TN];
      #pragma unroll
      for (int i=0;i<TM;++i) a[i] = As[kk][ty*TM+i];
      #pragma unroll
      for (int j=0;j<TN;++j) b[j] = Bs[kk][tx*TN+j];
      #pragma unroll
      for (int i=0;i<TM;++i)
        #pragma unroll
        for (int j=0;j<TN;++j) acc[i][j] += a[i]*b[j];
    }
    __syncthreads();
  }
  #pragma unroll
  for (int i=0;i<TM;++i) {
    int r = row0 + ty*TM + i;
    if (r >= M) continue;
    #pragma unroll
    for (int j=0;j<TN;++j) {
      int c = col0 + tx*TN + j;
      if (c < N) C[(size_t)r*ldc + c] = ep(r, c, acc[i][j]);
    }
  }
}

// ---------------- small kernels ----------------
__global__ void k_transpose(const float* src, float* dst, int R, int Cc) {
  __shared__ float tile[32][33];
  int c0 = blockIdx.x*32, r0 = blockIdx.y*32;
  int tx = threadIdx.x, ty = threadIdx.y;
  for (int i = ty; i < 32; i += 8) {
    int r = r0+i, c = c0+tx;
    if (r < R && c < Cc) tile[i][tx] = src[(size_t)r*Cc + c];
  }
  __syncthreads();
  for (int i = ty; i < 32; i += 8) {
    int dr = c0 + i, dc = r0 + tx;
    if (dr < Cc && dc < R) dst[(size_t)dr*R + dc] = tile[tx][i];
  }
}

__global__ void k_pool0(const float* x, float* pooled) {  // mean over nodes of x[bt,c,n]
  int bt = blockIdx.x; int c = threadIdx.x; // 64
  const float* p = x + (size_t)bt*32000 + (size_t)c*500;
  float s = 0.f;
  for (int n=0;n<500;++n) s += p[n];
  pooled[bt*64 + c] = s*(1.f/500.f);
}
__global__ void k_pool1(const float* src, float* pooled) { // mean over n of src[(bt*500+n)*128+o]
  int bt = blockIdx.x; int o = threadIdx.x; // 128
  float s = 0.f;
  for (int n=0;n<500;++n) s += src[((size_t)bt*500 + n)*128 + o];
  pooled[bt*128 + o] = s*(1.f/500.f);
}

__global__ void k_mlp(const float* pooled, int F, const float* f1w, const float* f1b,
                      const float* f2w, const float* f2b, float* aout) {
  int bt = threadIdx.x;
  if (bt >= 192) return;
  float h[8];
  for (int k=0;k<8;++k){
    float s = f1b[k];
    for (int c=0;c<F;++c) s += pooled[bt*F + c]*f1w[k*F + c];
    h[k] = fmaxf(s, 0.f);
  }
  float z[8]; float m = -1e30f;
  for (int k2=0;k2<8;++k2){
    float s = f2b[k2];
    for (int k=0;k<8;++k) s += h[k]*f2w[k2*8 + k];
    z[k2] = s; m = fmaxf(m, s);
  }
  float den = 0.f;
  for (int k2=0;k2<8;++k2){ z[k2] = expf(z[k2]-m); den += z[k2]; }
  float inv = 1.f/den;
  for (int k2=0;k2<8;++k2) aout[bt*8 + k2] = z[k2]*inv;
}

__global__ void k_ne(const float* a, const float* emb, float* ne) {
  int i = blockIdx.x*256 + threadIdx.x;
  if (i >= 768000) return;
  int d = i & 7; int rem = i >> 3; int n = rem % 500; int bt = rem / 500;
  float s = 0.f;
  #pragma unroll
  for (int k=0;k<8;++k) s += a[bt*8 + k]*emb[((size_t)k*500 + n)*8 + d];
  ne[i] = s;
}

__global__ void k_bn_stats(const float* src, float* stats, int M) {
  int col = threadIdx.x & 127; int seg = threadIdx.x >> 7;
  int r0 = blockIdx.x * 500; int r1 = r0 + 500; if (r1 > M) r1 = M;
  float s = 0.f, q = 0.f;
  for (int r = r0 + seg; r < r1; r += 2) {
    float v = src[(size_t)r*128 + col];
    s += v; q += v*v;
  }
  atomicAdd(&stats[col], s);
  atomicAdd(&stats[128+col], q);
}

__global__ void k_bn_apply(float* dst, const float* src, const float* st,
                           const float* g, const float* b, int total, float invM, int relu, int addd) {
  int i = blockIdx.x*256 + threadIdx.x;
  if (i >= total) return;
  int c = i & 127;
  float mean = st[c]*invM; float var = st[128+c]*invM - mean*mean;
  float rstd = rsqrtf(var + 1e-5f);
  float y = (src[i]-mean)*rstd*g[c] + b[c];
  if (relu) y = fmaxf(y, 0.f);
  dst[i] = addd ? dst[i] + y : y;
}

// per-batch GRU: 63 blocks x 8 nodes; gi local rows t*500+n, hsb local [n][t][128]
__global__ __launch_bounds__(384) void k_gru(const float* gi, const float* whh, const float* bhh, float* hsb) {
  __shared__ float h[8][132];
  __shared__ float uh[8][384];
  int tid = threadIdx.x;
  int n0 = blockIdx.x*8;
  for (int i=tid;i<1024;i+=384) h[i>>7][i&127] = 0.f;
  __syncthreads();
  for (int t=0;t<24;++t) {
    int j = tid;
    float acc[8];
    float bj = bhh[j];
    #pragma unroll
    for (int r=0;r<8;++r) acc[r] = bj;
    const float* wrow = whh + (size_t)j*128;
    for (int c=0;c<128;c+=4) {
      float w0 = wrow[c], w1 = wrow[c+1], w2 = wrow[c+2], w3 = wrow[c+3];
      #pragma unroll
      for (int r=0;r<8;++r) {
        float4 hv = *(const float4*)&h[r][c];
        acc[r] += hv.x*w0 + hv.y*w1 + hv.z*w2 + hv.w*w3;
      }
    }
    #pragma unroll
    for (int r=0;r<8;++r) uh[r][j] = acc[r];
    __syncthreads();
    for (int i=tid;i<1024;i+=384) {
      int r = i>>7, u = i&127;
      int n = n0 + r;
      int nc = (n < 500) ? n : 499;
      size_t grow = ((size_t)t*500 + nc)*384;
      float ir = gi[grow + u], iz = gi[grow + 128 + u], inn = gi[grow + 256 + u];
      float rg = 1.f/(1.f + expf(-(ir + uh[r][u])));
      float zg = 1.f/(1.f + expf(-(iz + uh[r][128+u])));
      float ng = tanhf(inn + rg*uh[r][256+u]);
      float hnew = (1.f - zg)*ng + zg*h[r][u];
      h[r][u] = hnew;
      if (n < 500) hsb[((size_t)n*24 + t)*128 + u] = hnew;
    }
    __syncthreads();
  }
}

__global__ __launch_bounds__(256) void k_attn(const float* Q, const float* K, const float* V,
    const float* ow, const float* ob, const float* fcw, const float* fcb, float* out2f_b) {
  __shared__ float Qs[24][128];
  __shared__ float Ks[24][128];
  __shared__ float Vs[24][128];
  __shared__ float Sc[8][24][24];
  __shared__ float xbar[128];
  int bn = blockIdx.x; int tid = threadIdx.x;
  size_t base = (size_t)bn*3072;
  float* Qf = &Qs[0][0]; float* Kf = &Ks[0][0]; float* Vf = &Vs[0][0];
  for (int i=tid;i<3072;i+=256){ Qf[i]=Q[base+i]; Kf[i]=K[base+i]; Vf[i]=V[base+i]; }
  __syncthreads();
  for (int i=tid;i<4608;i+=256){
    int hh = i/576; int r = i - hh*576; int t = r/24; int s_ = r - t*24;
    float d = 0.f;
    #pragma unroll
    for (int dd=0;dd<16;++dd) d += Qs[t][hh*16+dd]*Ks[s_][hh*16+dd];
    Sc[hh][t][s_] = d*0.25f;
  }
  __syncthreads();
  if (tid < 192) {
    int hh = tid/24, t = tid - (tid/24)*24;
    float m = -1e30f;
    for (int s_=0;s_<24;++s_) m = fmaxf(m, Sc[hh][t][s_]);
    float den = 0.f;
    for (int s_=0;s_<24;++s_){ float e = expf(Sc[hh][t][s_]-m); Sc[hh][t][s_] = e; den += e; }
    float inv = 1.f/den;
    for (int s_=0;s_<24;++s_) Sc[hh][t][s_] *= inv;
  }
  __syncthreads();
  for (int i=tid;i<3072;i+=256){
    int t = i >> 7; int o = i & 127; int hh = o >> 4;
    float s = 0.f;
    #pragma unroll
    for (int s_=0;s_<24;++s_) s += Sc[hh][t][s_]*Vs[s_][o];
    Qs[t][o] = s;  // xa overwrites Qs (Q no longer needed)
  }
  __syncthreads();
  if (tid < 128) {
    float s = 0.f;
    for (int t=0;t<24;++t) s += fcw[t]*Qs[t][tid];
    xbar[tid] = s;
  }
  __syncthreads();
  if (tid < 128) {
    int o = tid;
    float s = 0.f;
    for (int c=0;c<128;++c) s += xbar[c]*ow[o*128 + c];
    float sfc = 0.f;
    for (int t=0;t<24;++t) sfc += fcw[t];
    out2f_b[(size_t)bn*128 + o] = s + sfc*ob[o] + fcb[0];
  }
}

__global__ void k_rbar(const float* out2, const float* rw, float* rbar) {
  int i = blockIdx.x*256 + threadIdx.x;
  if (i >= 512000) return;
  int c = i & 127; int bn = i >> 7; int b = bn/500, n = bn - b*500;
  float s = 0.f;
  #pragma unroll
  for (int t=0;t<24;++t) s += rw[t] * out2[((size_t)(b*24 + t)*500 + n)*128 + c];
  rbar[i] = s;
}

__global__ void k_te(const float* tt, const float* w1, const float* b1,
                     const float* w2, const float* b2, float* te) {
  __shared__ float h1[128];
  int b = blockIdx.x; int o = threadIdx.x;
  float s = b1[o];
  for (int c=0;c<32;++c) s += tt[b*32 + c]*w1[o*32 + c];
  h1[o] = fmaxf(s, 0.f);
  __syncthreads();
  float s2 = b2[o];
  for (int c=0;c<128;++c) s2 += h1[c]*w2[o*128 + c];
  te[b*128 + o] = s2;
}

__global__ void k_grid(const float* gnm, const float* fin, float* out) {
  int e = threadIdx.x & 63; int gq = threadIdx.x >> 6;
  int g = blockIdx.x*4 + gq; int b = blockIdx.y;
  float s = 0.f;
  const float* gr = gnm + (size_t)g*500;
  const float* fb = fin + (size_t)b*500*64 + e;
  for (int n=0;n<500;++n) s += gr[n] * fb[(size_t)n*64];
  out[(size_t)b*32000 + (size_t)e*500 + g] = s;
}

// ---------------- launch ----------------
extern "C" void kernel_launch(void* const* d_in, const int* in_sizes, int n_in,
                              void* d_out, int out_size, void* d_ws, size_t ws_size,
                              hipStream_t stream) {
  const float* adj   = (const float*)d_in[0];
  const float* x     = (const float*)d_in[1];
  const float* gnm   = (const float*)d_in[2];
  const float* ttime = (const float*)d_in[3];
  const float* emb   = (const float*)d_in[4];
  const float* wp0   = (const float*)d_in[5];
  const float* bp0   = (const float*)d_in[6];
  const float* a0f1w = (const float*)d_in[7];
  const float* a0f1b = (const float*)d_in[8];
  const float* a0f2w = (const float*)d_in[9];
  const float* a0f2b = (const float*)d_in[10];
  const float* wp1   = (const float*)d_in[11];
  const float* bp1   = (const float*)d_in[12];
  const float* a1f1w = (const float*)d_in[13];
  const float* a1f1b = (const float*)d_in[14];
  const float* a1f2w = (const float*)d_in[15];
  const float* a1f2b = (const float*)d_in[16];
  const float* bn0g  = (const float*)d_in[17];
  const float* bn0b  = (const float*)d_in[18];
  const float* bn1g  = (const float*)d_in[19];
  const float* bn1b  = (const float*)d_in[20];
  const float* wih   = (const float*)d_in[21];
  const float* whh   = (const float*)d_in[22];
  const float* bih   = (const float*)d_in[23];
  const float* bhh   = (const float*)d_in[24];
  const float* bgg   = (const float*)d_in[25];
  const float* bgb   = (const float*)d_in[26];
  const float* cqw   = (const float*)d_in[27];
  const float* cqb   = (const float*)d_in[28];
  const float* ckw   = (const float*)d_in[29];
  const float* ckb   = (const float*)d_in[30];
  const float* vw    = (const float*)d_in[31];
  const float* vb    = (const float*)d_in[32];
  const float* ow    = (const float*)d_in[33];
  const float* ob    = (const float*)d_in[34];
  const float* r1w   = (const float*)d_in[35];
  const float* r1b   = (const float*)d_in[36];
  const float* fcw   = (const float*)d_in[37];
  const float* fcb   = (const float*)d_in[38];
  const float* rcw   = (const float*)d_in[39];
  const float* rcb   = (const float*)d_in[40];
  const float* r2w   = (const float*)d_in[41];
  const float* r2b   = (const float*)d_in[42];
  const float* bnrg  = (const float*)d_in[43];
  const float* bnrb  = (const float*)d_in[44];
  const float* te1w  = (const float*)d_in[45];
  const float* te1b  = (const float*)d_in[46];
  const float* te2w  = (const float*)d_in[47];
  const float* te2b  = (const float*)d_in[48];
  const float* finw  = (const float*)d_in[49];
  const float* finb  = (const float*)d_in[50];
  float* dout = (float*)d_out;
  float* W = (float*)d_ws;

  // ---- workspace layout (floats): three reused regions + smalls (~137 MB) ----
  size_t off = 0;
  auto alloc = [&](size_t n){ size_t r = off; off += (n + 255) & ~(size_t)255; return r; };
  size_t oStats = alloc(256);
  size_t oPool  = alloc(24576);
  size_t oAmix  = alloc(1536);
  size_t oTe    = alloc(1024);
  size_t oO2f   = alloc(512000);
  size_t oRbar  = alloc(512000);
  size_t oRes   = alloc(512000);
  size_t oFin   = alloc(256000);
  size_t oNe0   = alloc(768000);
  size_t oNe1   = alloc(768000);
  size_t oS2    = alloc(250000);
  size_t oR1    = alloc(12288000);  // out0 -> out2
  size_t oR2    = alloc(12288000);  // XG0 pair -> out1 -> hs
  size_t oR4    = alloc(6144000);   // Xn -> XG chunk -> gi chunk -> QKV chunk
  (void)n_in; (void)in_sizes; (void)out_size;
  if (ws_size < off * sizeof(float)) return;  // fail cleanly (absmax) instead of faulting

  float* stats = W + oStats;
  float* pooled= W + oPool;
  float* amix  = W + oAmix;
  float* teb   = W + oTe;
  float* out2f = W + oO2f;
  float* rbar  = W + oRbar;
  float* resout= W + oRes;
  float* fin   = W + oFin;
  float* ne0   = W + oNe0;
  float* ne1   = W + oNe1;
  float* S2    = W + oS2;
  float* out0  = W + oR1;              // [96000][128]
  float* out2  = W + oR1;              // overwrites out0 after it is dead
  float* XG1n  = W + oR2;              // [500][12288]
  float* XG2n  = W + oR2 + 6144000;    // [500][12288]
  float* out1  = W + oR2;              // [96000][128]
  float* hs    = W + oR2;              // [4000][24][128]
  float* Xn    = W + oR4;              // [500][12288]
  float* XG1c  = W + oR4;              // [500][6144]
  float* XG2c  = W + oR4 + 3072000;    // [500][6144]
  float* giC   = W + oR4;              // [12000][384]
  float* Qc    = W + oR4;              // [12000][128]
  float* Kc    = W + oR4 + 1536000;
  float* Vc    = W + oR4 + 3072000;

  // ---- Phase A: supports + flexgcn layer 0 ----
  k_transpose<<<dim3(16,384), dim3(32,8), 0, stream>>>(x, Xn, 12288, 500);
  gemm_gen<64,64,16,4,4><<<dim3(8,8), 256, 0, stream>>>(
      AgF32{adj,500}, BgF32{adj,500}, EpS2{}, S2, 500, 500, 500, 500);
  gemm_gen<64,128,16,4,8><<<dim3(96,8), 256, 0, stream>>>(
      AgF32{adj,500}, BgF32{Xn,12288}, EpNone{}, XG1n, 500, 12288, 500, 12288);
  gemm_gen<64,128,16,4,8><<<dim3(96,8), 256, 0, stream>>>(
      AgF32{S2,500}, BgF32{Xn,12288}, EpNone{}, XG2n, 500, 12288, 500, 12288);
  k_pool0<<<192, 64, 0, stream>>>(x, pooled);
  k_mlp<<<1, 192, 0, stream>>>(pooled, 64, a0f1w, a0f1b, a0f2w, a0f2b, amix);
  k_ne<<<3000, 256, 0, stream>>>(amix, emb, ne0);
  gemm_gen<64,128,16,4,8><<<dim3(1,1500), 256, 0, stream>>>(
      AgFlex0{Xn, XG1n, XG2n, ne0}, BgF32{wp0,128}, EpNeBias{ne0, bp0},
      out0, 96000, 128, 1536, 128);
  hipMemsetAsync((void*)stats, 0, 256*sizeof(float), stream);
  k_bn_stats<<<192, 256, 0, stream>>>(out0, stats, 96000);
  k_bn_apply<<<48000, 256, 0, stream>>>(out0, out0, stats, bn0g, bn0b, 12288000, 1.f/96000.f, 1, 0);

  // ---- Phase B: flexgcn layer 1 (chunked over 4 groups of 48 bt) + residual ----
  k_pool1<<<192, 128, 0, stream>>>(out0, pooled);
  k_mlp<<<1, 192, 0, stream>>>(pooled, 128, a1f1w, a1f1b, a1f2w, a1f2b, amix);
  k_ne<<<3000, 256, 0, stream>>>(amix, emb, ne1);
  for (int c4 = 0; c4 < 4; ++c4) {
    int btbase = c4 * 48;
    gemm_gen<64,128,16,4,8><<<dim3(48,8), 256, 0, stream>>>(
        AgF32{adj,500}, BgOut0{out0, btbase}, EpNone{}, XG1c, 500, 6144, 500, 6144);
    gemm_gen<64,128,16,4,8><<<dim3(48,8), 256, 0, stream>>>(
        AgF32{S2,500}, BgOut0{out0, btbase}, EpNone{}, XG2c, 500, 6144, 500, 6144);
    gemm_gen<64,128,16,4,8><<<dim3(1,375), 256, 0, stream>>>(
        AgFlex1{out0 + (size_t)btbase*64000, XG1c, XG2c, ne1 + (size_t)btbase*4000},
        BgF32{wp1,128}, EpNeBias{ne1 + (size_t)btbase*4000, bp1},
        out1 + (size_t)btbase*64000, 24000, 128, 3072, 128);
  }
  hipMemsetAsync((void*)stats, 0, 256*sizeof(float), stream);
  k_bn_stats<<<192, 256, 0, stream>>>(out1, stats, 96000);
  // out2 = x_row @ res1_w.T + res1_b + relu(bn1(out1))   (out2 overwrites out0 region)
  gemm_gen<64,128,16,4,8><<<dim3(1,1500), 256, 0, stream>>>(
      AgXrow{x}, BgT{r1w,64}, EpRes1{out1, stats, bn1g, bn1b, r1b, 1.f/96000.f},
      out2, 96000, 128, 64, 128);

  // ---- Phase C: GRU (per batch) ----
  for (int b = 0; b < 8; ++b) {
    gemm_gen<64,128,16,4,8><<<dim3(3,188), 256, 0, stream>>>(
        AgF32{out2 + (size_t)b*1536000, 128}, BgT{wih,128}, EpBias{bih},
        giC, 12000, 384, 128, 384);
    k_gru<<<63, 384, 0, stream>>>(giC, whh, bhh, hs + (size_t)b*1536000);
  }
  hipMemsetAsync((void*)stats, 0, 256*sizeof(float), stream);
  k_bn_stats<<<192, 256, 0, stream>>>(hs, stats, 96000);
  k_bn_apply<<<48000, 256, 0, stream>>>(hs, hs, stats, bgg, bgb, 12288000, 1.f/96000.f, 1, 0);

  // ---- Phase D: temporal attention (per batch) ----
  for (int b = 0; b < 8; ++b) {
    const float* hsb = hs + (size_t)b*1536000;
    gemm_gen<64,128,16,4,8><<<dim3(1,188), 256, 0, stream>>>(
        AgConv{hsb}, BgConvW{cqw}, EpBias{cqb}, Qc, 12000, 128, 384, 128);
    gemm_gen<64,128,16,4,8><<<dim3(1,188), 256, 0, stream>>>(
        AgConv{hsb}, BgConvW{ckw}, EpBias{ckb}, Kc, 12000, 128, 384, 128);
    gemm_gen<64,128,16,4,8><<<dim3(1,188), 256, 0, stream>>>(
        AgF32{hsb,128}, BgT{vw,128}, EpBias{vb}, Vc, 12000, 128, 128, 128);
    k_attn<<<500, 256, 0, stream>>>(Qc, Kc, Vc, ow, ob, fcw, fcb, out2f + (size_t)b*64000);
  }

  // ---- Phase E: residual-2 + BN + heads ----
  k_rbar<<<2000, 256, 0, stream>>>(out2, rcw, rbar);
  gemm_gen<64,128,16,4,8><<<dim3(1,63), 256, 0, stream>>>(
      AgF32{rbar,128}, BgT{r2w,128}, EpRes2{r2b, rcw, rcb}, resout, 4000, 128, 128, 128);
  hipMemsetAsync((void*)stats, 0, 256*sizeof(float), stream);
  k_bn_stats<<<8, 256, 0, stream>>>(resout, stats, 4000);
  k_bn_apply<<<2000, 256, 0, stream>>>(out2f, resout, stats, bnrg, bnrb, 512000, 1.f/4000.f, 0, 1);
  k_te<<<8, 128, 0, stream>>>(ttime, te1w, te1b, te2w, te2b, teb);
  gemm_gen<64,64,16,4,4><<<dim3(1,63), 256, 0, stream>>>(
      AgTeAdd{out2f, teb}, BgT{finw,128}, EpBias{finb}, fin, 4000, 64, 128, 64);
  k_grid<<<dim3(125,8), 256, 0, stream>>>(gnm, fin, dout);
}

// Round 4
// 7263.087 us; speedup vs baseline: 1.5149x; 1.5149x over previous
//
#include <hip/hip_runtime.h>
#include <math.h>

using short8 = __attribute__((ext_vector_type(8))) short;
using f32x4  = __attribute__((ext_vector_type(4))) float;

__device__ __forceinline__ unsigned short f2b(float f){
  unsigned int u = __builtin_bit_cast(unsigned int, f);
  u = (u + 0x7fffu + ((u >> 16) & 1u)) >> 16;
  return (unsigned short)u;
}

// ---------------- generator functors ----------------
struct AgF32 { const float* A; int lda;
  __device__ float operator()(int r, int k) const { return A[(size_t)r*lda + k]; } };
struct AgXrow { const float* x;  // row=bt*500+n, k=c : x[bt,c,n]
  __device__ float operator()(int r, int k) const {
    int bt = r/500, n = r - bt*500;
    return x[(size_t)bt*32000 + (size_t)k*500 + n]; } };
struct AgFlex0 { const float* Xn; const float* XG1; const float* XG2; const float* ne;
  // r global (bt*500+n), kp = d*192 + k*64 + c; all three sources [n][bt*64+c] ld 12288
  __device__ float operator()(int r, int kp) const {
    int d = kp / 192; int kc = kp - d*192; int k = kc >> 6; int c = kc & 63;
    int bt = r/500, n = r - bt*500;
    const float* s = (k==0)? Xn : (k==1)? XG1 : XG2;
    float v = s[(size_t)n*12288 + bt*64 + c];
    return ne[(size_t)r*8 + d] * v; } };
struct AgFlex1 { const float* s0; const float* XG1; const float* XG2; const float* ne;
  // r local in chunk (btl*500+n), kp = d*384 + k*128 + c
  __device__ float operator()(int r, int kp) const {
    int d = kp / 384; int kc = kp - d*384; int k = kc >> 7; int c = kc & 127;
    int btl = r/500, n = r - btl*500;
    float v = (k==0) ? s0[(size_t)r*128 + c]
                     : ((k==1)?XG1:XG2)[(size_t)n*6144 + btl*128 + c];
    return ne[(size_t)r*8 + d] * v; } };
struct AgConv { const float* hs; // local rows bnl*24+t, k = dt*128+c, pad over t
  __device__ float operator()(int r, int k) const {
    int t = r % 24; int dt = k >> 7; int c = k & 127; int t2 = t + dt - 1;
    if (t2 < 0 || t2 >= 24) return 0.f;
    return hs[(size_t)(r + (t2 - t))*128 + c]; } };
struct AgTeAdd { const float* o2f; const float* te;
  __device__ float operator()(int r, int k) const {
    return o2f[(size_t)r*128 + k] + te[(size_t)(r/500)*128 + k]; } };

struct BgF32 { const float* Bp; int ldb;
  __device__ float operator()(int k, int c) const { return Bp[(size_t)k*ldb + c]; } };
struct BgT { const float* W; int ld;   // weight [O,I] -> B[k][o]=W[o][k]
  __device__ float operator()(int k, int c) const { return W[(size_t)c*ld + k]; } };
struct BgConvW { const float* w;       // w[o,c,0,dt], k = dt*128+c
  __device__ float operator()(int k, int c) const {
    int dt = k >> 7; int cc = k & 127;
    return w[((size_t)c*128 + cc)*3 + dt]; } };
struct BgOut0 { const float* out0; int btbase;  // B[k=m][c]=out0[((btbase+c/128)*500+m)*128 + c%128]
  __device__ float operator()(int k, int c) const {
    int btl = c >> 7; int o = c & 127;
    return out0[((size_t)(btbase + btl)*500 + k)*128 + o]; } };

struct EpNone { __device__ float operator()(int, int, float a) const { return a; } };
struct Ep2AmX { const float* X; int ld;   // 2*acc - X[r][c]  (Chebyshev: S2@Y = 2*adj@(adj@Y) - Y)
  __device__ float operator()(int r, int c, float a) const { return 2.f*a - X[(size_t)r*ld + c]; } };
struct Ep2AmOut0 { const float* out0; int btbase;
  __device__ float operator()(int r, int c, float a) const {
    int btl = c >> 7; int o = c & 127;
    return 2.f*a - out0[((size_t)(btbase + btl)*500 + r)*128 + o]; } };
struct EpBias { const float* b;
  __device__ float operator()(int, int c, float a) const { return a + b[c]; } };
struct EpNeBias { const float* ne; const float* bp;  // + sum_d ne[r,d]*bp[d,o]
  __device__ float operator()(int r, int c, float a) const {
    float s = a;
    #pragma unroll
    for (int d=0; d<8; ++d) s += ne[(size_t)r*8 + d]*bp[d*128 + c];
    return s; } };
struct EpRes1 { const float* out1; const float* st; const float *g, *bb, *rb; float invM;
  __device__ float operator()(int r, int c, float a) const {
    float mean = st[c]*invM; float var = st[128+c]*invM - mean*mean;
    float rstd = rsqrtf(var + 1e-5f);
    float y = (out1[(size_t)r*128 + c] - mean)*rstd*g[c] + bb[c];
    y = fmaxf(y, 0.f);
    return a + rb[c] + y; } };
struct EpRes2 { const float *r2b, *rw, *rcb;
  __device__ float operator()(int, int c, float a) const {
    float s = 0.f;
    #pragma unroll
    for (int t=0; t<24; ++t) s += rw[t];
    return a + s*r2b[c] + rcb[0]; } };

// ---------------- MFMA generator GEMM ----------------
// 128x128 tile, BK=32, 4 waves in 2x2; wave does 4x4 mfma_f32_16x16x32_bf16 tiles.
// A/B frag: [idx=lane&15][k=(lane>>4)*8 + j]; C/D: col=lane&15, row=(lane>>4)*4+reg.
template<class AG, class BG, class EP>
__global__ __launch_bounds__(256)
void gemm_mfma(AG ag, BG bg, EP ep, float* C, int M, int N, int K, int ldc) {
  constexpr int BM=128, BN=128, BK=32;
  constexpr int LDA = BK + 8;   // shorts; 80B row stride: 16B aligned, 2-way banks on b128 reads
  __shared__ unsigned short As[BM*LDA];
  __shared__ unsigned short Bs[BN*LDA];
  int tid = threadIdx.x;
  int lane = tid & 63, wave = tid >> 6;
  int wr = (wave >> 1) * 64, wc = (wave & 1) * 64;
  int q = lane >> 4, r16 = lane & 15;
  int row0 = blockIdx.y*BM, col0 = blockIdx.x*BN;
  f32x4 acc[4][4] = {};
  for (int k0 = 0; k0 < K; k0 += BK) {
    // stage A (k-contiguous per thread: generator reads are c-fast/coalesced-ish)
    #pragma unroll
    for (int s = 0; s < 4; ++s) {
      int i = tid + s*256;
      int m = i >> 3, kk = (i & 7)*4;
      int gr = row0 + m, gk = k0 + kk;
      float v0=0.f,v1=0.f,v2=0.f,v3=0.f;
      if (gr < M) {
        if (gk   < K) v0 = ag(gr, gk);
        if (gk+1 < K) v1 = ag(gr, gk+1);
        if (gk+2 < K) v2 = ag(gr, gk+2);
        if (gk+3 < K) v3 = ag(gr, gk+3);
      }
      uint2 p; p.x = (unsigned)f2b(v0) | ((unsigned)f2b(v1)<<16);
      p.y = (unsigned)f2b(v2) | ((unsigned)f2b(v3)<<16);
      *(uint2*)&As[m*LDA + kk] = p;
    }
    // stage B (n-contiguous across lanes: coalesced global reads of big B panels)
    #pragma unroll
    for (int s = 0; s < 4; ++s) {
      int i = tid + s*256;
      int n = i & 127, kk = (i >> 7)*4;
      int gc = col0 + n, gk = k0 + kk;
      float v0=0.f,v1=0.f,v2=0.f,v3=0.f;
      if (gc < N) {
        if (gk   < K) v0 = bg(gk,   gc);
        if (gk+1 < K) v1 = bg(gk+1, gc);
        if (gk+2 < K) v2 = bg(gk+2, gc);
        if (gk+3 < K) v3 = bg(gk+3, gc);
      }
      uint2 p; p.x = (unsigned)f2b(v0) | ((unsigned)f2b(v1)<<16);
      p.y = (unsigned)f2b(v2) | ((unsigned)f2b(v3)<<16);
      *(uint2*)&Bs[n*LDA + kk] = p;
    }
    __syncthreads();
    short8 a[4], b[4];
    #pragma unroll
    for (int it=0;it<4;++it) a[it] = *(const short8*)&As[(wr + it*16 + r16)*LDA + q*8];
    #pragma unroll
    for (int jt=0;jt<4;++jt) b[jt] = *(const short8*)&Bs[(wc + jt*16 + r16)*LDA + q*8];
    #pragma unroll
    for (int it=0;it<4;++it)
      #pragma unroll
      for (int jt=0;jt<4;++jt)
        acc[it][jt] = __builtin_amdgcn_mfma_f32_16x16x32_bf16(a[it], b[jt], acc[it][jt], 0, 0, 0);
    __syncthreads();
  }
  #pragma unroll
  for (int it=0;it<4;++it) {
    int rb = row0 + wr + it*16 + q*4;
    #pragma unroll
    for (int jt=0;jt<4;++jt) {
      int c = col0 + wc + jt*16 + r16;
      if (c >= N) continue;
      #pragma unroll
      for (int v=0;v<4;++v) {
        int rr = rb + v;
        if (rr < M) C[(size_t)rr*ldc + c] = ep(rr, c, acc[it][jt][v]);
      }
    }
  }
}

// ---------------- small kernels ----------------
__global__ void k_transpose(const float* src, float* dst, int R, int Cc) {
  __shared__ float tile[32][33];
  int c0 = blockIdx.x*32, r0 = blockIdx.y*32;
  int tx = threadIdx.x, ty = threadIdx.y;
  for (int i = ty; i < 32; i += 8) {
    int r = r0+i, c = c0+tx;
    if (r < R && c < Cc) tile[i][tx] = src[(size_t)r*Cc + c];
  }
  __syncthreads();
  for (int i = ty; i < 32; i += 8) {
    int dr = c0 + i, dc = r0 + tx;
    if (dr < Cc && dc < R) dst[(size_t)dr*R + dc] = tile[tx][i];
  }
}

__global__ void k_pool0(const float* x, float* pooled) {  // mean over nodes of x[bt,c,n]
  int bt = blockIdx.x; int c = threadIdx.x; // 64
  const float* p = x + (size_t)bt*32000 + (size_t)c*500;
  float s = 0.f;
  for (int n=0;n<500;++n) s += p[n];
  pooled[bt*64 + c] = s*(1.f/500.f);
}
__global__ void k_pool1(const float* src, float* pooled) { // mean over n of src[(bt*500+n)*128+o]
  int bt = blockIdx.x; int o = threadIdx.x; // 128
  float s = 0.f;
  for (int n=0;n<500;++n) s += src[((size_t)bt*500 + n)*128 + o];
  pooled[bt*128 + o] = s*(1.f/500.f);
}

__global__ void k_mlp(const float* pooled, int F, const float* f1w, const float* f1b,
                      const float* f2w, const float* f2b, float* aout) {
  int bt = threadIdx.x;
  if (bt >= 192) return;
  float h[8];
  for (int k=0;k<8;++k){
    float s = f1b[k];
    for (int c=0;c<F;++c) s += pooled[bt*F + c]*f1w[k*F + c];
    h[k] = fmaxf(s, 0.f);
  }
  float z[8]; float m = -1e30f;
  for (int k2=0;k2<8;++k2){
    float s = f2b[k2];
    for (int k=0;k<8;++k) s += h[k]*f2w[k2*8 + k];
    z[k2] = s; m = fmaxf(m, s);
  }
  float den = 0.f;
  for (int k2=0;k2<8;++k2){ z[k2] = expf(z[k2]-m); den += z[k2]; }
  float inv = 1.f/den;
  for (int k2=0;k2<8;++k2) aout[bt*8 + k2] = z[k2]*inv;
}

__global__ void k_ne(const float* a, const float* emb, float* ne) {
  int i = blockIdx.x*256 + threadIdx.x;
  if (i >= 768000) return;
  int d = i & 7; int rem = i >> 3; int n = rem % 500; int bt = rem / 500;
  float s = 0.f;
  #pragma unroll
  for (int k=0;k<8;++k) s += a[bt*8 + k]*emb[((size_t)k*500 + n)*8 + d];
  ne[i] = s;
}

__global__ void k_bn_stats(const float* src, float* stats, int M) {
  int col = threadIdx.x & 127; int seg = threadIdx.x >> 7;
  int r0 = blockIdx.x * 500; int r1 = r0 + 500; if (r1 > M) r1 = M;
  float s = 0.f, q = 0.f;
  for (int r = r0 + seg; r < r1; r += 2) {
    float v = src[(size_t)r*128 + col];
    s += v; q += v*v;
  }
  atomicAdd(&stats[col], s);
  atomicAdd(&stats[128+col], q);
}

__global__ void k_bn_apply(float* dst, const float* src, const float* st,
                           const float* g, const float* b, int total, float invM, int relu, int addd) {
  int i = blockIdx.x*256 + threadIdx.x;
  if (i >= total) return;
  int c = i & 127;
  float mean = st[c]*invM; float var = st[128+c]*invM - mean*mean;
  float rstd = rsqrtf(var + 1e-5f);
  float y = (src[i]-mean)*rstd*g[c] + b[c];
  if (relu) y = fmaxf(y, 0.f);
  dst[i] = addd ? dst[i] + y : y;
}

// per-batch GRU: 63 blocks x 8 nodes; gi local rows t*500+n, hsb local [n][t][128]
__global__ __launch_bounds__(384) void k_gru(const float* gi, const float* whh, const float* bhh, float* hsb) {
  __shared__ float h[8][132];
  __shared__ float uh[8][384];
  int tid = threadIdx.x;
  int n0 = blockIdx.x*8;
  for (int i=tid;i<1024;i+=384) h[i>>7][i&127] = 0.f;
  __syncthreads();
  for (int t=0;t<24;++t) {
    int j = tid;
    float acc[8];
    float bj = bhh[j];
    #pragma unroll
    for (int r=0;r<8;++r) acc[r] = bj;
    const float* wrow = whh + (size_t)j*128;
    for (int c=0;c<128;c+=4) {
      float w0 = wrow[c], w1 = wrow[c+1], w2 = wrow[c+2], w3 = wrow[c+3];
      #pragma unroll
      for (int r=0;r<8;++r) {
        float4 hv = *(const float4*)&h[r][c];
        acc[r] += hv.x*w0 + hv.y*w1 + hv.z*w2 + hv.w*w3;
      }
    }
    #pragma unroll
    for (int r=0;r<8;++r) uh[r][j] = acc[r];
    __syncthreads();
    for (int i=tid;i<1024;i+=384) {
      int r = i>>7, u = i&127;
      int n = n0 + r;
      int nc = (n < 500) ? n : 499;
      size_t grow = ((size_t)t*500 + nc)*384;
      float ir = gi[grow + u], iz = gi[grow + 128 + u], inn = gi[grow + 256 + u];
      float rg = 1.f/(1.f + expf(-(ir + uh[r][u])));
      float zg = 1.f/(1.f + expf(-(iz + uh[r][128+u])));
      float ng = tanhf(inn + rg*uh[r][256+u]);
      float hnew = (1.f - zg)*ng + zg*h[r][u];
      h[r][u] = hnew;
      if (n < 500) hsb[((size_t)n*24 + t)*128 + u] = hnew;
    }
    __syncthreads();
  }
}

__global__ __launch_bounds__(256) void k_attn(const float* Q, const float* K, const float* V,
    const float* ow, const float* ob, const float* fcw, const float* fcb, float* out2f_b) {
  __shared__ float Qs[24][128];
  __shared__ float Ks[24][128];
  __shared__ float Vs[24][128];
  __shared__ float Sc[8][24][24];
  __shared__ float xbar[128];
  int bn = blockIdx.x; int tid = threadIdx.x;
  size_t base = (size_t)bn*3072;
  float* Qf = &Qs[0][0]; float* Kf = &Ks[0][0]; float* Vf = &Vs[0][0];
  for (int i=tid;i<3072;i+=256){ Qf[i]=Q[base+i]; Kf[i]=K[base+i]; Vf[i]=V[base+i]; }
  __syncthreads();
  for (int i=tid;i<4608;i+=256){
    int hh = i/576; int r = i - hh*576; int t = r/24; int s_ = r - t*24;
    float d = 0.f;
    #pragma unroll
    for (int dd=0;dd<16;++dd) d += Qs[t][hh*16+dd]*Ks[s_][hh*16+dd];
    Sc[hh][t][s_] = d*0.25f;
  }
  __syncthreads();
  if (tid < 192) {
    int hh = tid/24, t = tid - (tid/24)*24;
    float m = -1e30f;
    for (int s_=0;s_<24;++s_) m = fmaxf(m, Sc[hh][t][s_]);
    float den = 0.f;
    for (int s_=0;s_<24;++s_){ float e = expf(Sc[hh][t][s_]-m); Sc[hh][t][s_] = e; den += e; }
    float inv = 1.f/den;
    for (int s_=0;s_<24;++s_) Sc[hh][t][s_] *= inv;
  }
  __syncthreads();
  for (int i=tid;i<3072;i+=256){
    int t = i >> 7; int o = i & 127; int hh = o >> 4;
    float s = 0.f;
    #pragma unroll
    for (int s_=0;s_<24;++s_) s += Sc[hh][t][s_]*Vs[s_][o];
    Qs[t][o] = s;  // xa overwrites Qs (Q no longer needed)
  }
  __syncthreads();
  if (tid < 128) {
    float s = 0.f;
    for (int t=0;t<24;++t) s += fcw[t]*Qs[t][tid];
    xbar[tid] = s;
  }
  __syncthreads();
  if (tid < 128) {
    int o = tid;
    float s = 0.f;
    for (int c=0;c<128;++c) s += xbar[c]*ow[o*128 + c];
    float sfc = 0.f;
    for (int t=0;t<24;++t) sfc += fcw[t];
    out2f_b[(size_t)bn*128 + o] = s + sfc*ob[o] + fcb[0];
  }
}

__global__ void k_rbar(const float* out2, const float* rw, float* rbar) {
  int i = blockIdx.x*256 + threadIdx.x;
  if (i >= 512000) return;
  int c = i & 127; int bn = i >> 7; int b = bn/500, n = bn - b*500;
  float s = 0.f;
  #pragma unroll
  for (int t=0;t<24;++t) s += rw[t] * out2[((size_t)(b*24 + t)*500 + n)*128 + c];
  rbar[i] = s;
}

__global__ void k_te(const float* tt, const float* w1, const float* b1,
                     const float* w2, const float* b2, float* te) {
  __shared__ float h1[128];
  int b = blockIdx.x; int o = threadIdx.x;
  float s = b1[o];
  for (int c=0;c<32;++c) s += tt[b*32 + c]*w1[o*32 + c];
  h1[o] = fmaxf(s, 0.f);
  __syncthreads();
  float s2 = b2[o];
  for (int c=0;c<128;++c) s2 += h1[c]*w2[o*128 + c];
  te[b*128 + o] = s2;
}

__global__ void k_grid(const float* gnm, const float* fin, float* out) {
  int e = threadIdx.x & 63; int gq = threadIdx.x >> 6;
  int g = blockIdx.x*4 + gq; int b = blockIdx.y;
  float s = 0.f;
  const float* gr = gnm + (size_t)g*500;
  const float* fb = fin + (size_t)b*500*64 + e;
  for (int n=0;n<500;++n) s += gr[n] * fb[(size_t)n*64];
  out[(size_t)b*32000 + (size_t)e*500 + g] = s;
}

// ---------------- launch ----------------
extern "C" void kernel_launch(void* const* d_in, const int* in_sizes, int n_in,
                              void* d_out, int out_size, void* d_ws, size_t ws_size,
                              hipStream_t stream) {
  const float* adj   = (const float*)d_in[0];
  const float* x     = (const float*)d_in[1];
  const float* gnm   = (const float*)d_in[2];
  const float* ttime = (const float*)d_in[3];
  const float* emb   = (const float*)d_in[4];
  const float* wp0   = (const float*)d_in[5];
  const float* bp0   = (const float*)d_in[6];
  const float* a0f1w = (const float*)d_in[7];
  const float* a0f1b = (const float*)d_in[8];
  const float* a0f2w = (const float*)d_in[9];
  const float* a0f2b = (const float*)d_in[10];
  const float* wp1   = (const float*)d_in[11];
  const float* bp1   = (const float*)d_in[12];
  const float* a1f1w = (const float*)d_in[13];
  const float* a1f1b = (const float*)d_in[14];
  const float* a1f2w = (const float*)d_in[15];
  const float* a1f2b = (const float*)d_in[16];
  const float* bn0g  = (const float*)d_in[17];
  const float* bn0b  = (const float*)d_in[18];
  const float* bn1g  = (const float*)d_in[19];
  const float* bn1b  = (const float*)d_in[20];
  const float* wih   = (const float*)d_in[21];
  const float* whh   = (const float*)d_in[22];
  const float* bih   = (const float*)d_in[23];
  const float* bhh   = (const float*)d_in[24];
  const float* bgg   = (const float*)d_in[25];
  const float* bgb   = (const float*)d_in[26];
  const float* cqw   = (const float*)d_in[27];
  const float* cqb   = (const float*)d_in[28];
  const float* ckw   = (const float*)d_in[29];
  const float* ckb   = (const float*)d_in[30];
  const float* vw    = (const float*)d_in[31];
  const float* vb    = (const float*)d_in[32];
  const float* ow    = (const float*)d_in[33];
  const float* ob    = (const float*)d_in[34];
  const float* r1w   = (const float*)d_in[35];
  const float* r1b   = (const float*)d_in[36];
  const float* fcw   = (const float*)d_in[37];
  const float* fcb   = (const float*)d_in[38];
  const float* rcw   = (const float*)d_in[39];
  const float* rcb   = (const float*)d_in[40];
  const float* r2w   = (const float*)d_in[41];
  const float* r2b   = (const float*)d_in[42];
  const float* bnrg  = (const float*)d_in[43];
  const float* bnrb  = (const float*)d_in[44];
  const float* te1w  = (const float*)d_in[45];
  const float* te1b  = (const float*)d_in[46];
  const float* te2w  = (const float*)d_in[47];
  const float* te2b  = (const float*)d_in[48];
  const float* finw  = (const float*)d_in[49];
  const float* finb  = (const float*)d_in[50];
  float* dout = (float*)d_out;
  float* W = (float*)d_ws;

  // ---- workspace layout (floats): three reused regions + smalls ----
  size_t off = 0;
  auto alloc = [&](size_t n){ size_t r = off; off += (n + 255) & ~(size_t)255; return r; };
  size_t oStats = alloc(256);
  size_t oPool  = alloc(24576);
  size_t oAmix  = alloc(1536);
  size_t oTe    = alloc(1024);
  size_t oO2f   = alloc(512000);
  size_t oRbar  = alloc(512000);
  size_t oRes   = alloc(512000);
  size_t oFin   = alloc(256000);
  size_t oNe0   = alloc(768000);
  size_t oNe1   = alloc(768000);
  size_t oR1    = alloc(12288000);  // out0 -> out2
  size_t oR2    = alloc(12288000);  // XG pair -> out1 -> hs
  size_t oR4    = alloc(6144000);   // Xn -> XG chunk -> gi chunk -> QKV chunk
  (void)n_in; (void)in_sizes; (void)out_size;
  if (ws_size < off * sizeof(float)) return;  // fail cleanly (absmax) instead of faulting

  float* stats = W + oStats;
  float* pooled= W + oPool;
  float* amix  = W + oAmix;
  float* teb   = W + oTe;
  float* out2f = W + oO2f;
  float* rbar  = W + oRbar;
  float* resout= W + oRes;
  float* fin   = W + oFin;
  float* ne0   = W + oNe0;
  float* ne1   = W + oNe1;
  float* out0  = W + oR1;              // [96000][128]
  float* out2  = W + oR1;              // overwrites out0 after it is dead
  float* XG1n  = W + oR2;              // [500][12288]
  float* XG2n  = W + oR2 + 6144000;    // [500][12288]
  float* out1  = W + oR2;              // [96000][128]
  float* hs    = W + oR2;              // [4000][24][128]
  float* Xn    = W + oR4;              // [500][12288]
  float* XG1c  = W + oR4;              // [500][6144]
  float* XG2c  = W + oR4 + 3072000;    // [500][6144]
  float* giC   = W + oR4;              // [12000][384]
  float* Qc    = W + oR4;              // [12000][128]
  float* Kc    = W + oR4 + 1536000;
  float* Vc    = W + oR4 + 3072000;

  // ---- Phase A: supports + flexgcn layer 0 ----
  k_transpose<<<dim3(16,384), dim3(32,8), 0, stream>>>(x, Xn, 12288, 500);
  // XG1 = adj @ Xn ; XG2 = 2*adj@XG1 - Xn  (Chebyshev recurrence, no S2 materialization)
  gemm_mfma<<<dim3(96,4), 256, 0, stream>>>(
      AgF32{adj,500}, BgF32{Xn,12288}, EpNone{}, XG1n, 500, 12288, 500, 12288);
  gemm_mfma<<<dim3(96,4), 256, 0, stream>>>(
      AgF32{adj,500}, BgF32{XG1n,12288}, Ep2AmX{Xn,12288}, XG2n, 500, 12288, 500, 12288);
  k_pool0<<<192, 64, 0, stream>>>(x, pooled);
  k_mlp<<<1, 192, 0, stream>>>(pooled, 64, a0f1w, a0f1b, a0f2w, a0f2b, amix);
  k_ne<<<3000, 256, 0, stream>>>(amix, emb, ne0);
  gemm_mfma<<<dim3(1,750), 256, 0, stream>>>(
      AgFlex0{Xn, XG1n, XG2n, ne0}, BgF32{wp0,128}, EpNeBias{ne0, bp0},
      out0, 96000, 128, 1536, 128);
  hipMemsetAsync((void*)stats, 0, 256*sizeof(float), stream);
  k_bn_stats<<<192, 256, 0, stream>>>(out0, stats, 96000);
  k_bn_apply<<<48000, 256, 0, stream>>>(out0, out0, stats, bn0g, bn0b, 12288000, 1.f/96000.f, 1, 0);

  // ---- Phase B: flexgcn layer 1 (chunked over 4 groups of 48 bt) + residual ----
  k_pool1<<<192, 128, 0, stream>>>(out0, pooled);
  k_mlp<<<1, 192, 0, stream>>>(pooled, 128, a1f1w, a1f1b, a1f2w, a1f2b, amix);
  k_ne<<<3000, 256, 0, stream>>>(amix, emb, ne1);
  for (int c4 = 0; c4 < 4; ++c4) {
    int btbase = c4 * 48;
    gemm_mfma<<<dim3(48,4), 256, 0, stream>>>(
        AgF32{adj,500}, BgOut0{out0, btbase}, EpNone{}, XG1c, 500, 6144, 500, 6144);
    gemm_mfma<<<dim3(48,4), 256, 0, stream>>>(
        AgF32{adj,500}, BgF32{XG1c,6144}, Ep2AmOut0{out0, btbase}, XG2c, 500, 6144, 500, 6144);
    gemm_mfma<<<dim3(1,188), 256, 0, stream>>>(
        AgFlex1{out0 + (size_t)btbase*64000, XG1c, XG2c, ne1 + (size_t)btbase*4000},
        BgF32{wp1,128}, EpNeBias{ne1 + (size_t)btbase*4000, bp1},
        out1 + (size_t)btbase*64000, 24000, 128, 3072, 128);
  }
  hipMemsetAsync((void*)stats, 0, 256*sizeof(float), stream);
  k_bn_stats<<<192, 256, 0, stream>>>(out1, stats, 96000);
  // out2 = x_row @ res1_w.T + res1_b + relu(bn1(out1))   (out2 overwrites out0 region)
  gemm_mfma<<<dim3(1,750), 256, 0, stream>>>(
      AgXrow{x}, BgT{r1w,64}, EpRes1{out1, stats, bn1g, bn1b, r1b, 1.f/96000.f},
      out2, 96000, 128, 64, 128);

  // ---- Phase C: GRU (per batch) ----
  for (int b = 0; b < 8; ++b) {
    gemm_mfma<<<dim3(3,94), 256, 0, stream>>>(
        AgF32{out2 + (size_t)b*1536000, 128}, BgT{wih,128}, EpBias{bih},
        giC, 12000, 384, 128, 384);
    k_gru<<<63, 384, 0, stream>>>(giC, whh, bhh, hs + (size_t)b*1536000);
  }
  hipMemsetAsync((void*)stats, 0, 256*sizeof(float), stream);
  k_bn_stats<<<192, 256, 0, stream>>>(hs, stats, 96000);
  k_bn_apply<<<48000, 256, 0, stream>>>(hs, hs, stats, bgg, bgb, 12288000, 1.f/96000.f, 1, 0);

  // ---- Phase D: temporal attention (per batch) ----
  for (int b = 0; b < 8; ++b) {
    const float* hsb = hs + (size_t)b*1536000;
    gemm_mfma<<<dim3(1,94), 256, 0, stream>>>(
        AgConv{hsb}, BgConvW{cqw}, EpBias{cqb}, Qc, 12000, 128, 384, 128);
    gemm_mfma<<<dim3(1,94), 256, 0, stream>>>(
        AgConv{hsb}, BgConvW{ckw}, EpBias{ckb}, Kc, 12000, 128, 384, 128);
    gemm_mfma<<<dim3(1,94), 256, 0, stream>>>(
        AgF32{hsb,128}, BgT{vw,128}, EpBias{vb}, Vc, 12000, 128, 128, 128);
    k_attn<<<500, 256, 0, stream>>>(Qc, Kc, Vc, ow, ob, fcw, fcb, out2f + (size_t)b*64000);
  }

  // ---- Phase E: residual-2 + BN + heads ----
  k_rbar<<<2000, 256, 0, stream>>>(out2, rcw, rbar);
  gemm_mfma<<<dim3(1,32), 256, 0, stream>>>(
      AgF32{rbar,128}, BgT{r2w,128}, EpRes2{r2b, rcw, rcb}, resout, 4000, 128, 128, 128);
  hipMemsetAsync((void*)stats, 0, 256*sizeof(float), stream);
  k_bn_stats<<<8, 256, 0, stream>>>(resout, stats, 4000);
  k_bn_apply<<<2000, 256, 0, stream>>>(out2f, resout, stats, bnrg, bnrb, 512000, 1.f/4000.f, 0, 1);
  k_te<<<8, 128, 0, stream>>>(ttime, te1w, te1b, te2w, te2b, teb);
  gemm_mfma<<<dim3(1,32), 256, 0, stream>>>(
      AgTeAdd{out2f, teb}, BgT{finw,128}, EpBias{finb}, fin, 4000, 64, 128, 64);
  k_grid<<<dim3(125,8), 256, 0, stream>>>(gnm, fin, dout);
}

// Round 5
// 5623.442 us; speedup vs baseline: 1.9566x; 1.2916x over previous
//
#include <hip/hip_runtime.h>
#include <math.h>

using short8 = __attribute__((ext_vector_type(8))) short;
using f32x4  = __attribute__((ext_vector_type(4))) float;
using ushort_t = unsigned short;

__device__ __forceinline__ ushort_t f2b(float f){
  unsigned int u = __builtin_bit_cast(unsigned int, f);
  u = (u + 0x7fffu + ((u >> 16) & 1u)) >> 16;
  return (ushort_t)u;
}
__device__ __forceinline__ float b2f(ushort_t u){
  unsigned int v = ((unsigned int)u) << 16;
  return __builtin_bit_cast(float, v);
}

// ---------------- generator functors ----------------
struct AgF32 { const float* A; int lda;
  __device__ float operator()(int r, int k) const { return A[(size_t)r*lda + k]; } };
struct AgBf16p { const ushort_t* A; int lda;
  __device__ float operator()(int r, int k) const { return b2f(A[(size_t)r*lda + k]); } };
struct AgXrow { const float* x;  // row=bt*500+n, k=c : x[bt,c,n]
  __device__ float operator()(int r, int k) const {
    int bt = r/500, n = r - bt*500;
    return x[(size_t)bt*32000 + (size_t)k*500 + n]; } };
struct AgFlex0 { const ushort_t* Xn; const ushort_t* XG1; const ushort_t* XG2; const float* ne;
  // r global (bt*500+n), kp = d*192 + k*64 + c; sources [n][bt*64+c] ld 12288 (bf16)
  __device__ float operator()(int r, int kp) const {
    int d = kp / 192; int kc = kp - d*192; int k = kc >> 6; int c = kc & 63;
    int bt = r/500, n = r - bt*500;
    const ushort_t* s = (k==0)? Xn : (k==1)? XG1 : XG2;
    float v = b2f(s[(size_t)n*12288 + bt*64 + c]);
    return ne[(size_t)r*8 + d] * v; } };
struct AgFlex1 { const float* s0; const ushort_t* XG1; const ushort_t* XG2; const float* ne;
  // r global (bt*500+n), kp = d*384 + k*128 + c; s0 f32 [r][128]; XG bf16 [n][bt*128+c] ld 24576
  __device__ float operator()(int r, int kp) const {
    int d = kp / 384; int kc = kp - d*384; int k = kc >> 7; int c = kc & 127;
    int bt = r/500, n = r - bt*500;
    float v = (k==0) ? s0[(size_t)r*128 + c]
                     : b2f(((k==1)?XG1:XG2)[(size_t)n*24576 + bt*128 + c]);
    return ne[(size_t)r*8 + d] * v; } };
struct AgTeAdd { const float* o2f; const float* te;
  __device__ float operator()(int r, int k) const {
    return o2f[(size_t)r*128 + k] + te[(size_t)(r/500)*128 + k]; } };

struct BgF32 { const float* Bp; int ldb;
  __device__ float operator()(int k, int c) const { return Bp[(size_t)k*ldb + c]; } };
struct BgBf16p { const ushort_t* Bp; int ldb;
  __device__ float operator()(int k, int c) const { return b2f(Bp[(size_t)k*ldb + c]); } };
struct BgT { const float* W; int ld;   // weight [O,I] -> B[k][o]=W[o][k]
  __device__ float operator()(int k, int c) const { return W[(size_t)c*ld + k]; } };

struct EpNone { __device__ float operator()(int, int, float a) const { return a; } };
struct EpS2   { __device__ float operator()(int r, int c, float a) const { return 2.f*a - (r==c ? 1.f : 0.f); } };
struct EpBias { const float* b;
  __device__ float operator()(int, int c, float a) const { return a + b[c]; } };
struct EpNeBias { const float* ne; const float* bp;  // + sum_d ne[r,d]*bp[d,o]
  __device__ float operator()(int r, int c, float a) const {
    float s = a;
    #pragma unroll
    for (int d=0; d<8; ++d) s += ne[(size_t)r*8 + d]*bp[d*128 + c];
    return s; } };
struct EpRes1 { const ushort_t* out1; const float* st; const float *g, *bb, *rb; float invM;
  __device__ float operator()(int r, int c, float a) const {
    float mean = st[c]*invM; float var = st[128+c]*invM - mean*mean;
    float rstd = rsqrtf(var + 1e-5f);
    float y = (b2f(out1[(size_t)r*128 + c]) - mean)*rstd*g[c] + bb[c];
    y = fmaxf(y, 0.f);
    return a + rb[c] + y; } };
struct EpRes2 { const float *r2b, *rw, *rcb;
  __device__ float operator()(int, int c, float a) const {
    float s = 0.f;
    #pragma unroll
    for (int t=0; t<24; ++t) s += rw[t];
    return a + s*r2b[c] + rcb[0]; } };

// ---------------- pipelined MFMA generator GEMM ----------------
// 128x128 tile, BK=32, 4 waves 2x2; register-prefetch of next K-tile overlaps MFMA.
template<bool BOUT, class AG, class BG, class EP>
__global__ __launch_bounds__(256)
void gemm_mfma(AG ag, BG bg, EP ep, void* Cv, int M, int N, int K, int ldc) {
  constexpr int BM=128, BN=128, BK=32;
  constexpr int LDA = BK + 8;   // shorts; 80B row stride
  __shared__ ushort_t As[BM*LDA];
  __shared__ ushort_t Bs[BN*LDA];
  int tid = threadIdx.x;
  int lane = tid & 63, wave = tid >> 6;
  int wr = (wave >> 1) * 64, wc = (wave & 1) * 64;
  int q = lane >> 4, r16 = lane & 15;
  int row0 = blockIdx.y*BM, col0 = blockIdx.x*BN;
  int am = tid >> 3, ak = (tid & 7) * 4;     // A: rows am+32s, k ak..ak+3
  int bn = tid & 127, bk = (tid >> 7) * 4;   // B: col bn, k bk+8s ..
  float ra[4][4], rb[4][4];
  int nK = (K + BK - 1) / BK;
  // prologue: load tile 0
  #pragma unroll
  for (int s=0;s<4;++s){
    int gr = row0 + am + 32*s;
    #pragma unroll
    for (int v=0;v<4;++v){ int gk = ak + v;
      ra[s][v] = (gr < M && gk < K) ? ag(gr, gk) : 0.f; }
    int gc = col0 + bn;
    #pragma unroll
    for (int v=0;v<4;++v){ int gk = bk + 8*s + v;
      rb[s][v] = (gc < N && gk < K) ? bg(gk, gc) : 0.f; }
  }
  f32x4 acc[4][4] = {};
  for (int t=0; t<nK; ++t) {
    // store prefetched regs to LDS
    #pragma unroll
    for (int s=0;s<4;++s){
      uint2 pa; pa.x = (unsigned)f2b(ra[s][0]) | ((unsigned)f2b(ra[s][1])<<16);
      pa.y = (unsigned)f2b(ra[s][2]) | ((unsigned)f2b(ra[s][3])<<16);
      *(uint2*)&As[(am + 32*s)*LDA + ak] = pa;
      uint2 pb; pb.x = (unsigned)f2b(rb[s][0]) | ((unsigned)f2b(rb[s][1])<<16);
      pb.y = (unsigned)f2b(rb[s][2]) | ((unsigned)f2b(rb[s][3])<<16);
      *(uint2*)&Bs[bn*LDA + bk + 8*s] = pb;
    }
    __syncthreads();
    if (t+1 < nK) {
      int k0 = (t+1)*BK;
      #pragma unroll
      for (int s=0;s<4;++s){
        int gr = row0 + am + 32*s;
        #pragma unroll
        for (int v=0;v<4;++v){ int gk = k0 + ak + v;
          ra[s][v] = (gr < M && gk < K) ? ag(gr, gk) : 0.f; }
        int gc = col0 + bn;
        #pragma unroll
        for (int v=0;v<4;++v){ int gk = k0 + bk + 8*s + v;
          rb[s][v] = (gc < N && gk < K) ? bg(gk, gc) : 0.f; }
      }
    }
    short8 a[4], b[4];
    #pragma unroll
    for (int it=0;it<4;++it) a[it] = *(const short8*)&As[(wr + it*16 + r16)*LDA + q*8];
    #pragma unroll
    for (int jt=0;jt<4;++jt) b[jt] = *(const short8*)&Bs[(wc + jt*16 + r16)*LDA + q*8];
    #pragma unroll
    for (int it=0;it<4;++it)
      #pragma unroll
      for (int jt=0;jt<4;++jt)
        acc[it][jt] = __builtin_amdgcn_mfma_f32_16x16x32_bf16(a[it], b[jt], acc[it][jt], 0, 0, 0);
    __syncthreads();
  }
  #pragma unroll
  for (int it=0;it<4;++it) {
    #pragma unroll
    for (int v=0;v<4;++v) {
      int rr = row0 + wr + it*16 + q*4 + v;
      if (rr >= M) continue;
      #pragma unroll
      for (int jt=0;jt<4;++jt) {
        int c = col0 + wc + jt*16 + r16;
        if (c >= N) continue;
        float val = ep(rr, c, acc[it][jt][v]);
        if (BOUT) ((ushort_t*)Cv)[(size_t)rr*ldc + c] = f2b(val);
        else      ((float*)Cv)[(size_t)rr*ldc + c] = val;
      }
    }
  }
}

// ---------------- small kernels ----------------
__global__ void k_transpose_bf(const float* src, ushort_t* dst, int R, int Cc) {
  __shared__ float tile[32][33];
  int c0 = blockIdx.x*32, r0 = blockIdx.y*32;
  int tx = threadIdx.x, ty = threadIdx.y;
  for (int i = ty; i < 32; i += 8) {
    int r = r0+i, c = c0+tx;
    if (r < R && c < Cc) tile[i][tx] = src[(size_t)r*Cc + c];
  }
  __syncthreads();
  for (int i = ty; i < 32; i += 8) {
    int dr = c0 + i, dc = r0 + tx;
    if (dr < Cc && dc < R) dst[(size_t)dr*R + dc] = f2b(tile[tx][i]);
  }
}

__global__ void k_copyY_bf(const float* out0, ushort_t* Y) { // Y[n*24576+bt*128+o]
  int i = blockIdx.x*256 + threadIdx.x;
  if (i >= 12288000) return;
  int o = i & 127; int r = i >> 7; int btl = r % 192; int n = r / 192;
  Y[i] = f2b(out0[((size_t)btl*500 + n)*128 + o]);
}

__global__ void k_pool0(const float* x, float* pooled) {
  int bt = blockIdx.x; int c = threadIdx.x; // 64
  const float* p = x + (size_t)bt*32000 + (size_t)c*500;
  float s = 0.f;
  for (int n=0;n<500;++n) s += p[n];
  pooled[bt*64 + c] = s*(1.f/500.f);
}
__global__ void k_pool1(const float* src, float* pooled) {
  int bt = blockIdx.x; int o = threadIdx.x; // 128
  float s = 0.f;
  for (int n=0;n<500;++n) s += src[((size_t)bt*500 + n)*128 + o];
  pooled[bt*128 + o] = s*(1.f/500.f);
}

__global__ void k_mlp(const float* pooled, int F, const float* f1w, const float* f1b,
                      const float* f2w, const float* f2b, float* aout) {
  int bt = threadIdx.x;
  if (bt >= 192) return;
  float h[8];
  for (int k=0;k<8;++k){
    float s = f1b[k];
    for (int c=0;c<F;++c) s += pooled[bt*F + c]*f1w[k*F + c];
    h[k] = fmaxf(s, 0.f);
  }
  float z[8]; float m = -1e30f;
  for (int k2=0;k2<8;++k2){
    float s = f2b[k2];
    for (int k=0;k<8;++k) s += h[k]*f2w[k2*8 + k];
    z[k2] = s; m = fmaxf(m, s);
  }
  float den = 0.f;
  for (int k2=0;k2<8;++k2){ z[k2] = expf(z[k2]-m); den += z[k2]; }
  float inv = 1.f/den;
  for (int k2=0;k2<8;++k2) aout[bt*8 + k2] = z[k2]*inv;
}

__global__ void k_ne(const float* a, const float* emb, float* ne) {
  int i = blockIdx.x*256 + threadIdx.x;
  if (i >= 768000) return;
  int d = i & 7; int rem = i >> 3; int n = rem % 500; int bt = rem / 500;
  float s = 0.f;
  #pragma unroll
  for (int k=0;k<8;++k) s += a[bt*8 + k]*emb[((size_t)k*500 + n)*8 + d];
  ne[i] = s;
}

__global__ void k_bn_stats(const float* src, float* stats, int M) {
  int col = threadIdx.x & 127; int seg = threadIdx.x >> 7;
  int r0 = blockIdx.x * 500; int r1 = r0 + 500; if (r1 > M) r1 = M;
  float s = 0.f, q = 0.f;
  for (int r = r0 + seg; r < r1; r += 2) {
    float v = src[(size_t)r*128 + col];
    s += v; q += v*v;
  }
  atomicAdd(&stats[col], s);
  atomicAdd(&stats[128+col], q);
}
__global__ void k_bn_stats_bf(const ushort_t* src, float* stats, int M) {
  int col = threadIdx.x & 127; int seg = threadIdx.x >> 7;
  int r0 = blockIdx.x * 500; int r1 = r0 + 500; if (r1 > M) r1 = M;
  float s = 0.f, q = 0.f;
  for (int r = r0 + seg; r < r1; r += 2) {
    float v = b2f(src[(size_t)r*128 + col]);
    s += v; q += v*v;
  }
  atomicAdd(&stats[col], s);
  atomicAdd(&stats[128+col], q);
}

__global__ void k_bn_apply(float* dst, const float* src, const float* st,
                           const float* g, const float* b, int total, float invM, int relu, int addd) {
  int i = blockIdx.x*256 + threadIdx.x;
  if (i >= total) return;
  int c = i & 127;
  float mean = st[c]*invM; float var = st[128+c]*invM - mean*mean;
  float rstd = rsqrtf(var + 1e-5f);
  float y = (src[i]-mean)*rstd*g[c] + b[c];
  if (relu) y = fmaxf(y, 0.f);
  dst[i] = addd ? dst[i] + y : y;
}

// fused gi-GEMM + GRU: all 4000 bn in one launch; 500 blocks x 8 bn
__global__ __launch_bounds__(384) void k_gru2(const float* out2, const float* wih, const float* whh,
    const float* bih, const float* bhh, float* hs) {
  __shared__ float h[8][132];
  __shared__ float xs[8][132];
  __shared__ float ui[8][388];
  __shared__ float uh[8][388];
  int tid = threadIdx.x;
  int bn0 = blockIdx.x*8;
  for (int i=tid;i<1024;i+=384) h[i>>7][i&127] = 0.f;
  __syncthreads();
  int j = tid;
  float bi = bih[j], bh = bhh[j];
  const float* wi = wih + (size_t)j*128;
  const float* wh = whh + (size_t)j*128;
  for (int t=0;t<24;++t) {
    for (int i=tid;i<1024;i+=384){
      int r=i>>7, c=i&127; int bnn=bn0+r; int b=bnn/500, n=bnn-b*500;
      xs[r][c] = out2[((size_t)(b*24+t)*500+n)*128 + c];
    }
    __syncthreads();
    float ai[8], ah[8];
    #pragma unroll
    for (int r=0;r<8;++r){ ai[r]=bi; ah[r]=bh; }
    for (int c=0;c<128;c+=4){
      float4 w4i = *(const float4*)&wi[c];
      float4 w4h = *(const float4*)&wh[c];
      #pragma unroll
      for (int r=0;r<8;++r){
        float4 xv = *(const float4*)&xs[r][c];
        float4 hv = *(const float4*)&h[r][c];
        ai[r] += xv.x*w4i.x + xv.y*w4i.y + xv.z*w4i.z + xv.w*w4i.w;
        ah[r] += hv.x*w4h.x + hv.y*w4h.y + hv.z*w4h.z + hv.w*w4h.w;
      }
    }
    #pragma unroll
    for (int r=0;r<8;++r){ ui[r][j]=ai[r]; uh[r][j]=ah[r]; }
    __syncthreads();
    for (int i=tid;i<1024;i+=384){
      int r=i>>7, u=i&127;
      float ir=ui[r][u], iz=ui[r][128+u], inn=ui[r][256+u];
      float hr=uh[r][u], hz=uh[r][128+u], hn=uh[r][256+u];
      float rg = 1.f/(1.f+expf(-(ir+hr)));
      float zg = 1.f/(1.f+expf(-(iz+hz)));
      float ng = tanhf(inn + rg*hn);
      float hnew = (1.f-zg)*ng + zg*h[r][u];
      h[r][u] = hnew;
      hs[((size_t)(bn0+r)*24 + t)*128 + u] = hnew;
    }
    __syncthreads();
  }
}

// fused conv-Q/K/V + attention + fc + ow: one block per (b,n)
__global__ __launch_bounds__(256) void k_attn2(const float* hs,
    const float* cqw, const float* cqb, const float* ckw, const float* ckb,
    const float* vw, const float* vb, const float* ow, const float* ob,
    const float* fcw, const float* fcb, float* out2f) {
  __shared__ float un[4608];           // X[26][132] (3432) then Sc[8][24][24] (4608)
  __shared__ float Qs[24][132];
  __shared__ float Ks[24][132];
  __shared__ float Vs[24][132];
  __shared__ float xbar[128];
  float (*X)[132] = (float(*)[132])un;
  float (*Sc)[24][24] = (float(*)[24][24])un;
  int bn = blockIdx.x; int tid = threadIdx.x;
  for (int i=tid;i<3072;i+=256){ int t=i>>7, c=i&127; X[t+1][c] = hs[(size_t)bn*3072 + i]; }
  if (tid < 128) X[0][tid] = 0.f; else X[25][tid-128] = 0.f;
  __syncthreads();
  {
    int o = tid & 127; int th = tid >> 7; int t0 = th*12;
    float aQ[12], aK[12], aV[12];
    float cb = cqb[o], kb = ckb[o], vbv = vb[o];
    #pragma unroll
    for (int tt=0;tt<12;++tt){ aQ[tt]=cb; aK[tt]=kb; aV[tt]=vbv; }
    const float* wq = cqw + (size_t)o*384;
    const float* wk = ckw + (size_t)o*384;
    const float* wv = vw + (size_t)o*128;
    for (int c=0;c<128;++c){
      float q0=wq[c*3], q1=wq[c*3+1], q2=wq[c*3+2];
      float k0=wk[c*3], k1=wk[c*3+1], k2=wk[c*3+2];
      float vv=wv[c];
      float xp = X[t0][c], xc = X[t0+1][c];
      #pragma unroll
      for (int tt=0;tt<12;++tt){
        float xn = X[t0+tt+2][c];
        aQ[tt] += xp*q0 + xc*q1 + xn*q2;
        aK[tt] += xp*k0 + xc*k1 + xn*k2;
        aV[tt] += xc*vv;
        xp = xc; xc = xn;
      }
    }
    #pragma unroll
    for (int tt=0;tt<12;++tt){ Qs[t0+tt][o]=aQ[tt]; Ks[t0+tt][o]=aK[tt]; Vs[t0+tt][o]=aV[tt]; }
  }
  __syncthreads();
  for (int i=tid;i<4608;i+=256){
    int hh = i/576; int r = i - hh*576; int t = r/24; int s_ = r - t*24;
    float d = 0.f;
    #pragma unroll
    for (int dd=0;dd<16;++dd) d += Qs[t][hh*16+dd]*Ks[s_][hh*16+dd];
    Sc[hh][t][s_] = d*0.25f;
  }
  __syncthreads();
  if (tid < 192) {
    int hh = tid/24, t = tid - (tid/24)*24;
    float m = -1e30f;
    for (int s_=0;s_<24;++s_) m = fmaxf(m, Sc[hh][t][s_]);
    float den = 0.f;
    for (int s_=0;s_<24;++s_){ float e = expf(Sc[hh][t][s_]-m); Sc[hh][t][s_] = e; den += e; }
    float inv = 1.f/den;
    for (int s_=0;s_<24;++s_) Sc[hh][t][s_] *= inv;
  }
  __syncthreads();
  for (int i=tid;i<3072;i+=256){
    int t = i >> 7; int o = i & 127; int hh = o >> 4;
    float s = 0.f;
    #pragma unroll
    for (int s_=0;s_<24;++s_) s += Sc[hh][t][s_]*Vs[s_][o];
    Qs[t][o] = s;
  }
  __syncthreads();
  if (tid < 128) {
    float s = 0.f;
    for (int t=0;t<24;++t) s += fcw[t]*Qs[t][tid];
    xbar[tid] = s;
  }
  __syncthreads();
  if (tid < 128) {
    int o = tid;
    float s = 0.f;
    for (int c=0;c<128;++c) s += xbar[c]*ow[o*128 + c];
    float sfc = 0.f;
    for (int t=0;t<24;++t) sfc += fcw[t];
    out2f[(size_t)bn*128 + o] = s + sfc*ob[o] + fcb[0];
  }
}

__global__ void k_rbar(const float* out2, const float* rw, float* rbar) {
  int i = blockIdx.x*256 + threadIdx.x;
  if (i >= 512000) return;
  int c = i & 127; int bnn = i >> 7; int b = bnn/500, n = bnn - b*500;
  float s = 0.f;
  #pragma unroll
  for (int t=0;t<24;++t) s += rw[t] * out2[((size_t)(b*24 + t)*500 + n)*128 + c];
  rbar[i] = s;
}

__global__ void k_te(const float* tt, const float* w1, const float* b1,
                     const float* w2, const float* b2, float* te) {
  __shared__ float h1[128];
  int b = blockIdx.x; int o = threadIdx.x;
  float s = b1[o];
  for (int c=0;c<32;++c) s += tt[b*32 + c]*w1[o*32 + c];
  h1[o] = fmaxf(s, 0.f);
  __syncthreads();
  float s2 = b2[o];
  for (int c=0;c<128;++c) s2 += h1[c]*w2[o*128 + c];
  te[b*128 + o] = s2;
}

__global__ void k_grid(const float* gnm, const float* fin, float* out) {
  int e = threadIdx.x & 63; int gq = threadIdx.x >> 6;
  int g = blockIdx.x*4 + gq; int b = blockIdx.y;
  float s = 0.f;
  const float* gr = gnm + (size_t)g*500;
  const float* fb = fin + (size_t)b*500*64 + e;
  for (int n=0;n<500;++n) s += gr[n] * fb[(size_t)n*64];
  out[(size_t)b*32000 + (size_t)e*500 + g] = s;
}

// ---------------- launch ----------------
extern "C" void kernel_launch(void* const* d_in, const int* in_sizes, int n_in,
                              void* d_out, int out_size, void* d_ws, size_t ws_size,
                              hipStream_t stream) {
  const float* adj   = (const float*)d_in[0];
  const float* x     = (const float*)d_in[1];
  const float* gnm   = (const float*)d_in[2];
  const float* ttime = (const float*)d_in[3];
  const float* emb   = (const float*)d_in[4];
  const float* wp0   = (const float*)d_in[5];
  const float* bp0   = (const float*)d_in[6];
  const float* a0f1w = (const float*)d_in[7];
  const float* a0f1b = (const float*)d_in[8];
  const float* a0f2w = (const float*)d_in[9];
  const float* a0f2b = (const float*)d_in[10];
  const float* wp1   = (const float*)d_in[11];
  const float* bp1   = (const float*)d_in[12];
  const float* a1f1w = (const float*)d_in[13];
  const float* a1f1b = (const float*)d_in[14];
  const float* a1f2w = (const float*)d_in[15];
  const float* a1f2b = (const float*)d_in[16];
  const float* bn0g  = (const float*)d_in[17];
  const float* bn0b  = (const float*)d_in[18];
  const float* bn1g  = (const float*)d_in[19];
  const float* bn1b  = (const float*)d_in[20];
  const float* wih   = (const float*)d_in[21];
  const float* whh   = (const float*)d_in[22];
  const float* bih   = (const float*)d_in[23];
  const float* bhh   = (const float*)d_in[24];
  const float* bgg   = (const float*)d_in[25];
  const float* bgb   = (const float*)d_in[26];
  const float* cqw   = (const float*)d_in[27];
  const float* cqb   = (const float*)d_in[28];
  const float* ckw   = (const float*)d_in[29];
  const float* ckb   = (const float*)d_in[30];
  const float* vw    = (const float*)d_in[31];
  const float* vb    = (const float*)d_in[32];
  const float* ow    = (const float*)d_in[33];
  const float* ob    = (const float*)d_in[34];
  const float* r1w   = (const float*)d_in[35];
  const float* r1b   = (const float*)d_in[36];
  const float* fcw   = (const float*)d_in[37];
  const float* fcb   = (const float*)d_in[38];
  const float* rcw   = (const float*)d_in[39];
  const float* rcb   = (const float*)d_in[40];
  const float* r2w   = (const float*)d_in[41];
  const float* r2b   = (const float*)d_in[42];
  const float* bnrg  = (const float*)d_in[43];
  const float* bnrb  = (const float*)d_in[44];
  const float* te1w  = (const float*)d_in[45];
  const float* te1b  = (const float*)d_in[46];
  const float* te2w  = (const float*)d_in[47];
  const float* te2b  = (const float*)d_in[48];
  const float* finw  = (const float*)d_in[49];
  const float* finb  = (const float*)d_in[50];
  float* dout = (float*)d_out;
  float* W = (float*)d_ws;

  size_t off = 0;
  auto alloc = [&](size_t n){ size_t r = off; off += (n + 255) & ~(size_t)255; return r; };
  size_t oStats = alloc(256);
  size_t oPool  = alloc(24576);
  size_t oAmix  = alloc(1536);
  size_t oTe    = alloc(1024);
  size_t oO2f   = alloc(512000);
  size_t oRbar  = alloc(512000);
  size_t oRes   = alloc(512000);
  size_t oFin   = alloc(256000);
  size_t oNe0   = alloc(768000);
  size_t oNe1   = alloc(768000);
  size_t oS2    = alloc(125000);    // bf16 [500][500]
  size_t oR1    = alloc(12288000);  // out0 -> out2 (f32)
  size_t oR2    = alloc(12288000);  // XG-A pair bf16 -> XG-B pair bf16 -> hs f32
  size_t oR4    = alloc(6144000);   // Xn bf16 -> Y0bf bf16 -> out1 bf16
  (void)n_in; (void)in_sizes; (void)out_size;
  if (ws_size < off * sizeof(float)) return;

  float* stats = W + oStats;
  float* pooled= W + oPool;
  float* amix  = W + oAmix;
  float* teb   = W + oTe;
  float* out2f = W + oO2f;
  float* rbar  = W + oRbar;
  float* resout= W + oRes;
  float* fin   = W + oFin;
  float* ne0   = W + oNe0;
  float* ne1   = W + oNe1;
  ushort_t* S2bf = (ushort_t*)(W + oS2);
  float* out0  = W + oR1;
  float* out2  = W + oR1;
  ushort_t* XG1n = (ushort_t*)(W + oR2);             // [500][12288]
  ushort_t* XG2n = XG1n + 6144000;
  ushort_t* XGB1 = (ushort_t*)(W + oR2);             // [500][24576]
  ushort_t* XGB2 = XGB1 + 12288000;
  float* hs    = W + oR2;
  ushort_t* Xnbf = (ushort_t*)(W + oR4);             // [500][12288]
  ushort_t* Y0bf = (ushort_t*)(W + oR4);             // [500][24576]
  ushort_t* out1 = (ushort_t*)(W + oR4);             // [96000][128]

  // ---- Phase A ----
  k_transpose_bf<<<dim3(16,384), dim3(32,8), 0, stream>>>(x, Xnbf, 12288, 500);
  gemm_mfma<true><<<dim3(4,4), 256, 0, stream>>>(
      AgF32{adj,500}, BgF32{adj,500}, EpS2{}, (void*)S2bf, 500, 500, 500, 500);
  gemm_mfma<true><<<dim3(96,4), 256, 0, stream>>>(
      AgF32{adj,500}, BgBf16p{Xnbf,12288}, EpNone{}, (void*)XG1n, 500, 12288, 500, 12288);
  gemm_mfma<true><<<dim3(96,4), 256, 0, stream>>>(
      AgBf16p{S2bf,500}, BgBf16p{Xnbf,12288}, EpNone{}, (void*)XG2n, 500, 12288, 500, 12288);
  k_pool0<<<192, 64, 0, stream>>>(x, pooled);
  k_mlp<<<1, 192, 0, stream>>>(pooled, 64, a0f1w, a0f1b, a0f2w, a0f2b, amix);
  k_ne<<<3000, 256, 0, stream>>>(amix, emb, ne0);
  gemm_mfma<false><<<dim3(1,750), 256, 0, stream>>>(
      AgFlex0{Xnbf, XG1n, XG2n, ne0}, BgF32{wp0,128}, EpNeBias{ne0, bp0},
      (void*)out0, 96000, 128, 1536, 128);
  hipMemsetAsync((void*)stats, 0, 256*sizeof(float), stream);
  k_bn_stats<<<192, 256, 0, stream>>>(out0, stats, 96000);
  k_bn_apply<<<48000, 256, 0, stream>>>(out0, out0, stats, bn0g, bn0b, 12288000, 1.f/96000.f, 1, 0);

  // ---- Phase B ----
  k_pool1<<<192, 128, 0, stream>>>(out0, pooled);
  k_mlp<<<1, 192, 0, stream>>>(pooled, 128, a1f1w, a1f1b, a1f2w, a1f2b, amix);
  k_ne<<<3000, 256, 0, stream>>>(amix, emb, ne1);
  k_copyY_bf<<<48000, 256, 0, stream>>>(out0, Y0bf);
  gemm_mfma<true><<<dim3(192,4), 256, 0, stream>>>(
      AgF32{adj,500}, BgBf16p{Y0bf,24576}, EpNone{}, (void*)XGB1, 500, 24576, 500, 24576);
  gemm_mfma<true><<<dim3(192,4), 256, 0, stream>>>(
      AgBf16p{S2bf,500}, BgBf16p{Y0bf,24576}, EpNone{}, (void*)XGB2, 500, 24576, 500, 24576);
  gemm_mfma<true><<<dim3(1,750), 256, 0, stream>>>(
      AgFlex1{out0, XGB1, XGB2, ne1}, BgF32{wp1,128}, EpNeBias{ne1, bp1},
      (void*)out1, 96000, 128, 3072, 128);
  hipMemsetAsync((void*)stats, 0, 256*sizeof(float), stream);
  k_bn_stats_bf<<<192, 256, 0, stream>>>(out1, stats, 96000);
  gemm_mfma<false><<<dim3(1,750), 256, 0, stream>>>(
      AgXrow{x}, BgT{r1w,64}, EpRes1{out1, stats, bn1g, bn1b, r1b, 1.f/96000.f},
      (void*)out2, 96000, 128, 64, 128);

  // ---- Phase C: fused gi+GRU ----
  k_gru2<<<500, 384, 0, stream>>>(out2, wih, whh, bih, bhh, hs);
  hipMemsetAsync((void*)stats, 0, 256*sizeof(float), stream);
  k_bn_stats<<<192, 256, 0, stream>>>(hs, stats, 96000);
  k_bn_apply<<<48000, 256, 0, stream>>>(hs, hs, stats, bgg, bgb, 12288000, 1.f/96000.f, 1, 0);

  // ---- Phase D: fused QKV+attention ----
  k_attn2<<<4000, 256, 0, stream>>>(hs, cqw, cqb, ckw, ckb, vw, vb, ow, ob, fcw, fcb, out2f);

  // ---- Phase E ----
  k_rbar<<<2000, 256, 0, stream>>>(out2, rcw, rbar);
  gemm_mfma<false><<<dim3(1,32), 256, 0, stream>>>(
      AgF32{rbar,128}, BgT{r2w,128}, EpRes2{r2b, rcw, rcb}, (void*)resout, 4000, 128, 128, 128);
  hipMemsetAsync((void*)stats, 0, 256*sizeof(float), stream);
  k_bn_stats<<<8, 256, 0, stream>>>(resout, stats, 4000);
  k_bn_apply<<<2000, 256, 0, stream>>>(out2f, resout, stats, bnrg, bnrb, 512000, 1.f/4000.f, 0, 1);
  k_te<<<8, 128, 0, stream>>>(ttime, te1w, te1b, te2w, te2b, teb);
  gemm_mfma<false><<<dim3(1,32), 256, 0, stream>>>(
      AgTeAdd{out2f, teb}, BgT{finw,128}, EpBias{finb}, (void*)fin, 4000, 64, 128, 64);
  k_grid<<<dim3(125,8), 256, 0, stream>>>(gnm, fin, dout);
}

// Round 6
// 4358.462 us; speedup vs baseline: 2.5244x; 1.2902x over previous
//
#include <hip/hip_runtime.h>
#include <math.h>

using short8 = __attribute__((ext_vector_type(8))) short;
using f32x4  = __attribute__((ext_vector_type(4))) float;
using ushort_t = unsigned short;

__device__ __forceinline__ ushort_t f2b(float f){
  unsigned int u = __builtin_bit_cast(unsigned int, f);
  u = (u + 0x7fffu + ((u >> 16) & 1u)) >> 16;
  return (ushort_t)u;
}
__device__ __forceinline__ float b2f(ushort_t u){
  unsigned int v = ((unsigned int)u) << 16;
  return __builtin_bit_cast(float, v);
}

// ---------------- generator functors ----------------
struct AgF32 { const float* A; int lda;
  __device__ float operator()(int r, int k) const { return A[(size_t)r*lda + k]; } };
struct AgBf16p { const ushort_t* A; int lda;
  __device__ float operator()(int r, int k) const { return b2f(A[(size_t)r*lda + k]); } };
struct AgXrow { const float* x;  // row=bt*500+n, k=c : x[bt,c,n]
  __device__ float operator()(int r, int k) const {
    int bt = r/500, n = r - bt*500;
    return x[(size_t)bt*32000 + (size_t)k*500 + n]; } };
struct AgFlex0 { const ushort_t* Xn; const ushort_t* XG1; const ushort_t* XG2; const float* ne;
  __device__ float operator()(int r, int kp) const {
    int d = kp / 192; int kc = kp - d*192; int k = kc >> 6; int c = kc & 63;
    int bt = r/500, n = r - bt*500;
    const ushort_t* s = (k==0)? Xn : (k==1)? XG1 : XG2;
    float v = b2f(s[(size_t)n*12288 + bt*64 + c]);
    return ne[(size_t)r*8 + d] * v; } };
struct AgFlex1 { const float* s0; const ushort_t* XG1; const ushort_t* XG2; const float* ne;
  __device__ float operator()(int r, int kp) const {
    int d = kp / 384; int kc = kp - d*384; int k = kc >> 7; int c = kc & 127;
    int bt = r/500, n = r - bt*500;
    float v = (k==0) ? s0[(size_t)r*128 + c]
                     : b2f(((k==1)?XG1:XG2)[(size_t)n*24576 + bt*128 + c]);
    return ne[(size_t)r*8 + d] * v; } };
struct AgConv { const float* hs; // rows bn*24+t, k = dt*128+c, pad over t
  __device__ float operator()(int r, int k) const {
    int t = r % 24; int dt = k >> 7; int c = k & 127; int t2 = t + dt - 1;
    if (t2 < 0 || t2 >= 24) return 0.f;
    return hs[(size_t)(r + (t2 - t))*128 + c]; } };
struct AgTeAdd { const float* o2f; const float* te;
  __device__ float operator()(int r, int k) const {
    return o2f[(size_t)r*128 + k] + te[(size_t)(r/500)*128 + k]; } };

struct BgF32 { const float* Bp; int ldb;
  __device__ float operator()(int k, int c) const { return Bp[(size_t)k*ldb + c]; } };
struct BgBf16p { const ushort_t* Bp; int ldb;
  __device__ float operator()(int k, int c) const { return b2f(Bp[(size_t)k*ldb + c]); } };
struct BgT { const float* W; int ld;   // weight [O,I] -> B[k][o]=W[o][k]
  __device__ float operator()(int k, int c) const { return W[(size_t)c*ld + k]; } };
struct BgConvW { const float* w;       // w[o,c,0,dt], k = dt*128+c
  __device__ float operator()(int k, int c) const {
    int dt = k >> 7; int cc = k & 127;
    return w[((size_t)c*128 + cc)*3 + dt]; } };

struct EpNone { __device__ float operator()(int, int, float a) const { return a; } };
struct EpS2   { __device__ float operator()(int r, int c, float a) const { return 2.f*a - (r==c ? 1.f : 0.f); } };
struct EpBias { const float* b;
  __device__ float operator()(int, int c, float a) const { return a + b[c]; } };
struct EpNeBias { const float* ne; const float* bp;
  __device__ float operator()(int r, int c, float a) const {
    float s = a;
    #pragma unroll
    for (int d=0; d<8; ++d) s += ne[(size_t)r*8 + d]*bp[d*128 + c];
    return s; } };
struct EpRes1 { const ushort_t* out1; const float* st; const float *g, *bb, *rb; float invM;
  __device__ float operator()(int r, int c, float a) const {
    float mean = st[c]*invM; float var = st[128+c]*invM - mean*mean;
    float rstd = rsqrtf(var + 1e-5f);
    float y = (b2f(out1[(size_t)r*128 + c]) - mean)*rstd*g[c] + bb[c];
    y = fmaxf(y, 0.f);
    return a + rb[c] + y; } };
struct EpRes2 { const float *r2b, *rw, *rcb;
  __device__ float operator()(int, int c, float a) const {
    float s = 0.f;
    #pragma unroll
    for (int t=0; t<24; ++t) s += rw[t];
    return a + s*r2b[c] + rcb[0]; } };

// ---------------- pipelined MFMA generator GEMM ----------------
template<bool BOUT, class AG, class BG, class EP>
__global__ __launch_bounds__(256)
void gemm_mfma(AG ag, BG bg, EP ep, void* Cv, int M, int N, int K, int ldc) {
  constexpr int BM=128, BN=128, BK=32;
  constexpr int LDA = BK + 8;
  __shared__ ushort_t As[BM*LDA];
  __shared__ ushort_t Bs[BN*LDA];
  int tid = threadIdx.x;
  int lane = tid & 63, wave = tid >> 6;
  int wr = (wave >> 1) * 64, wc = (wave & 1) * 64;
  int q = lane >> 4, r16 = lane & 15;
  int row0 = blockIdx.y*BM, col0 = blockIdx.x*BN;
  int am = tid >> 3, ak = (tid & 7) * 4;
  int bn = tid & 127, bk = (tid >> 7) * 4;
  float ra[4][4], rb[4][4];
  int nK = (K + BK - 1) / BK;
  #pragma unroll
  for (int s=0;s<4;++s){
    int gr = row0 + am + 32*s;
    #pragma unroll
    for (int v=0;v<4;++v){ int gk = ak + v;
      ra[s][v] = (gr < M && gk < K) ? ag(gr, gk) : 0.f; }
    int gc = col0 + bn;
    #pragma unroll
    for (int v=0;v<4;++v){ int gk = bk + 8*s + v;
      rb[s][v] = (gc < N && gk < K) ? bg(gk, gc) : 0.f; }
  }
  f32x4 acc[4][4] = {};
  for (int t=0; t<nK; ++t) {
    #pragma unroll
    for (int s=0;s<4;++s){
      uint2 pa; pa.x = (unsigned)f2b(ra[s][0]) | ((unsigned)f2b(ra[s][1])<<16);
      pa.y = (unsigned)f2b(ra[s][2]) | ((unsigned)f2b(ra[s][3])<<16);
      *(uint2*)&As[(am + 32*s)*LDA + ak] = pa;
      uint2 pb; pb.x = (unsigned)f2b(rb[s][0]) | ((unsigned)f2b(rb[s][1])<<16);
      pb.y = (unsigned)f2b(rb[s][2]) | ((unsigned)f2b(rb[s][3])<<16);
      *(uint2*)&Bs[bn*LDA + bk + 8*s] = pb;
    }
    __syncthreads();
    if (t+1 < nK) {
      int k0 = (t+1)*BK;
      #pragma unroll
      for (int s=0;s<4;++s){
        int gr = row0 + am + 32*s;
        #pragma unroll
        for (int v=0;v<4;++v){ int gk = k0 + ak + v;
          ra[s][v] = (gr < M && gk < K) ? ag(gr, gk) : 0.f; }
        int gc = col0 + bn;
        #pragma unroll
        for (int v=0;v<4;++v){ int gk = k0 + bk + 8*s + v;
          rb[s][v] = (gc < N && gk < K) ? bg(gk, gc) : 0.f; }
      }
    }
    short8 a[4], b[4];
    #pragma unroll
    for (int it=0;it<4;++it) a[it] = *(const short8*)&As[(wr + it*16 + r16)*LDA + q*8];
    #pragma unroll
    for (int jt=0;jt<4;++jt) b[jt] = *(const short8*)&Bs[(wc + jt*16 + r16)*LDA + q*8];
    #pragma unroll
    for (int it=0;it<4;++it)
      #pragma unroll
      for (int jt=0;jt<4;++jt)
        acc[it][jt] = __builtin_amdgcn_mfma_f32_16x16x32_bf16(a[it], b[jt], acc[it][jt], 0, 0, 0);
    __syncthreads();
  }
  #pragma unroll
  for (int it=0;it<4;++it) {
    #pragma unroll
    for (int v=0;v<4;++v) {
      int rr = row0 + wr + it*16 + q*4 + v;
      if (rr >= M) continue;
      #pragma unroll
      for (int jt=0;jt<4;++jt) {
        int c = col0 + wc + jt*16 + r16;
        if (c >= N) continue;
        float val = ep(rr, c, acc[it][jt][v]);
        if (BOUT) ((ushort_t*)Cv)[(size_t)rr*ldc + c] = f2b(val);
        else      ((float*)Cv)[(size_t)rr*ldc + c] = val;
      }
    }
  }
}

// ---------------- small kernels ----------------
__global__ void k_transpose_bf(const float* src, ushort_t* dst, int R, int Cc) {
  __shared__ float tile[32][33];
  int c0 = blockIdx.x*32, r0 = blockIdx.y*32;
  int tx = threadIdx.x, ty = threadIdx.y;
  for (int i = ty; i < 32; i += 8) {
    int r = r0+i, c = c0+tx;
    if (r < R && c < Cc) tile[i][tx] = src[(size_t)r*Cc + c];
  }
  __syncthreads();
  for (int i = ty; i < 32; i += 8) {
    int dr = c0 + i, dc = r0 + tx;
    if (dr < Cc && dc < R) dst[(size_t)dr*R + dc] = f2b(tile[tx][i]);
  }
}

__global__ void k_copyY_bf(const float* out0, ushort_t* Y) {
  int i = blockIdx.x*256 + threadIdx.x;
  if (i >= 12288000) return;
  int o = i & 127; int r = i >> 7; int btl = r % 192; int n = r / 192;
  Y[i] = f2b(out0[((size_t)btl*500 + n)*128 + o]);
}

__global__ void k_pool0(const float* x, float* pooled) {
  int bt = blockIdx.x; int c = threadIdx.x;
  const float* p = x + (size_t)bt*32000 + (size_t)c*500;
  float s = 0.f;
  for (int n=0;n<500;++n) s += p[n];
  pooled[bt*64 + c] = s*(1.f/500.f);
}
__global__ void k_pool1(const float* src, float* pooled) {
  int bt = blockIdx.x; int o = threadIdx.x;
  float s = 0.f;
  for (int n=0;n<500;++n) s += src[((size_t)bt*500 + n)*128 + o];
  pooled[bt*128 + o] = s*(1.f/500.f);
}

__global__ void k_mlp(const float* pooled, int F, const float* f1w, const float* f1b,
                      const float* f2w, const float* f2b, float* aout) {
  int bt = threadIdx.x;
  if (bt >= 192) return;
  float h[8];
  for (int k=0;k<8;++k){
    float s = f1b[k];
    for (int c=0;c<F;++c) s += pooled[bt*F + c]*f1w[k*F + c];
    h[k] = fmaxf(s, 0.f);
  }
  float z[8]; float m = -1e30f;
  for (int k2=0;k2<8;++k2){
    float s = f2b[k2];
    for (int k=0;k<8;++k) s += h[k]*f2w[k2*8 + k];
    z[k2] = s; m = fmaxf(m, s);
  }
  float den = 0.f;
  for (int k2=0;k2<8;++k2){ z[k2] = expf(z[k2]-m); den += z[k2]; }
  float inv = 1.f/den;
  for (int k2=0;k2<8;++k2) aout[bt*8 + k2] = z[k2]*inv;
}

__global__ void k_ne(const float* a, const float* emb, float* ne) {
  int i = blockIdx.x*256 + threadIdx.x;
  if (i >= 768000) return;
  int d = i & 7; int rem = i >> 3; int n = rem % 500; int bt = rem / 500;
  float s = 0.f;
  #pragma unroll
  for (int k=0;k<8;++k) s += a[bt*8 + k]*emb[((size_t)k*500 + n)*8 + d];
  ne[i] = s;
}

__global__ void k_bn_stats(const float* src, float* stats, int M) {
  int col = threadIdx.x & 127; int seg = threadIdx.x >> 7;
  int r0 = blockIdx.x * 500; int r1 = r0 + 500; if (r1 > M) r1 = M;
  float s = 0.f, q = 0.f;
  for (int r = r0 + seg; r < r1; r += 2) {
    float v = src[(size_t)r*128 + col];
    s += v; q += v*v;
  }
  atomicAdd(&stats[col], s);
  atomicAdd(&stats[128+col], q);
}
__global__ void k_bn_stats_bf(const ushort_t* src, float* stats, int M) {
  int col = threadIdx.x & 127; int seg = threadIdx.x >> 7;
  int r0 = blockIdx.x * 500; int r1 = r0 + 500; if (r1 > M) r1 = M;
  float s = 0.f, q = 0.f;
  for (int r = r0 + seg; r < r1; r += 2) {
    float v = b2f(src[(size_t)r*128 + col]);
    s += v; q += v*v;
  }
  atomicAdd(&stats[col], s);
  atomicAdd(&stats[128+col], q);
}

__global__ void k_bn_apply(float* dst, const float* src, const float* st,
                           const float* g, const float* b, int total, float invM, int relu, int addd) {
  int i = blockIdx.x*256 + threadIdx.x;
  if (i >= total) return;
  int c = i & 127;
  float mean = st[c]*invM; float var = st[128+c]*invM - mean*mean;
  float rstd = rsqrtf(var + 1e-5f);
  float y = (src[i]-mean)*rstd*g[c] + b[c];
  if (relu) y = fmaxf(y, 0.f);
  dst[i] = addd ? dst[i] + y : y;
}

// fused gi-GEMM + GRU: 500 blocks x 8 bn
__global__ __launch_bounds__(384) void k_gru2(const float* out2, const float* wih, const float* whh,
    const float* bih, const float* bhh, float* hs) {
  __shared__ float h[8][132];
  __shared__ float xs[8][132];
  __shared__ float ui[8][388];
  __shared__ float uh[8][388];
  int tid = threadIdx.x;
  int bn0 = blockIdx.x*8;
  for (int i=tid;i<1024;i+=384) h[i>>7][i&127] = 0.f;
  __syncthreads();
  int j = tid;
  float bi = bih[j], bh = bhh[j];
  const float* wi = wih + (size_t)j*128;
  const float* wh = whh + (size_t)j*128;
  for (int t=0;t<24;++t) {
    for (int i=tid;i<1024;i+=384){
      int r=i>>7, c=i&127; int bnn=bn0+r; int b=bnn/500, n=bnn-b*500;
      xs[r][c] = out2[((size_t)(b*24+t)*500+n)*128 + c];
    }
    __syncthreads();
    float ai[8], ah[8];
    #pragma unroll
    for (int r=0;r<8;++r){ ai[r]=bi; ah[r]=bh; }
    for (int c=0;c<128;c+=4){
      float4 w4i = *(const float4*)&wi[c];
      float4 w4h = *(const float4*)&wh[c];
      #pragma unroll
      for (int r=0;r<8;++r){
        float4 xv = *(const float4*)&xs[r][c];
        float4 hv = *(const float4*)&h[r][c];
        ai[r] += xv.x*w4i.x + xv.y*w4i.y + xv.z*w4i.z + xv.w*w4i.w;
        ah[r] += hv.x*w4h.x + hv.y*w4h.y + hv.z*w4h.z + hv.w*w4h.w;
      }
    }
    #pragma unroll
    for (int r=0;r<8;++r){ ui[r][j]=ai[r]; uh[r][j]=ah[r]; }
    __syncthreads();
    for (int i=tid;i<1024;i+=384){
      int r=i>>7, u=i&127;
      float ir=ui[r][u], iz=ui[r][128+u], inn=ui[r][256+u];
      float hr=uh[r][u], hz=uh[r][128+u], hn=uh[r][256+u];
      float rg = 1.f/(1.f+expf(-(ir+hr)));
      float zg = 1.f/(1.f+expf(-(iz+hz)));
      float ng = tanhf(inn + rg*hn);
      float hnew = (1.f-zg)*ng + zg*h[r][u];
      h[r][u] = hnew;
      hs[((size_t)(bn0+r)*24 + t)*128 + u] = hnew;
    }
    __syncthreads();
  }
}

// attention-only: QK^T, softmax, PV, fc, ow  (Q/K/V bf16 from GEMMs)
__global__ __launch_bounds__(256) void k_attn3(const ushort_t* Q, const ushort_t* K, const ushort_t* V,
    const float* ow, const float* ob, const float* fcw, const float* fcb, float* out2f) {
  __shared__ float Qs[24][133];
  __shared__ float Ks[24][133];
  __shared__ float Vs[24][133];
  __shared__ float Sc[8][24][25];
  __shared__ float xbar[128];
  int bn = blockIdx.x; int tid = threadIdx.x;
  size_t base = (size_t)bn*3072;
  for (int i=tid;i<3072;i+=256){
    int t=i>>7, c=i&127;
    Qs[t][c]=b2f(Q[base+i]); Ks[t][c]=b2f(K[base+i]); Vs[t][c]=b2f(V[base+i]);
  }
  __syncthreads();
  for (int i=tid;i<4608;i+=256){
    int hh = i/576; int r = i - hh*576; int t = r/24; int s_ = r - t*24;
    float d = 0.f;
    #pragma unroll
    for (int dd=0;dd<16;++dd) d += Qs[t][hh*16+dd]*Ks[s_][hh*16+dd];
    Sc[hh][t][s_] = d*0.25f;
  }
  __syncthreads();
  if (tid < 192) {
    int hh = tid/24, t = tid - (tid/24)*24;
    float m = -1e30f;
    for (int s_=0;s_<24;++s_) m = fmaxf(m, Sc[hh][t][s_]);
    float den = 0.f;
    for (int s_=0;s_<24;++s_){ float e = expf(Sc[hh][t][s_]-m); Sc[hh][t][s_] = e; den += e; }
    float inv = 1.f/den;
    for (int s_=0;s_<24;++s_) Sc[hh][t][s_] *= inv;
  }
  __syncthreads();
  for (int i=tid;i<3072;i+=256){
    int t = i >> 7; int o = i & 127; int hh = o >> 4;
    float s = 0.f;
    #pragma unroll
    for (int s_=0;s_<24;++s_) s += Sc[hh][t][s_]*Vs[s_][o];
    Qs[t][o] = s;   // xa overwrites Qs
  }
  __syncthreads();
  if (tid < 128) {
    float s = 0.f;
    for (int t=0;t<24;++t) s += fcw[t]*Qs[t][tid];
    xbar[tid] = s;
  }
  __syncthreads();
  if (tid < 128) {
    int o = tid;
    float s = 0.f;
    for (int c=0;c<128;++c) s += xbar[c]*ow[o*128 + c];
    float sfc = 0.f;
    for (int t=0;t<24;++t) sfc += fcw[t];
    out2f[(size_t)bn*128 + o] = s + sfc*ob[o] + fcb[0];
  }
}

__global__ void k_rbar(const float* out2, const float* rw, float* rbar) {
  int i = blockIdx.x*256 + threadIdx.x;
  if (i >= 512000) return;
  int c = i & 127; int bnn = i >> 7; int b = bnn/500, n = bnn - b*500;
  float s = 0.f;
  #pragma unroll
  for (int t=0;t<24;++t) s += rw[t] * out2[((size_t)(b*24 + t)*500 + n)*128 + c];
  rbar[i] = s;
}

__global__ void k_te(const float* tt, const float* w1, const float* b1,
                     const float* w2, const float* b2, float* te) {
  __shared__ float h1[128];
  int b = blockIdx.x; int o = threadIdx.x;
  float s = b1[o];
  for (int c=0;c<32;++c) s += tt[b*32 + c]*w1[o*32 + c];
  h1[o] = fmaxf(s, 0.f);
  __syncthreads();
  float s2 = b2[o];
  for (int c=0;c<128;++c) s2 += h1[c]*w2[o*128 + c];
  te[b*128 + o] = s2;
}

__global__ void k_grid(const float* gnm, const float* fin, float* out) {
  int e = threadIdx.x & 63; int gq = threadIdx.x >> 6;
  int g = blockIdx.x*4 + gq; int b = blockIdx.y;
  float s = 0.f;
  const float* gr = gnm + (size_t)g*500;
  const float* fb = fin + (size_t)b*500*64 + e;
  for (int n=0;n<500;++n) s += gr[n] * fb[(size_t)n*64];
  out[(size_t)b*32000 + (size_t)e*500 + g] = s;
}

// ---------------- launch ----------------
extern "C" void kernel_launch(void* const* d_in, const int* in_sizes, int n_in,
                              void* d_out, int out_size, void* d_ws, size_t ws_size,
                              hipStream_t stream) {
  const float* adj   = (const float*)d_in[0];
  const float* x     = (const float*)d_in[1];
  const float* gnm   = (const float*)d_in[2];
  const float* ttime = (const float*)d_in[3];
  const float* emb   = (const float*)d_in[4];
  const float* wp0   = (const float*)d_in[5];
  const float* bp0   = (const float*)d_in[6];
  const float* a0f1w = (const float*)d_in[7];
  const float* a0f1b = (const float*)d_in[8];
  const float* a0f2w = (const float*)d_in[9];
  const float* a0f2b = (const float*)d_in[10];
  const float* wp1   = (const float*)d_in[11];
  const float* bp1   = (const float*)d_in[12];
  const float* a1f1w = (const float*)d_in[13];
  const float* a1f1b = (const float*)d_in[14];
  const float* a1f2w = (const float*)d_in[15];
  const float* a1f2b = (const float*)d_in[16];
  const float* bn0g  = (const float*)d_in[17];
  const float* bn0b  = (const float*)d_in[18];
  const float* bn1g  = (const float*)d_in[19];
  const float* bn1b  = (const float*)d_in[20];
  const float* wih   = (const float*)d_in[21];
  const float* whh   = (const float*)d_in[22];
  const float* bih   = (const float*)d_in[23];
  const float* bhh   = (const float*)d_in[24];
  const float* bgg   = (const float*)d_in[25];
  const float* bgb   = (const float*)d_in[26];
  const float* cqw   = (const float*)d_in[27];
  const float* cqb   = (const float*)d_in[28];
  const float* ckw   = (const float*)d_in[29];
  const float* ckb   = (const float*)d_in[30];
  const float* vw    = (const float*)d_in[31];
  const float* vb    = (const float*)d_in[32];
  const float* ow    = (const float*)d_in[33];
  const float* ob    = (const float*)d_in[34];
  const float* r1w   = (const float*)d_in[35];
  const float* r1b   = (const float*)d_in[36];
  const float* fcw   = (const float*)d_in[37];
  const float* fcb   = (const float*)d_in[38];
  const float* rcw   = (const float*)d_in[39];
  const float* rcb   = (const float*)d_in[40];
  const float* r2w   = (const float*)d_in[41];
  const float* r2b   = (const float*)d_in[42];
  const float* bnrg  = (const float*)d_in[43];
  const float* bnrb  = (const float*)d_in[44];
  const float* te1w  = (const float*)d_in[45];
  const float* te1b  = (const float*)d_in[46];
  const float* te2w  = (const float*)d_in[47];
  const float* te2b  = (const float*)d_in[48];
  const float* finw  = (const float*)d_in[49];
  const float* finb  = (const float*)d_in[50];
  float* dout = (float*)d_out;
  float* W = (float*)d_ws;

  size_t off = 0;
  auto alloc = [&](size_t n){ size_t r = off; off += (n + 255) & ~(size_t)255; return r; };
  size_t oStats = alloc(256);
  size_t oPool  = alloc(24576);
  size_t oAmix  = alloc(1536);
  size_t oTe    = alloc(1024);
  size_t oO2f   = alloc(512000);
  size_t oRbar  = alloc(512000);
  size_t oRes   = alloc(512000);
  size_t oFin   = alloc(256000);
  size_t oNe0   = alloc(768000);
  size_t oNe1   = alloc(768000);
  size_t oS2    = alloc(125000);    // bf16 [500][500]
  size_t oR1    = alloc(12288000);  // out0 -> out2 -> Qbf+Kbf
  size_t oR2    = alloc(12288000);  // XG pairs -> hs
  size_t oR4    = alloc(6144000);   // Xn bf16 -> Y0bf -> out1 bf16 -> Vbf
  (void)n_in; (void)in_sizes; (void)out_size;
  if (ws_size < off * sizeof(float)) return;

  float* stats = W + oStats;
  float* pooled= W + oPool;
  float* amix  = W + oAmix;
  float* teb   = W + oTe;
  float* out2f = W + oO2f;
  float* rbar  = W + oRbar;
  float* resout= W + oRes;
  float* fin   = W + oFin;
  float* ne0   = W + oNe0;
  float* ne1   = W + oNe1;
  ushort_t* S2bf = (ushort_t*)(W + oS2);
  float* out0  = W + oR1;
  float* out2  = W + oR1;
  ushort_t* Qbf  = (ushort_t*)(W + oR1);             // after out2 dead
  ushort_t* Kbf  = Qbf + 12288000;
  ushort_t* XG1n = (ushort_t*)(W + oR2);             // [500][12288]
  ushort_t* XG2n = XG1n + 6144000;
  ushort_t* XGB1 = (ushort_t*)(W + oR2);             // [500][24576]
  ushort_t* XGB2 = XGB1 + 12288000;
  float* hs    = W + oR2;
  ushort_t* Xnbf = (ushort_t*)(W + oR4);             // [500][12288]
  ushort_t* Y0bf = (ushort_t*)(W + oR4);             // [500][24576]
  ushort_t* out1 = (ushort_t*)(W + oR4);             // [96000][128]
  ushort_t* Vbf  = (ushort_t*)(W + oR4);             // after out1 dead

  // ---- Phase A ----
  k_transpose_bf<<<dim3(16,384), dim3(32,8), 0, stream>>>(x, Xnbf, 12288, 500);
  gemm_mfma<true><<<dim3(4,4), 256, 0, stream>>>(
      AgF32{adj,500}, BgF32{adj,500}, EpS2{}, (void*)S2bf, 500, 500, 500, 500);
  gemm_mfma<true><<<dim3(96,4), 256, 0, stream>>>(
      AgF32{adj,500}, BgBf16p{Xnbf,12288}, EpNone{}, (void*)XG1n, 500, 12288, 500, 12288);
  gemm_mfma<true><<<dim3(96,4), 256, 0, stream>>>(
      AgBf16p{S2bf,500}, BgBf16p{Xnbf,12288}, EpNone{}, (void*)XG2n, 500, 12288, 500, 12288);
  k_pool0<<<192, 64, 0, stream>>>(x, pooled);
  k_mlp<<<1, 192, 0, stream>>>(pooled, 64, a0f1w, a0f1b, a0f2w, a0f2b, amix);
  k_ne<<<3000, 256, 0, stream>>>(amix, emb, ne0);
  gemm_mfma<false><<<dim3(1,750), 256, 0, stream>>>(
      AgFlex0{Xnbf, XG1n, XG2n, ne0}, BgF32{wp0,128}, EpNeBias{ne0, bp0},
      (void*)out0, 96000, 128, 1536, 128);
  hipMemsetAsync((void*)stats, 0, 256*sizeof(float), stream);
  k_bn_stats<<<192, 256, 0, stream>>>(out0, stats, 96000);
  k_bn_apply<<<48000, 256, 0, stream>>>(out0, out0, stats, bn0g, bn0b, 12288000, 1.f/96000.f, 1, 0);

  // ---- Phase B ----
  k_pool1<<<192, 128, 0, stream>>>(out0, pooled);
  k_mlp<<<1, 192, 0, stream>>>(pooled, 128, a1f1w, a1f1b, a1f2w, a1f2b, amix);
  k_ne<<<3000, 256, 0, stream>>>(amix, emb, ne1);
  k_copyY_bf<<<48000, 256, 0, stream>>>(out0, Y0bf);
  gemm_mfma<true><<<dim3(192,4), 256, 0, stream>>>(
      AgF32{adj,500}, BgBf16p{Y0bf,24576}, EpNone{}, (void*)XGB1, 500, 24576, 500, 24576);
  gemm_mfma<true><<<dim3(192,4), 256, 0, stream>>>(
      AgBf16p{S2bf,500}, BgBf16p{Y0bf,24576}, EpNone{}, (void*)XGB2, 500, 24576, 500, 24576);
  gemm_mfma<true><<<dim3(1,750), 256, 0, stream>>>(
      AgFlex1{out0, XGB1, XGB2, ne1}, BgF32{wp1,128}, EpNeBias{ne1, bp1},
      (void*)out1, 96000, 128, 3072, 128);
  hipMemsetAsync((void*)stats, 0, 256*sizeof(float), stream);
  k_bn_stats_bf<<<192, 256, 0, stream>>>(out1, stats, 96000);
  gemm_mfma<false><<<dim3(1,750), 256, 0, stream>>>(
      AgXrow{x}, BgT{r1w,64}, EpRes1{out1, stats, bn1g, bn1b, r1b, 1.f/96000.f},
      (void*)out2, 96000, 128, 64, 128);

  // ---- Phase C: fused gi+GRU ----
  k_gru2<<<500, 384, 0, stream>>>(out2, wih, whh, bih, bhh, hs);
  hipMemsetAsync((void*)stats, 0, 256*sizeof(float), stream);
  k_bn_stats<<<192, 256, 0, stream>>>(hs, stats, 96000);
  k_bn_apply<<<48000, 256, 0, stream>>>(hs, hs, stats, bgg, bgb, 12288000, 1.f/96000.f, 1, 0);

  // ---- Phase E-part1 (consumes out2, freeing R1 for Q/K) ----
  k_rbar<<<2000, 256, 0, stream>>>(out2, rcw, rbar);
  gemm_mfma<false><<<dim3(1,32), 256, 0, stream>>>(
      AgF32{rbar,128}, BgT{r2w,128}, EpRes2{r2b, rcw, rcb}, (void*)resout, 4000, 128, 128, 128);
  hipMemsetAsync((void*)stats, 0, 256*sizeof(float), stream);
  k_bn_stats<<<8, 256, 0, stream>>>(resout, stats, 4000);

  // ---- Phase D: conv-QKV via MFMA GEMMs + light attention ----
  gemm_mfma<true><<<dim3(1,750), 256, 0, stream>>>(
      AgConv{hs}, BgConvW{cqw}, EpBias{cqb}, (void*)Qbf, 96000, 128, 384, 128);
  gemm_mfma<true><<<dim3(1,750), 256, 0, stream>>>(
      AgConv{hs}, BgConvW{ckw}, EpBias{ckb}, (void*)Kbf, 96000, 128, 384, 128);
  gemm_mfma<true><<<dim3(1,750), 256, 0, stream>>>(
      AgF32{hs,128}, BgT{vw,128}, EpBias{vb}, (void*)Vbf, 96000, 128, 128, 128);
  k_attn3<<<4000, 256, 0, stream>>>(Qbf, Kbf, Vbf, ow, ob, fcw, fcb, out2f);

  // ---- Phase E-part2 ----
  k_bn_apply<<<2000, 256, 0, stream>>>(out2f, resout, stats, bnrg, bnrb, 512000, 1.f/4000.f, 0, 1);
  k_te<<<8, 128, 0, stream>>>(ttime, te1w, te1b, te2w, te2b, teb);
  gemm_mfma<false><<<dim3(1,32), 256, 0, stream>>>(
      AgTeAdd{out2f, teb}, BgT{finw,128}, EpBias{finb}, (void*)fin, 4000, 64, 128, 64);
  k_grid<<<dim3(125,8), 256, 0, stream>>>(gnm, fin, dout);
}

// Round 7
// 3817.828 us; speedup vs baseline: 2.8819x; 1.1416x over previous
//
#include <hip/hip_runtime.h>
#include <math.h>

using short8 = __attribute__((ext_vector_type(8))) short;
using f32x4  = __attribute__((ext_vector_type(4))) float;
using ushort_t = unsigned short;

__device__ __forceinline__ ushort_t f2b(float f){
  unsigned int u = __builtin_bit_cast(unsigned int, f);
  u = (u + 0x7fffu + ((u >> 16) & 1u)) >> 16;
  return (ushort_t)u;
}
__device__ __forceinline__ float b2f(ushort_t u){
  unsigned int v = ((unsigned int)u) << 16;
  return __builtin_bit_cast(float, v);
}

// ---------------- generator functors ----------------
struct AgF32 { const float* A; int lda;
  __device__ float operator()(int r, int k) const { return A[(size_t)r*lda + k]; } };
struct AgBf16p { const ushort_t* A; int lda;
  __device__ float operator()(int r, int k) const { return b2f(A[(size_t)r*lda + k]); } };
struct AgXrow { const float* x;  // row=bt*500+n, k=c : x[bt,c,n]
  __device__ float operator()(int r, int k) const {
    int bt = r/500, n = r - bt*500;
    return x[(size_t)bt*32000 + (size_t)k*500 + n]; } };
struct AgFlex0 { const ushort_t* Xn; const ushort_t* XG1; const ushort_t* XG2; const float* ne;
  __device__ float operator()(int r, int kp) const {
    int d = kp / 192; int kc = kp - d*192; int k = kc >> 6; int c = kc & 63;
    int bt = r/500, n = r - bt*500;
    const ushort_t* s = (k==0)? Xn : (k==1)? XG1 : XG2;
    float v = b2f(s[(size_t)n*12288 + bt*64 + c]);
    return ne[(size_t)r*8 + d] * v; } };
struct AgFlex1 { const float* s0; const ushort_t* XG1; const ushort_t* XG2; const float* ne;
  __device__ float operator()(int r, int kp) const {
    int d = kp / 384; int kc = kp - d*384; int k = kc >> 7; int c = kc & 127;
    int bt = r/500, n = r - bt*500;
    float v = (k==0) ? s0[(size_t)r*128 + c]
                     : b2f(((k==1)?XG1:XG2)[(size_t)n*24576 + bt*128 + c]);
    return ne[(size_t)r*8 + d] * v; } };
struct AgConv { const float* hs; // rows bn*24+t, k = dt*128+c, pad over t
  __device__ float operator()(int r, int k) const {
    int t = r % 24; int dt = k >> 7; int c = k & 127; int t2 = t + dt - 1;
    if (t2 < 0 || t2 >= 24) return 0.f;
    return hs[(size_t)(r + (t2 - t))*128 + c]; } };
struct AgTeAdd { const float* o2f; const float* te;
  __device__ float operator()(int r, int k) const {
    return o2f[(size_t)r*128 + k] + te[(size_t)(r/500)*128 + k]; } };

struct BgF32 { const float* Bp; int ldb;
  __device__ float operator()(int k, int c) const { return Bp[(size_t)k*ldb + c]; } };
struct BgBf16p { const ushort_t* Bp; int ldb;
  __device__ float operator()(int k, int c) const { return b2f(Bp[(size_t)k*ldb + c]); } };
struct BgT { const float* W; int ld;   // weight [O,I] -> B[k][o]=W[o][k]
  __device__ float operator()(int k, int c) const { return W[(size_t)c*ld + k]; } };
struct BgConvW { const float* w;       // w[o,c,0,dt], k = dt*128+c
  __device__ float operator()(int k, int c) const {
    int dt = k >> 7; int cc = k & 127;
    return w[((size_t)c*128 + cc)*3 + dt]; } };

struct EpNone { __device__ float operator()(int, int, float a) const { return a; } };
struct EpS2   { __device__ float operator()(int r, int c, float a) const { return 2.f*a - (r==c ? 1.f : 0.f); } };
struct EpBias { const float* b;
  __device__ float operator()(int, int c, float a) const { return a + b[c]; } };
struct EpNeBias { const float* ne; const float* bp;
  __device__ float operator()(int r, int c, float a) const {
    float s = a;
    #pragma unroll
    for (int d=0; d<8; ++d) s += ne[(size_t)r*8 + d]*bp[d*128 + c];
    return s; } };
struct EpRes1 { const ushort_t* out1; const float* st; const float *g, *bb, *rb; float invM;
  __device__ float operator()(int r, int c, float a) const {
    float mean = st[c]*invM; float var = st[128+c]*invM - mean*mean;
    float rstd = rsqrtf(var + 1e-5f);
    float y = (b2f(out1[(size_t)r*128 + c]) - mean)*rstd*g[c] + bb[c];
    y = fmaxf(y, 0.f);
    return a + rb[c] + y; } };
struct EpRes2 { const float *r2b, *rw, *rcb;
  __device__ float operator()(int, int c, float a) const {
    float s = 0.f;
    #pragma unroll
    for (int t=0; t<24; ++t) s += rw[t];
    return a + s*r2b[c] + rcb[0]; } };

// ---------------- pipelined MFMA generator GEMM ----------------
template<bool BOUT, class AG, class BG, class EP>
__global__ __launch_bounds__(256)
void gemm_mfma(AG ag, BG bg, EP ep, void* Cv, int M, int N, int K, int ldc) {
  constexpr int BM=128, BN=128, BK=32;
  constexpr int LDA = BK + 8;
  __shared__ ushort_t As[BM*LDA];
  __shared__ ushort_t Bs[BN*LDA];
  int tid = threadIdx.x;
  int lane = tid & 63, wave = tid >> 6;
  int wr = (wave >> 1) * 64, wc = (wave & 1) * 64;
  int q = lane >> 4, r16 = lane & 15;
  int row0 = blockIdx.y*BM, col0 = blockIdx.x*BN;
  int am = tid >> 3, ak = (tid & 7) * 4;
  int bn = tid & 127, bk = (tid >> 7) * 4;
  float ra[4][4], rb[4][4];
  int nK = (K + BK - 1) / BK;
  #pragma unroll
  for (int s=0;s<4;++s){
    int gr = row0 + am + 32*s;
    #pragma unroll
    for (int v=0;v<4;++v){ int gk = ak + v;
      ra[s][v] = (gr < M && gk < K) ? ag(gr, gk) : 0.f; }
    int gc = col0 + bn;
    #pragma unroll
    for (int v=0;v<4;++v){ int gk = bk + 8*s + v;
      rb[s][v] = (gc < N && gk < K) ? bg(gk, gc) : 0.f; }
  }
  f32x4 acc[4][4] = {};
  for (int t=0; t<nK; ++t) {
    #pragma unroll
    for (int s=0;s<4;++s){
      uint2 pa; pa.x = (unsigned)f2b(ra[s][0]) | ((unsigned)f2b(ra[s][1])<<16);
      pa.y = (unsigned)f2b(ra[s][2]) | ((unsigned)f2b(ra[s][3])<<16);
      *(uint2*)&As[(am + 32*s)*LDA + ak] = pa;
      uint2 pb; pb.x = (unsigned)f2b(rb[s][0]) | ((unsigned)f2b(rb[s][1])<<16);
      pb.y = (unsigned)f2b(rb[s][2]) | ((unsigned)f2b(rb[s][3])<<16);
      *(uint2*)&Bs[bn*LDA + bk + 8*s] = pb;
    }
    __syncthreads();
    if (t+1 < nK) {
      int k0 = (t+1)*BK;
      #pragma unroll
      for (int s=0;s<4;++s){
        int gr = row0 + am + 32*s;
        #pragma unroll
        for (int v=0;v<4;++v){ int gk = k0 + ak + v;
          ra[s][v] = (gr < M && gk < K) ? ag(gr, gk) : 0.f; }
        int gc = col0 + bn;
        #pragma unroll
        for (int v=0;v<4;++v){ int gk = k0 + bk + 8*s + v;
          rb[s][v] = (gc < N && gk < K) ? bg(gk, gc) : 0.f; }
      }
    }
    short8 a[4], b[4];
    #pragma unroll
    for (int it=0;it<4;++it) a[it] = *(const short8*)&As[(wr + it*16 + r16)*LDA + q*8];
    #pragma unroll
    for (int jt=0;jt<4;++jt) b[jt] = *(const short8*)&Bs[(wc + jt*16 + r16)*LDA + q*8];
    #pragma unroll
    for (int it=0;it<4;++it)
      #pragma unroll
      for (int jt=0;jt<4;++jt)
        acc[it][jt] = __builtin_amdgcn_mfma_f32_16x16x32_bf16(a[it], b[jt], acc[it][jt], 0, 0, 0);
    __syncthreads();
  }
  #pragma unroll
  for (int it=0;it<4;++it) {
    #pragma unroll
    for (int v=0;v<4;++v) {
      int rr = row0 + wr + it*16 + q*4 + v;
      if (rr >= M) continue;
      #pragma unroll
      for (int jt=0;jt<4;++jt) {
        int c = col0 + wc + jt*16 + r16;
        if (c >= N) continue;
        float val = ep(rr, c, acc[it][jt][v]);
        if (BOUT) ((ushort_t*)Cv)[(size_t)rr*ldc + c] = f2b(val);
        else      ((float*)Cv)[(size_t)rr*ldc + c] = val;
      }
    }
  }
}

// ---------------- small kernels ----------------
__global__ void k_transpose_bf(const float* src, ushort_t* dst, int R, int Cc) {
  __shared__ float tile[32][33];
  int c0 = blockIdx.x*32, r0 = blockIdx.y*32;
  int tx = threadIdx.x, ty = threadIdx.y;
  for (int i = ty; i < 32; i += 8) {
    int r = r0+i, c = c0+tx;
    if (r < R && c < Cc) tile[i][tx] = src[(size_t)r*Cc + c];
  }
  __syncthreads();
  for (int i = ty; i < 32; i += 8) {
    int dr = c0 + i, dc = r0 + tx;
    if (dr < Cc && dc < R) dst[(size_t)dr*R + dc] = f2b(tile[tx][i]);
  }
}

__global__ void k_copyY_bf(const float* out0, ushort_t* Y) {
  int i = blockIdx.x*256 + threadIdx.x;
  if (i >= 12288000) return;
  int o = i & 127; int r = i >> 7; int btl = r % 192; int n = r / 192;
  Y[i] = f2b(out0[((size_t)btl*500 + n)*128 + o]);
}

__global__ void k_pool0(const float* x, float* pooled) {
  int bt = blockIdx.x; int c = threadIdx.x;
  const float* p = x + (size_t)bt*32000 + (size_t)c*500;
  float s = 0.f;
  for (int n=0;n<500;++n) s += p[n];
  pooled[bt*64 + c] = s*(1.f/500.f);
}
__global__ void k_pool1(const float* src, float* pooled) {
  int bt = blockIdx.x; int o = threadIdx.x;
  float s = 0.f;
  for (int n=0;n<500;++n) s += src[((size_t)bt*500 + n)*128 + o];
  pooled[bt*128 + o] = s*(1.f/500.f);
}

__global__ void k_mlp(const float* pooled, int F, const float* f1w, const float* f1b,
                      const float* f2w, const float* f2b, float* aout) {
  int bt = threadIdx.x;
  if (bt >= 192) return;
  float h[8];
  for (int k=0;k<8;++k){
    float s = f1b[k];
    for (int c=0;c<F;++c) s += pooled[bt*F + c]*f1w[k*F + c];
    h[k] = fmaxf(s, 0.f);
  }
  float z[8]; float m = -1e30f;
  for (int k2=0;k2<8;++k2){
    float s = f2b[k2];
    for (int k=0;k<8;++k) s += h[k]*f2w[k2*8 + k];
    z[k2] = s; m = fmaxf(m, s);
  }
  float den = 0.f;
  for (int k2=0;k2<8;++k2){ z[k2] = expf(z[k2]-m); den += z[k2]; }
  float inv = 1.f/den;
  for (int k2=0;k2<8;++k2) aout[bt*8 + k2] = z[k2]*inv;
}

__global__ void k_ne(const float* a, const float* emb, float* ne) {
  int i = blockIdx.x*256 + threadIdx.x;
  if (i >= 768000) return;
  int d = i & 7; int rem = i >> 3; int n = rem % 500; int bt = rem / 500;
  float s = 0.f;
  #pragma unroll
  for (int k=0;k<8;++k) s += a[bt*8 + k]*emb[((size_t)k*500 + n)*8 + d];
  ne[i] = s;
}

__global__ void k_bn_stats(const float* src, float* stats, int M, int rpb) {
  int col = threadIdx.x & 127; int seg = threadIdx.x >> 7;
  int r0 = blockIdx.x * rpb; int r1 = r0 + rpb; if (r1 > M) r1 = M;
  float s = 0.f, q = 0.f;
  for (int r = r0 + seg; r < r1; r += 2) {
    float v = src[(size_t)r*128 + col];
    s += v; q += v*v;
  }
  atomicAdd(&stats[col], s);
  atomicAdd(&stats[128+col], q);
}
__global__ void k_bn_stats_bf(const ushort_t* src, float* stats, int M, int rpb) {
  int col = threadIdx.x & 127; int seg = threadIdx.x >> 7;
  int r0 = blockIdx.x * rpb; int r1 = r0 + rpb; if (r1 > M) r1 = M;
  float s = 0.f, q = 0.f;
  for (int r = r0 + seg; r < r1; r += 2) {
    float v = b2f(src[(size_t)r*128 + col]);
    s += v; q += v*v;
  }
  atomicAdd(&stats[col], s);
  atomicAdd(&stats[128+col], q);
}

__global__ void k_bn_apply(float* dst, const float* src, const float* st,
                           const float* g, const float* b, int total, float invM, int relu, int addd) {
  int i = blockIdx.x*256 + threadIdx.x;
  if (i >= total) return;
  int c = i & 127;
  float mean = st[c]*invM; float var = st[128+c]*invM - mean*mean;
  float rstd = rsqrtf(var + 1e-5f);
  float y = (src[i]-mean)*rstd*g[c] + b[c];
  if (relu) y = fmaxf(y, 0.f);
  dst[i] = addd ? dst[i] + y : y;
}

// recurrent-only GRU: gi precomputed (bf16); 500 blocks x 8 bn
__global__ __launch_bounds__(384) void k_gru3(const ushort_t* gi, const float* whh,
    const float* bhh, float* hs) {
  __shared__ float h[8][132];
  __shared__ float uh[8][388];
  int tid = threadIdx.x;
  int bn0 = blockIdx.x*8;
  for (int i=tid;i<1024;i+=384) h[i>>7][i&127] = 0.f;
  __syncthreads();
  int j = tid;
  float bh = bhh[j];
  const float* wh = whh + (size_t)j*128;
  for (int t=0;t<24;++t) {
    float ah[8];
    #pragma unroll
    for (int r=0;r<8;++r) ah[r]=bh;
    for (int c=0;c<128;c+=4){
      float4 w4h = *(const float4*)&wh[c];
      #pragma unroll
      for (int r=0;r<8;++r){
        float4 hv = *(const float4*)&h[r][c];
        ah[r] += hv.x*w4h.x + hv.y*w4h.y + hv.z*w4h.z + hv.w*w4h.w;
      }
    }
    #pragma unroll
    for (int r=0;r<8;++r) uh[r][j]=ah[r];
    __syncthreads();
    for (int i=tid;i<1024;i+=384){
      int r=i>>7, u=i&127;
      int bnn = bn0 + r; int b = bnn/500, n = bnn - b*500;
      size_t gbase = ((size_t)(b*24 + t)*500 + n)*384;
      float ir=b2f(gi[gbase+u]), iz=b2f(gi[gbase+128+u]), inn=b2f(gi[gbase+256+u]);
      float hr=uh[r][u], hz=uh[r][128+u], hn=uh[r][256+u];
      float rg = 1.f/(1.f+expf(-(ir+hr)));
      float zg = 1.f/(1.f+expf(-(iz+hz)));
      float ng = tanhf(inn + rg*hn);
      float hnew = (1.f-zg)*ng + zg*h[r][u];
      h[r][u] = hnew;
      hs[((size_t)bnn*24 + t)*128 + u] = hnew;
    }
    __syncthreads();
  }
}

// attention-only: QK^T, softmax, PV, fc, ow  (Q/K/V bf16 from GEMMs)
__global__ __launch_bounds__(256) void k_attn3(const ushort_t* Q, const ushort_t* K, const ushort_t* V,
    const float* ow, const float* ob, const float* fcw, const float* fcb, float* out2f) {
  __shared__ float Qs[24][133];
  __shared__ float Ks[24][133];
  __shared__ float Vs[24][133];
  __shared__ float Sc[8][24][25];
  __shared__ float xbar[128];
  int bn = blockIdx.x; int tid = threadIdx.x;
  size_t base = (size_t)bn*3072;
  for (int i=tid;i<3072;i+=256){
    int t=i>>7, c=i&127;
    Qs[t][c]=b2f(Q[base+i]); Ks[t][c]=b2f(K[base+i]); Vs[t][c]=b2f(V[base+i]);
  }
  __syncthreads();
  for (int i=tid;i<4608;i+=256){
    int hh = i/576; int r = i - hh*576; int t = r/24; int s_ = r - t*24;
    float d = 0.f;
    #pragma unroll
    for (int dd=0;dd<16;++dd) d += Qs[t][hh*16+dd]*Ks[s_][hh*16+dd];
    Sc[hh][t][s_] = d*0.25f;
  }
  __syncthreads();
  if (tid < 192) {
    int hh = tid/24, t = tid - (tid/24)*24;
    float m = -1e30f;
    for (int s_=0;s_<24;++s_) m = fmaxf(m, Sc[hh][t][s_]);
    float den = 0.f;
    for (int s_=0;s_<24;++s_){ float e = expf(Sc[hh][t][s_]-m); Sc[hh][t][s_] = e; den += e; }
    float inv = 1.f/den;
    for (int s_=0;s_<24;++s_) Sc[hh][t][s_] *= inv;
  }
  __syncthreads();
  for (int i=tid;i<3072;i+=256){
    int t = i >> 7; int o = i & 127; int hh = o >> 4;
    float s = 0.f;
    #pragma unroll
    for (int s_=0;s_<24;++s_) s += Sc[hh][t][s_]*Vs[s_][o];
    Qs[t][o] = s;
  }
  __syncthreads();
  if (tid < 128) {
    float s = 0.f;
    for (int t=0;t<24;++t) s += fcw[t]*Qs[t][tid];
    xbar[tid] = s;
  }
  __syncthreads();
  if (tid < 128) {
    int o = tid;
    float s = 0.f;
    for (int c=0;c<128;++c) s += xbar[c]*ow[o*128 + c];
    float sfc = 0.f;
    for (int t=0;t<24;++t) sfc += fcw[t];
    out2f[(size_t)bn*128 + o] = s + sfc*ob[o] + fcb[0];
  }
}

__global__ void k_rbar(const float* out2, const float* rw, float* rbar) {
  int i = blockIdx.x*256 + threadIdx.x;
  if (i >= 512000) return;
  int c = i & 127; int bnn = i >> 7; int b = bnn/500, n = bnn - b*500;
  float s = 0.f;
  #pragma unroll
  for (int t=0;t<24;++t) s += rw[t] * out2[((size_t)(b*24 + t)*500 + n)*128 + c];
  rbar[i] = s;
}

__global__ void k_te(const float* tt, const float* w1, const float* b1,
                     const float* w2, const float* b2, float* te) {
  __shared__ float h1[128];
  int b = blockIdx.x; int o = threadIdx.x;
  float s = b1[o];
  for (int c=0;c<32;++c) s += tt[b*32 + c]*w1[o*32 + c];
  h1[o] = fmaxf(s, 0.f);
  __syncthreads();
  float s2 = b2[o];
  for (int c=0;c<128;++c) s2 += h1[c]*w2[o*128 + c];
  te[b*128 + o] = s2;
}

__global__ void k_grid(const float* gnm, const float* fin, float* out) {
  int e = threadIdx.x & 63; int gq = threadIdx.x >> 6;
  int g = blockIdx.x*4 + gq; int b = blockIdx.y;
  float s = 0.f;
  const float* gr = gnm + (size_t)g*500;
  const float* fb = fin + (size_t)b*500*64 + e;
  for (int n=0;n<500;++n) s += gr[n] * fb[(size_t)n*64];
  out[(size_t)b*32000 + (size_t)e*500 + g] = s;
}

// ---------------- launch ----------------
extern "C" void kernel_launch(void* const* d_in, const int* in_sizes, int n_in,
                              void* d_out, int out_size, void* d_ws, size_t ws_size,
                              hipStream_t stream) {
  const float* adj   = (const float*)d_in[0];
  const float* x     = (const float*)d_in[1];
  const float* gnm   = (const float*)d_in[2];
  const float* ttime = (const float*)d_in[3];
  const float* emb   = (const float*)d_in[4];
  const float* wp0   = (const float*)d_in[5];
  const float* bp0   = (const float*)d_in[6];
  const float* a0f1w = (const float*)d_in[7];
  const float* a0f1b = (const float*)d_in[8];
  const float* a0f2w = (const float*)d_in[9];
  const float* a0f2b = (const float*)d_in[10];
  const float* wp1   = (const float*)d_in[11];
  const float* bp1   = (const float*)d_in[12];
  const float* a1f1w = (const float*)d_in[13];
  const float* a1f1b = (const float*)d_in[14];
  const float* a1f2w = (const float*)d_in[15];
  const float* a1f2b = (const float*)d_in[16];
  const float* bn0g  = (const float*)d_in[17];
  const float* bn0b  = (const float*)d_in[18];
  const float* bn1g  = (const float*)d_in[19];
  const float* bn1b  = (const float*)d_in[20];
  const float* wih   = (const float*)d_in[21];
  const float* whh   = (const float*)d_in[22];
  const float* bih   = (const float*)d_in[23];
  const float* bhh   = (const float*)d_in[24];
  const float* bgg   = (const float*)d_in[25];
  const float* bgb   = (const float*)d_in[26];
  const float* cqw   = (const float*)d_in[27];
  const float* cqb   = (const float*)d_in[28];
  const float* ckw   = (const float*)d_in[29];
  const float* ckb   = (const float*)d_in[30];
  const float* vw    = (const float*)d_in[31];
  const float* vb    = (const float*)d_in[32];
  const float* ow    = (const float*)d_in[33];
  const float* ob    = (const float*)d_in[34];
  const float* r1w   = (const float*)d_in[35];
  const float* r1b   = (const float*)d_in[36];
  const float* fcw   = (const float*)d_in[37];
  const float* fcb   = (const float*)d_in[38];
  const float* rcw   = (const float*)d_in[39];
  const float* rcb   = (const float*)d_in[40];
  const float* r2w   = (const float*)d_in[41];
  const float* r2b   = (const float*)d_in[42];
  const float* bnrg  = (const float*)d_in[43];
  const float* bnrb  = (const float*)d_in[44];
  const float* te1w  = (const float*)d_in[45];
  const float* te1b  = (const float*)d_in[46];
  const float* te2w  = (const float*)d_in[47];
  const float* te2b  = (const float*)d_in[48];
  const float* finw  = (const float*)d_in[49];
  const float* finb  = (const float*)d_in[50];
  float* dout = (float*)d_out;
  float* W = (float*)d_ws;

  size_t off = 0;
  auto alloc = [&](size_t n){ size_t r = off; off += (n + 255) & ~(size_t)255; return r; };
  size_t oStats = alloc(256);
  size_t oPool  = alloc(24576);
  size_t oAmix  = alloc(1536);
  size_t oTe    = alloc(1024);
  size_t oO2f   = alloc(512000);
  size_t oRbar  = alloc(512000);
  size_t oRes   = alloc(512000);
  size_t oFin   = alloc(256000);
  size_t oNe0   = alloc(768000);
  size_t oNe1   = alloc(768000);
  size_t oS2    = alloc(125000);    // bf16 [500][500]
  size_t oR1    = alloc(12288000);  // out0 -> out2 -> hs
  size_t oR2    = alloc(12288000);  // XG pairs -> gi(low) -> Q,K
  size_t oR4    = alloc(6144000);   // Xn -> Y0bf -> out1 -> gi(high) -> V
  (void)n_in; (void)in_sizes; (void)out_size;
  if (ws_size < off * sizeof(float)) return;

  float* stats = W + oStats;
  float* pooled= W + oPool;
  float* amix  = W + oAmix;
  float* teb   = W + oTe;
  float* out2f = W + oO2f;
  float* rbar  = W + oRbar;
  float* resout= W + oRes;
  float* fin   = W + oFin;
  float* ne0   = W + oNe0;
  float* ne1   = W + oNe1;
  ushort_t* S2bf = (ushort_t*)(W + oS2);
  float* out0  = W + oR1;
  float* out2  = W + oR1;
  float* hs    = W + oR1;                             // after out2 dead
  ushort_t* XG1n = (ushort_t*)(W + oR2);              // [500][12288]
  ushort_t* XG2n = XG1n + 6144000;
  ushort_t* XGB1 = (ushort_t*)(W + oR2);              // [500][24576]
  ushort_t* XGB2 = XGB1 + 12288000;
  ushort_t* gi16 = (ushort_t*)(W + oR2);              // [96000][384] spans R2+R4
  ushort_t* Qbf  = (ushort_t*)(W + oR2);              // after gi dead
  ushort_t* Kbf  = Qbf + 12288000;
  ushort_t* Vbf  = Kbf + 12288000;
  ushort_t* Xnbf = (ushort_t*)(W + oR4);              // [500][12288]
  ushort_t* Y0bf = (ushort_t*)(W + oR4);              // [500][24576]
  ushort_t* out1 = (ushort_t*)(W + oR4);              // [96000][128]

  // ---- Phase A ----
  k_transpose_bf<<<dim3(16,384), dim3(32,8), 0, stream>>>(x, Xnbf, 12288, 500);
  gemm_mfma<true><<<dim3(4,4), 256, 0, stream>>>(
      AgF32{adj,500}, BgF32{adj,500}, EpS2{}, (void*)S2bf, 500, 500, 500, 500);
  gemm_mfma<true><<<dim3(96,4), 256, 0, stream>>>(
      AgF32{adj,500}, BgBf16p{Xnbf,12288}, EpNone{}, (void*)XG1n, 500, 12288, 500, 12288);
  gemm_mfma<true><<<dim3(96,4), 256, 0, stream>>>(
      AgBf16p{S2bf,500}, BgBf16p{Xnbf,12288}, EpNone{}, (void*)XG2n, 500, 12288, 500, 12288);
  k_pool0<<<192, 64, 0, stream>>>(x, pooled);
  k_mlp<<<1, 192, 0, stream>>>(pooled, 64, a0f1w, a0f1b, a0f2w, a0f2b, amix);
  k_ne<<<3000, 256, 0, stream>>>(amix, emb, ne0);
  gemm_mfma<false><<<dim3(1,750), 256, 0, stream>>>(
      AgFlex0{Xnbf, XG1n, XG2n, ne0}, BgF32{wp0,128}, EpNeBias{ne0, bp0},
      (void*)out0, 96000, 128, 1536, 128);
  hipMemsetAsync((void*)stats, 0, 256*sizeof(float), stream);
  k_bn_stats<<<768, 256, 0, stream>>>(out0, stats, 96000, 125);
  k_bn_apply<<<48000, 256, 0, stream>>>(out0, out0, stats, bn0g, bn0b, 12288000, 1.f/96000.f, 1, 0);

  // ---- Phase B ----
  k_pool1<<<192, 128, 0, stream>>>(out0, pooled);
  k_mlp<<<1, 192, 0, stream>>>(pooled, 128, a1f1w, a1f1b, a1f2w, a1f2b, amix);
  k_ne<<<3000, 256, 0, stream>>>(amix, emb, ne1);
  k_copyY_bf<<<48000, 256, 0, stream>>>(out0, Y0bf);
  gemm_mfma<true><<<dim3(192,4), 256, 0, stream>>>(
      AgF32{adj,500}, BgBf16p{Y0bf,24576}, EpNone{}, (void*)XGB1, 500, 24576, 500, 24576);
  gemm_mfma<true><<<dim3(192,4), 256, 0, stream>>>(
      AgBf16p{S2bf,500}, BgBf16p{Y0bf,24576}, EpNone{}, (void*)XGB2, 500, 24576, 500, 24576);
  gemm_mfma<true><<<dim3(1,750), 256, 0, stream>>>(
      AgFlex1{out0, XGB1, XGB2, ne1}, BgF32{wp1,128}, EpNeBias{ne1, bp1},
      (void*)out1, 96000, 128, 3072, 128);
  hipMemsetAsync((void*)stats, 0, 256*sizeof(float), stream);
  k_bn_stats_bf<<<768, 256, 0, stream>>>(out1, stats, 96000, 125);
  gemm_mfma<false><<<dim3(1,750), 256, 0, stream>>>(
      AgXrow{x}, BgT{r1w,64}, EpRes1{out1, stats, bn1g, bn1b, r1b, 1.f/96000.f},
      (void*)out2, 96000, 128, 64, 128);

  // ---- Phase E-part1 (only needs out2) ----
  k_rbar<<<2000, 256, 0, stream>>>(out2, rcw, rbar);
  gemm_mfma<false><<<dim3(1,32), 256, 0, stream>>>(
      AgF32{rbar,128}, BgT{r2w,128}, EpRes2{r2b, rcw, rcb}, (void*)resout, 4000, 128, 128, 128);
  hipMemsetAsync((void*)stats, 0, 256*sizeof(float), stream);
  k_bn_stats<<<32, 256, 0, stream>>>(resout, stats, 4000, 125);

  // ---- Phase C: gi on MFMA, then recurrent-only GRU ----
  gemm_mfma<true><<<dim3(3,750), 256, 0, stream>>>(
      AgF32{out2,128}, BgT{wih,128}, EpBias{bih}, (void*)gi16, 96000, 384, 128, 384);
  k_gru3<<<500, 384, 0, stream>>>(gi16, whh, bhh, hs);
  // BN over hs (uses a second stats buffer region to not clobber resout stats)
  hipMemsetAsync((void*)(stats+256), 0, 256*sizeof(float), stream);
  k_bn_stats<<<768, 256, 0, stream>>>(hs, stats+256, 96000, 125);
  k_bn_apply<<<48000, 256, 0, stream>>>(hs, hs, stats+256, bgg, bgb, 12288000, 1.f/96000.f, 1, 0);

  // ---- Phase D: conv-QKV via MFMA GEMMs + light attention ----
  gemm_mfma<true><<<dim3(1,750), 256, 0, stream>>>(
      AgConv{hs}, BgConvW{cqw}, EpBias{cqb}, (void*)Qbf, 96000, 128, 384, 128);
  gemm_mfma<true><<<dim3(1,750), 256, 0, stream>>>(
      AgConv{hs}, BgConvW{ckw}, EpBias{ckb}, (void*)Kbf, 96000, 128, 384, 128);
  gemm_mfma<true><<<dim3(1,750), 256, 0, stream>>>(
      AgF32{hs,128}, BgT{vw,128}, EpBias{vb}, (void*)Vbf, 96000, 128, 128, 128);
  k_attn3<<<4000, 256, 0, stream>>>(Qbf, Kbf, Vbf, ow, ob, fcw, fcb, out2f);

  // ---- Phase E-part2 ----
  k_bn_apply<<<2000, 256, 0, stream>>>(out2f, resout, stats, bnrg, bnrb, 512000, 1.f/4000.f, 0, 1);
  k_te<<<8, 128, 0, stream>>>(ttime, te1w, te1b, te2w, te2b, teb);
  gemm_mfma<false><<<dim3(1,32), 256, 0, stream>>>(
      AgTeAdd{out2f, teb}, BgT{finw,128}, EpBias{finb}, (void*)fin, 4000, 64, 128, 64);
  k_grid<<<dim3(125,8), 256, 0, stream>>>(gnm, fin, dout);
}

// Round 8
// 2782.110 us; speedup vs baseline: 3.9548x; 1.3723x over previous
//
#include <hip/hip_runtime.h>
#include <math.h>

using short8 = __attribute__((ext_vector_type(8))) short;
using f32x4  = __attribute__((ext_vector_type(4))) float;
using ushort_t = unsigned short;

__device__ __forceinline__ ushort_t f2b(float f){
  unsigned int u = __builtin_bit_cast(unsigned int, f);
  u = (u + 0x7fffu + ((u >> 16) & 1u)) >> 16;
  return (ushort_t)u;
}
__device__ __forceinline__ float b2f(ushort_t u){
  unsigned int v = ((unsigned int)u) << 16;
  return __builtin_bit_cast(float, v);
}
__device__ __forceinline__ float4 f4z(){ return float4{0.f,0.f,0.f,0.f}; }

// ---------------- A generators (vector load4 protocol, k aligned to 4) ----------------
struct AgF32 { const float* A; int lda;
  __device__ float4 load4(int r, int k, int K) const {
    if (k+3 < K) return *(const float4*)&A[(size_t)r*lda + k];
    float4 v = f4z();
    if (k   < K) v.x = A[(size_t)r*lda + k];
    if (k+1 < K) v.y = A[(size_t)r*lda + k+1];
    if (k+2 < K) v.z = A[(size_t)r*lda + k+2];
    if (k+3 < K) v.w = A[(size_t)r*lda + k+3];
    return v; } };
struct AgBf16p { const ushort_t* A; int lda;
  __device__ float4 load4(int r, int k, int K) const {
    if (k+3 < K) {
      uint2 p = *(const uint2*)&A[(size_t)r*lda + k];
      return float4{b2f((ushort_t)p.x), b2f((ushort_t)(p.x>>16)),
                    b2f((ushort_t)p.y), b2f((ushort_t)(p.y>>16))};
    }
    float4 v = f4z();
    if (k   < K) v.x = b2f(A[(size_t)r*lda + k]);
    if (k+1 < K) v.y = b2f(A[(size_t)r*lda + k+1]);
    if (k+2 < K) v.z = b2f(A[(size_t)r*lda + k+2]);
    if (k+3 < K) v.w = b2f(A[(size_t)r*lda + k+3]);
    return v; } };
struct AgXrow { const float* x;  // row=bt*500+n, k=c : x[bt,c,n]
  __device__ float4 load4(int r, int k, int K) const {
    int bt = r/500, n = r - bt*500;
    const float* p = x + (size_t)bt*32000 + n;
    float4 v = f4z();
    if (k   < K) v.x = p[(size_t)k*500];
    if (k+1 < K) v.y = p[(size_t)(k+1)*500];
    if (k+2 < K) v.z = p[(size_t)(k+2)*500];
    if (k+3 < K) v.w = p[(size_t)(k+3)*500];
    return v; } };
// flex: kp = kc*8 + d (d-inner). load4 covers one kc, d0..d0+3.
struct AgFlex0v { const ushort_t* Xn; const ushort_t* XG1; const ushort_t* XG2; const float* ne;
  // sources [n][bt*64+c] ld 12288 bf16; kc = k*64+c, K=1536
  __device__ float4 load4(int r, int k4, int) const {
    int d0 = k4 & 7; int kc = k4 >> 3; int k = kc >> 6; int c = kc & 63;
    int bt = r/500, n = r - bt*500;
    const ushort_t* s = (k==0)? Xn : (k==1)? XG1 : XG2;
    float v = b2f(s[(size_t)n*12288 + bt*64 + c]);
    float4 ne4 = *(const float4*)&ne[(size_t)r*8 + d0];
    return float4{v*ne4.x, v*ne4.y, v*ne4.z, v*ne4.w}; } };
struct AgFlex1v { const ushort_t* Y0; const ushort_t* XG1; const ushort_t* XG2; const float* ne;
  // sources [n][bt*128+c] ld 24576 bf16; kc = k*128+c, K=3072
  __device__ float4 load4(int r, int k4, int) const {
    int d0 = k4 & 7; int kc = k4 >> 3; int k = kc >> 7; int c = kc & 127;
    int bt = r/500, n = r - bt*500;
    const ushort_t* s = (k==0)? Y0 : (k==1)? XG1 : XG2;
    float v = b2f(s[(size_t)n*24576 + bt*128 + c]);
    float4 ne4 = *(const float4*)&ne[(size_t)r*8 + d0];
    return float4{v*ne4.x, v*ne4.y, v*ne4.z, v*ne4.w}; } };
struct AgConv { const float* hs; // rows bn*24+t, k = dt*128+c; 4 consecutive c same dt
  __device__ float4 load4(int r, int k, int) const {
    int t = r % 24; int dt = k >> 7; int c = k & 127; int t2 = t + dt - 1;
    if (t2 < 0 || t2 >= 24) return f4z();
    return *(const float4*)&hs[(size_t)(r + (t2 - t))*128 + c]; } };
struct AgTeAdd { const float* o2f; const float* te;
  __device__ float4 load4(int r, int k, int) const {
    float4 a = *(const float4*)&o2f[(size_t)r*128 + k];
    float4 b = *(const float4*)&te[(size_t)(r/500)*128 + k];
    return float4{a.x+b.x, a.y+b.y, a.z+b.z, a.w+b.w}; } };

// ---------------- B generators (scalar) ----------------
struct BgF32 { const float* Bp; int ldb;
  __device__ float operator()(int k, int c) const { return Bp[(size_t)k*ldb + c]; } };
struct BgBf16p { const ushort_t* Bp; int ldb;
  __device__ float operator()(int k, int c) const { return b2f(Bp[(size_t)k*ldb + c]); } };
struct BgT { const float* W; int ld;
  __device__ float operator()(int k, int c) const { return W[(size_t)c*ld + k]; } };
struct BgConvW { const float* w;       // w[o,c,0,dt], k = dt*128+c
  __device__ float operator()(int k, int c) const {
    int dt = k >> 7; int cc = k & 127;
    return w[((size_t)c*128 + cc)*3 + dt]; } };
struct BgWp { const float* wp; int KC;   // wp[d][kc][o], kp = kc*8 + d
  __device__ float operator()(int kp, int c) const {
    int d = kp & 7; int kc = kp >> 3;
    return wp[((size_t)d*KC + kc)*128 + c]; } };

// ---------------- epilogues ----------------
struct EpNone { __device__ float operator()(int, int, float a) const { return a; } };
struct EpS2   { __device__ float operator()(int r, int c, float a) const { return 2.f*a - (r==c ? 1.f : 0.f); } };
struct EpBias { const float* b;
  __device__ float operator()(int, int c, float a) const { return a + b[c]; } };
struct EpNeBias { const float* ne; const float* bp;
  __device__ float operator()(int r, int c, float a) const {
    float s = a;
    #pragma unroll
    for (int d=0; d<8; ++d) s += ne[(size_t)r*8 + d]*bp[d*128 + c];
    return s; } };
struct EpRes1 { const ushort_t* out1; const float* st; const float *g, *bb, *rb; float invM;
  __device__ float operator()(int r, int c, float a) const {
    float mean = st[c]*invM; float var = st[128+c]*invM - mean*mean;
    float rstd = rsqrtf(var + 1e-5f);
    float y = (b2f(out1[(size_t)r*128 + c]) - mean)*rstd*g[c] + bb[c];
    y = fmaxf(y, 0.f);
    return a + rb[c] + y; } };
struct EpRes2 { const float *r2b, *rw, *rcb;
  __device__ float operator()(int, int c, float a) const {
    float s = 0.f;
    #pragma unroll
    for (int t=0; t<24; ++t) s += rw[t];
    return a + s*r2b[c] + rcb[0]; } };

// ---------------- pipelined MFMA generator GEMM ----------------
template<bool BOUT, class AG, class BG, class EP>
__global__ __launch_bounds__(256)
void gemm_mfma(AG ag, BG bg, EP ep, void* Cv, int M, int N, int K, int ldc) {
  constexpr int BM=128, BN=128, BK=32;
  constexpr int LDA = BK + 8;
  __shared__ ushort_t As[BM*LDA];
  __shared__ ushort_t Bs[BN*LDA];
  int tid = threadIdx.x;
  int lane = tid & 63, wave = tid >> 6;
  int wr = (wave >> 1) * 64, wc = (wave & 1) * 64;
  int q = lane >> 4, r16 = lane & 15;
  int row0 = blockIdx.y*BM, col0 = blockIdx.x*BN;
  int am = tid >> 3, ak = (tid & 7) * 4;
  int bn = tid & 127, bk = (tid >> 7) * 4;
  float4 ra[4]; float rb[4][4];
  int nK = (K + BK - 1) / BK;
  #pragma unroll
  for (int s=0;s<4;++s){
    int gr = row0 + am + 32*s;
    ra[s] = (gr < M) ? ag.load4(gr, ak, K) : f4z();
    int gc = col0 + bn;
    #pragma unroll
    for (int v=0;v<4;++v){ int gk = bk + 8*s + v;
      rb[s][v] = (gc < N && gk < K) ? bg(gk, gc) : 0.f; }
  }
  f32x4 acc[4][4] = {};
  for (int t=0; t<nK; ++t) {
    #pragma unroll
    for (int s=0;s<4;++s){
      uint2 pa; pa.x = (unsigned)f2b(ra[s].x) | ((unsigned)f2b(ra[s].y)<<16);
      pa.y = (unsigned)f2b(ra[s].z) | ((unsigned)f2b(ra[s].w)<<16);
      *(uint2*)&As[(am + 32*s)*LDA + ak] = pa;
      uint2 pb; pb.x = (unsigned)f2b(rb[s][0]) | ((unsigned)f2b(rb[s][1])<<16);
      pb.y = (unsigned)f2b(rb[s][2]) | ((unsigned)f2b(rb[s][3])<<16);
      *(uint2*)&Bs[bn*LDA + bk + 8*s] = pb;
    }
    __syncthreads();
    if (t+1 < nK) {
      int k0 = (t+1)*BK;
      #pragma unroll
      for (int s=0;s<4;++s){
        int gr = row0 + am + 32*s;
        ra[s] = (gr < M) ? ag.load4(gr, k0+ak, K) : f4z();
        int gc = col0 + bn;
        #pragma unroll
        for (int v=0;v<4;++v){ int gk = k0 + bk + 8*s + v;
          rb[s][v] = (gc < N && gk < K) ? bg(gk, gc) : 0.f; }
      }
    }
    short8 a[4], b[4];
    #pragma unroll
    for (int it=0;it<4;++it) a[it] = *(const short8*)&As[(wr + it*16 + r16)*LDA + q*8];
    #pragma unroll
    for (int jt=0;jt<4;++jt) b[jt] = *(const short8*)&Bs[(wc + jt*16 + r16)*LDA + q*8];
    #pragma unroll
    for (int it=0;it<4;++it)
      #pragma unroll
      for (int jt=0;jt<4;++jt)
        acc[it][jt] = __builtin_amdgcn_mfma_f32_16x16x32_bf16(a[it], b[jt], acc[it][jt], 0, 0, 0);
    __syncthreads();
  }
  #pragma unroll
  for (int it=0;it<4;++it) {
    #pragma unroll
    for (int v=0;v<4;++v) {
      int rr = row0 + wr + it*16 + q*4 + v;
      if (rr >= M) continue;
      #pragma unroll
      for (int jt=0;jt<4;++jt) {
        int c = col0 + wc + jt*16 + r16;
        if (c >= N) continue;
        float val = ep(rr, c, acc[it][jt][v]);
        if (BOUT) ((ushort_t*)Cv)[(size_t)rr*ldc + c] = f2b(val);
        else      ((float*)Cv)[(size_t)rr*ldc + c] = val;
      }
    }
  }
}

// ---------------- small kernels ----------------
__global__ void k_transpose_bf(const float* src, ushort_t* dst, int R, int Cc) {
  __shared__ float tile[32][33];
  int c0 = blockIdx.x*32, r0 = blockIdx.y*32;
  int tx = threadIdx.x, ty = threadIdx.y;
  for (int i = ty; i < 32; i += 8) {
    int r = r0+i, c = c0+tx;
    if (r < R && c < Cc) tile[i][tx] = src[(size_t)r*Cc + c];
  }
  __syncthreads();
  for (int i = ty; i < 32; i += 8) {
    int dr = c0 + i, dc = r0 + tx;
    if (dr < Cc && dc < R) dst[(size_t)dr*R + dc] = f2b(tile[tx][i]);
  }
}

__global__ void k_copyY_bf(const float* out0, ushort_t* Y) {
  int i = blockIdx.x*256 + threadIdx.x;
  if (i >= 12288000) return;
  int o = i & 127; int r = i >> 7; int btl = r % 192; int n = r / 192;
  Y[i] = f2b(out0[((size_t)btl*500 + n)*128 + o]);
}

__global__ void k_pool0(const float* x, float* pooled) {
  int bt = blockIdx.x; int c = threadIdx.x;
  const float* p = x + (size_t)bt*32000 + (size_t)c*500;
  float s = 0.f;
  for (int n=0;n<500;++n) s += p[n];
  pooled[bt*64 + c] = s*(1.f/500.f);
}
__global__ void k_pool1(const float* src, float* pooled) {
  int bt = blockIdx.x; int o = threadIdx.x;
  float s = 0.f;
  for (int n=0;n<500;++n) s += src[((size_t)bt*500 + n)*128 + o];
  pooled[bt*128 + o] = s*(1.f/500.f);
}

__global__ void k_mlp(const float* pooled, int F, const float* f1w, const float* f1b,
                      const float* f2w, const float* f2b, float* aout) {
  int bt = threadIdx.x;
  if (bt >= 192) return;
  float h[8];
  for (int k=0;k<8;++k){
    float s = f1b[k];
    for (int c=0;c<F;++c) s += pooled[bt*F + c]*f1w[k*F + c];
    h[k] = fmaxf(s, 0.f);
  }
  float z[8]; float m = -1e30f;
  for (int k2=0;k2<8;++k2){
    float s = f2b[k2];
    for (int k=0;k<8;++k) s += h[k]*f2w[k2*8 + k];
    z[k2] = s; m = fmaxf(m, s);
  }
  float den = 0.f;
  for (int k2=0;k2<8;++k2){ z[k2] = expf(z[k2]-m); den += z[k2]; }
  float inv = 1.f/den;
  for (int k2=0;k2<8;++k2) aout[bt*8 + k2] = z[k2]*inv;
}

__global__ void k_ne(const float* a, const float* emb, float* ne) {
  int i = blockIdx.x*256 + threadIdx.x;
  if (i >= 768000) return;
  int d = i & 7; int rem = i >> 3; int n = rem % 500; int bt = rem / 500;
  float s = 0.f;
  #pragma unroll
  for (int k=0;k<8;++k) s += a[bt*8 + k]*emb[((size_t)k*500 + n)*8 + d];
  ne[i] = s;
}

__global__ void k_bn_stats(const float* src, float* stats, int M, int rpb) {
  int col = threadIdx.x & 127; int seg = threadIdx.x >> 7;
  int r0 = blockIdx.x * rpb; int r1 = r0 + rpb; if (r1 > M) r1 = M;
  float s = 0.f, q = 0.f;
  for (int r = r0 + seg; r < r1; r += 2) {
    float v = src[(size_t)r*128 + col];
    s += v; q += v*v;
  }
  atomicAdd(&stats[col], s);
  atomicAdd(&stats[128+col], q);
}
__global__ void k_bn_stats_bf(const ushort_t* src, float* stats, int M, int rpb) {
  int col = threadIdx.x & 127; int seg = threadIdx.x >> 7;
  int r0 = blockIdx.x * rpb; int r1 = r0 + rpb; if (r1 > M) r1 = M;
  float s = 0.f, q = 0.f;
  for (int r = r0 + seg; r < r1; r += 2) {
    float v = b2f(src[(size_t)r*128 + col]);
    s += v; q += v*v;
  }
  atomicAdd(&stats[col], s);
  atomicAdd(&stats[128+col], q);
}

__global__ void k_bn_apply(float* dst, const float* src, const float* st,
                           const float* g, const float* b, int total, float invM, int relu, int addd) {
  int i = blockIdx.x*256 + threadIdx.x;
  if (i >= total) return;
  int c = i & 127;
  float mean = st[c]*invM; float var = st[128+c]*invM - mean*mean;
  float rstd = rsqrtf(var + 1e-5f);
  float y = (src[i]-mean)*rstd*g[c] + b[c];
  if (relu) y = fmaxf(y, 0.f);
  dst[i] = addd ? dst[i] + y : y;
}

// recurrent-only GRU: gi precomputed (bf16); 500 blocks x 8 bn
__global__ __launch_bounds__(384) void k_gru3(const ushort_t* gi, const float* whh,
    const float* bhh, float* hs) {
  __shared__ float h[8][132];
  __shared__ float uh[8][388];
  int tid = threadIdx.x;
  int bn0 = blockIdx.x*8;
  for (int i=tid;i<1024;i+=384) h[i>>7][i&127] = 0.f;
  __syncthreads();
  int j = tid;
  float bh = bhh[j];
  const float* wh = whh + (size_t)j*128;
  for (int t=0;t<24;++t) {
    float ah[8];
    #pragma unroll
    for (int r=0;r<8;++r) ah[r]=bh;
    for (int c=0;c<128;c+=4){
      float4 w4h = *(const float4*)&wh[c];
      #pragma unroll
      for (int r=0;r<8;++r){
        float4 hv = *(const float4*)&h[r][c];
        ah[r] += hv.x*w4h.x + hv.y*w4h.y + hv.z*w4h.z + hv.w*w4h.w;
      }
    }
    #pragma unroll
    for (int r=0;r<8;++r) uh[r][j]=ah[r];
    __syncthreads();
    for (int i=tid;i<1024;i+=384){
      int r=i>>7, u=i&127;
      int bnn = bn0 + r; int b = bnn/500, n = bnn - b*500;
      size_t gbase = ((size_t)(b*24 + t)*500 + n)*384;
      float ir=b2f(gi[gbase+u]), iz=b2f(gi[gbase+128+u]), inn=b2f(gi[gbase+256+u]);
      float hr=uh[r][u], hz=uh[r][128+u], hn=uh[r][256+u];
      float rg = 1.f/(1.f+expf(-(ir+hr)));
      float zg = 1.f/(1.f+expf(-(iz+hz)));
      float ng = tanhf(inn + rg*hn);
      float hnew = (1.f-zg)*ng + zg*h[r][u];
      h[r][u] = hnew;
      hs[((size_t)bnn*24 + t)*128 + u] = hnew;
    }
    __syncthreads();
  }
}

// attention-only: QK^T, softmax, PV, fc, ow
__global__ __launch_bounds__(256) void k_attn3(const ushort_t* Q, const ushort_t* K, const ushort_t* V,
    const float* ow, const float* ob, const float* fcw, const float* fcb, float* out2f) {
  __shared__ float Qs[24][133];
  __shared__ float Ks[24][133];
  __shared__ float Vs[24][133];
  __shared__ float Sc[8][24][25];
  __shared__ float xbar[128];
  int bn = blockIdx.x; int tid = threadIdx.x;
  size_t base = (size_t)bn*3072;
  for (int i=tid;i<3072;i+=256){
    int t=i>>7, c=i&127;
    Qs[t][c]=b2f(Q[base+i]); Ks[t][c]=b2f(K[base+i]); Vs[t][c]=b2f(V[base+i]);
  }
  __syncthreads();
  for (int i=tid;i<4608;i+=256){
    int hh = i/576; int r = i - hh*576; int t = r/24; int s_ = r - t*24;
    float d = 0.f;
    #pragma unroll
    for (int dd=0;dd<16;++dd) d += Qs[t][hh*16+dd]*Ks[s_][hh*16+dd];
    Sc[hh][t][s_] = d*0.25f;
  }
  __syncthreads();
  if (tid < 192) {
    int hh = tid/24, t = tid - (tid/24)*24;
    float m = -1e30f;
    for (int s_=0;s_<24;++s_) m = fmaxf(m, Sc[hh][t][s_]);
    float den = 0.f;
    for (int s_=0;s_<24;++s_){ float e = expf(Sc[hh][t][s_]-m); Sc[hh][t][s_] = e; den += e; }
    float inv = 1.f/den;
    for (int s_=0;s_<24;++s_) Sc[hh][t][s_] *= inv;
  }
  __syncthreads();
  for (int i=tid;i<3072;i+=256){
    int t = i >> 7; int o = i & 127; int hh = o >> 4;
    float s = 0.f;
    #pragma unroll
    for (int s_=0;s_<24;++s_) s += Sc[hh][t][s_]*Vs[s_][o];
    Qs[t][o] = s;
  }
  __syncthreads();
  if (tid < 128) {
    float s = 0.f;
    for (int t=0;t<24;++t) s += fcw[t]*Qs[t][tid];
    xbar[tid] = s;
  }
  __syncthreads();
  if (tid < 128) {
    int o = tid;
    float s = 0.f;
    for (int c=0;c<128;++c) s += xbar[c]*ow[o*128 + c];
    float sfc = 0.f;
    for (int t=0;t<24;++t) sfc += fcw[t];
    out2f[(size_t)bn*128 + o] = s + sfc*ob[o] + fcb[0];
  }
}

__global__ void k_rbar(const float* out2, const float* rw, float* rbar) {
  int i = blockIdx.x*256 + threadIdx.x;
  if (i >= 512000) return;
  int c = i & 127; int bnn = i >> 7; int b = bnn/500, n = bnn - b*500;
  float s = 0.f;
  #pragma unroll
  for (int t=0;t<24;++t) s += rw[t] * out2[((size_t)(b*24 + t)*500 + n)*128 + c];
  rbar[i] = s;
}

__global__ void k_te(const float* tt, const float* w1, const float* b1,
                     const float* w2, const float* b2, float* te) {
  __shared__ float h1[128];
  int b = blockIdx.x; int o = threadIdx.x;
  float s = b1[o];
  for (int c=0;c<32;++c) s += tt[b*32 + c]*w1[o*32 + c];
  h1[o] = fmaxf(s, 0.f);
  __syncthreads();
  float s2 = b2[o];
  for (int c=0;c<128;++c) s2 += h1[c]*w2[o*128 + c];
  te[b*128 + o] = s2;
}

__global__ void k_grid(const float* gnm, const float* fin, float* out) {
  int e = threadIdx.x & 63; int gq = threadIdx.x >> 6;
  int g = blockIdx.x*4 + gq; int b = blockIdx.y;
  float s = 0.f;
  const float* gr = gnm + (size_t)g*500;
  const float* fb = fin + (size_t)b*500*64 + e;
  for (int n=0;n<500;++n) s += gr[n] * fb[(size_t)n*64];
  out[(size_t)b*32000 + (size_t)e*500 + g] = s;
}

// ---------------- launch ----------------
extern "C" void kernel_launch(void* const* d_in, const int* in_sizes, int n_in,
                              void* d_out, int out_size, void* d_ws, size_t ws_size,
                              hipStream_t stream) {
  const float* adj   = (const float*)d_in[0];
  const float* x     = (const float*)d_in[1];
  const float* gnm   = (const float*)d_in[2];
  const float* ttime = (const float*)d_in[3];
  const float* emb   = (const float*)d_in[4];
  const float* wp0   = (const float*)d_in[5];
  const float* bp0   = (const float*)d_in[6];
  const float* a0f1w = (const float*)d_in[7];
  const float* a0f1b = (const float*)d_in[8];
  const float* a0f2w = (const float*)d_in[9];
  const float* a0f2b = (const float*)d_in[10];
  const float* wp1   = (const float*)d_in[11];
  const float* bp1   = (const float*)d_in[12];
  const float* a1f1w = (const float*)d_in[13];
  const float* a1f1b = (const float*)d_in[14];
  const float* a1f2w = (const float*)d_in[15];
  const float* a1f2b = (const float*)d_in[16];
  const float* bn0g  = (const float*)d_in[17];
  const float* bn0b  = (const float*)d_in[18];
  const float* bn1g  = (const float*)d_in[19];
  const float* bn1b  = (const float*)d_in[20];
  const float* wih   = (const float*)d_in[21];
  const float* whh   = (const float*)d_in[22];
  const float* bih   = (const float*)d_in[23];
  const float* bhh   = (const float*)d_in[24];
  const float* bgg   = (const float*)d_in[25];
  const float* bgb   = (const float*)d_in[26];
  const float* cqw   = (const float*)d_in[27];
  const float* cqb   = (const float*)d_in[28];
  const float* ckw   = (const float*)d_in[29];
  const float* ckb   = (const float*)d_in[30];
  const float* vw    = (const float*)d_in[31];
  const float* vb    = (const float*)d_in[32];
  const float* ow    = (const float*)d_in[33];
  const float* ob    = (const float*)d_in[34];
  const float* r1w   = (const float*)d_in[35];
  const float* r1b   = (const float*)d_in[36];
  const float* fcw   = (const float*)d_in[37];
  const float* fcb   = (const float*)d_in[38];
  const float* rcw   = (const float*)d_in[39];
  const float* rcb   = (const float*)d_in[40];
  const float* r2w   = (const float*)d_in[41];
  const float* r2b   = (const float*)d_in[42];
  const float* bnrg  = (const float*)d_in[43];
  const float* bnrb  = (const float*)d_in[44];
  const float* te1w  = (const float*)d_in[45];
  const float* te1b  = (const float*)d_in[46];
  const float* te2w  = (const float*)d_in[47];
  const float* te2b  = (const float*)d_in[48];
  const float* finw  = (const float*)d_in[49];
  const float* finb  = (const float*)d_in[50];
  float* dout = (float*)d_out;
  float* W = (float*)d_ws;

  size_t off = 0;
  auto alloc = [&](size_t n){ size_t r = off; off += (n + 255) & ~(size_t)255; return r; };
  size_t oStats = alloc(512);
  size_t oPool  = alloc(24576);
  size_t oAmix  = alloc(1536);
  size_t oTe    = alloc(1024);
  size_t oO2f   = alloc(512000);
  size_t oRbar  = alloc(512000);
  size_t oRes   = alloc(512000);
  size_t oFin   = alloc(256000);
  size_t oNe0   = alloc(768000);
  size_t oNe1   = alloc(768000);
  size_t oS2    = alloc(125000);    // bf16 [500][500]
  size_t oR1    = alloc(12288000);  // out0 -> out2 -> hs
  size_t oR2    = alloc(12288000);  // XG pairs -> gi(low) -> Q,K
  size_t oR4    = alloc(6144000);   // Xn -> Y0bf -> (out1 shares) -> gi(high) -> V
  (void)n_in; (void)in_sizes; (void)out_size;
  if (ws_size < off * sizeof(float)) return;

  float* stats = W + oStats;
  float* pooled= W + oPool;
  float* amix  = W + oAmix;
  float* teb   = W + oTe;
  float* out2f = W + oO2f;
  float* rbar  = W + oRbar;
  float* resout= W + oRes;
  float* fin   = W + oFin;
  float* ne0   = W + oNe0;
  float* ne1   = W + oNe1;
  ushort_t* S2bf = (ushort_t*)(W + oS2);
  float* out0  = W + oR1;
  float* out2  = W + oR1;
  float* hs    = W + oR1;                             // after out2 dead
  ushort_t* XG1n = (ushort_t*)(W + oR2);              // [500][12288]
  ushort_t* XG2n = XG1n + 6144000;
  ushort_t* XGB1 = (ushort_t*)(W + oR2);              // [500][24576]
  ushort_t* XGB2 = XGB1 + 12288000;
  ushort_t* gi16 = (ushort_t*)(W + oR2);              // [96000][384] spans R2+R4... careful
  ushort_t* Qbf  = (ushort_t*)(W + oR2);              // after gi dead
  ushort_t* Kbf  = Qbf + 12288000;
  ushort_t* Vbf  = Kbf + 12288000;
  ushort_t* Xnbf = (ushort_t*)(W + oR4);              // [500][12288]
  ushort_t* Y0bf = (ushort_t*)(W + oR4);              // [500][24576]
  // NOTE: out1 must coexist with Y0bf (flex1 A reads Y0bf while writing out1).
  // out1 lives in the upper half of R2 after XGB2?? No — XGB1/XGB2 are read by flex1 too.
  // out1 goes to the rbar region? rbar (512000 f32) too small. Use gi16 region top:
  // gi16 not yet live during flex1; out1 = first 12.3M ushorts of R2? XGB1 occupies it.
  // => place out1 in R1? out0 is read by pool1 only BEFORE flex1; but EpRes1 (after flex1)
  //    reads out1 while writing out2 (R1) — overlap. Solution: out1 in gi-high = R4 upper?
  //    R4 holds Y0bf fully (24.58MB = whole R4). Use a dedicated slice: reuse 'rbar+res+o2f'? no.
  // Simplest: allocate a dedicated out1 region (bf16, 24.58 MB = 6.14M floats).
  ushort_t* out1 = (ushort_t*)(W + alloc(6144000));
  if (ws_size < off * sizeof(float)) return;

  // ---- Phase A ----
  k_transpose_bf<<<dim3(16,384), dim3(32,8), 0, stream>>>(x, Xnbf, 12288, 500);
  gemm_mfma<true><<<dim3(4,4), 256, 0, stream>>>(
      AgF32{adj,500}, BgF32{adj,500}, EpS2{}, (void*)S2bf, 500, 500, 500, 500);
  gemm_mfma<true><<<dim3(96,4), 256, 0, stream>>>(
      AgF32{adj,500}, BgBf16p{Xnbf,12288}, EpNone{}, (void*)XG1n, 500, 12288, 500, 12288);
  gemm_mfma<true><<<dim3(96,4), 256, 0, stream>>>(
      AgBf16p{S2bf,500}, BgBf16p{Xnbf,12288}, EpNone{}, (void*)XG2n, 500, 12288, 500, 12288);
  k_pool0<<<192, 64, 0, stream>>>(x, pooled);
  k_mlp<<<1, 192, 0, stream>>>(pooled, 64, a0f1w, a0f1b, a0f2w, a0f2b, amix);
  k_ne<<<3000, 256, 0, stream>>>(amix, emb, ne0);
  gemm_mfma<false><<<dim3(1,750), 256, 0, stream>>>(
      AgFlex0v{Xnbf, XG1n, XG2n, ne0}, BgWp{wp0, 192}, EpNeBias{ne0, bp0},
      (void*)out0, 96000, 128, 1536, 128);
  hipMemsetAsync((void*)stats, 0, 256*sizeof(float), stream);
  k_bn_stats<<<768, 256, 0, stream>>>(out0, stats, 96000, 125);
  k_bn_apply<<<48000, 256, 0, stream>>>(out0, out0, stats, bn0g, bn0b, 12288000, 1.f/96000.f, 1, 0);

  // ---- Phase B ----
  k_pool1<<<192, 128, 0, stream>>>(out0, pooled);
  k_mlp<<<1, 192, 0, stream>>>(pooled, 128, a1f1w, a1f1b, a1f2w, a1f2b, amix);
  k_ne<<<3000, 256, 0, stream>>>(amix, emb, ne1);
  k_copyY_bf<<<48000, 256, 0, stream>>>(out0, Y0bf);
  gemm_mfma<true><<<dim3(192,4), 256, 0, stream>>>(
      AgF32{adj,500}, BgBf16p{Y0bf,24576}, EpNone{}, (void*)XGB1, 500, 24576, 500, 24576);
  gemm_mfma<true><<<dim3(192,4), 256, 0, stream>>>(
      AgBf16p{S2bf,500}, BgBf16p{Y0bf,24576}, EpNone{}, (void*)XGB2, 500, 24576, 500, 24576);
  gemm_mfma<true><<<dim3(1,750), 256, 0, stream>>>(
      AgFlex1v{Y0bf, XGB1, XGB2, ne1}, BgWp{wp1, 384}, EpNeBias{ne1, bp1},
      (void*)out1, 96000, 128, 3072, 128);
  hipMemsetAsync((void*)stats, 0, 256*sizeof(float), stream);
  k_bn_stats_bf<<<768, 256, 0, stream>>>(out1, stats, 96000, 125);
  gemm_mfma<false><<<dim3(1,750), 256, 0, stream>>>(
      AgXrow{x}, BgT{r1w,64}, EpRes1{out1, stats, bn1g, bn1b, r1b, 1.f/96000.f},
      (void*)out2, 96000, 128, 64, 128);

  // ---- Phase E-part1 (only needs out2) ----
  k_rbar<<<2000, 256, 0, stream>>>(out2, rcw, rbar);
  gemm_mfma<false><<<dim3(1,32), 256, 0, stream>>>(
      AgF32{rbar,128}, BgT{r2w,128}, EpRes2{r2b, rcw, rcb}, (void*)resout, 4000, 128, 128, 128);
  hipMemsetAsync((void*)stats, 0, 256*sizeof(float), stream);
  k_bn_stats<<<32, 256, 0, stream>>>(resout, stats, 4000, 125);

  // ---- Phase C: gi on MFMA, then recurrent-only GRU ----
  gemm_mfma<true><<<dim3(3,750), 256, 0, stream>>>(
      AgF32{out2,128}, BgT{wih,128}, EpBias{bih}, (void*)gi16, 96000, 384, 128, 384);
  k_gru3<<<500, 384, 0, stream>>>(gi16, whh, bhh, hs);
  hipMemsetAsync((void*)(stats+256), 0, 256*sizeof(float), stream);
  k_bn_stats<<<768, 256, 0, stream>>>(hs, stats+256, 96000, 125);
  k_bn_apply<<<48000, 256, 0, stream>>>(hs, hs, stats+256, bgg, bgb, 12288000, 1.f/96000.f, 1, 0);

  // ---- Phase D: conv-QKV via MFMA GEMMs + light attention ----
  gemm_mfma<true><<<dim3(1,750), 256, 0, stream>>>(
      AgConv{hs}, BgConvW{cqw}, EpBias{cqb}, (void*)Qbf, 96000, 128, 384, 128);
  gemm_mfma<true><<<dim3(1,750), 256, 0, stream>>>(
      AgConv{hs}, BgConvW{ckw}, EpBias{ckb}, (void*)Kbf, 96000, 128, 384, 128);
  gemm_mfma<true><<<dim3(1,750), 256, 0, stream>>>(
      AgF32{hs,128}, BgT{vw,128}, EpBias{vb}, (void*)Vbf, 96000, 128, 128, 128);
  k_attn3<<<4000, 256, 0, stream>>>(Qbf, Kbf, Vbf, ow, ob, fcw, fcb, out2f);

  // ---- Phase E-part2 ----
  k_bn_apply<<<2000, 256, 0, stream>>>(out2f, resout, stats, bnrg, bnrb, 512000, 1.f/4000.f, 0, 1);
  k_te<<<8, 128, 0, stream>>>(ttime, te1w, te1b, te2w, te2b, teb);
  gemm_mfma<false><<<dim3(1,32), 256, 0, stream>>>(
      AgTeAdd{out2f, teb}, BgT{finw,128}, EpBias{finb}, (void*)fin, 4000, 64, 128, 64);
  k_grid<<<dim3(125,8), 256, 0, stream>>>(gnm, fin, dout);
}

// Round 9
// 2116.073 us; speedup vs baseline: 5.1995x; 1.3148x over previous
//
#include <hip/hip_runtime.h>
#include <math.h>

using short8 = __attribute__((ext_vector_type(8))) short;
using f32x4  = __attribute__((ext_vector_type(4))) float;
using ushort_t = unsigned short;

__device__ __forceinline__ ushort_t f2b(float f){
  unsigned int u = __builtin_bit_cast(unsigned int, f);
  u = (u + 0x7fffu + ((u >> 16) & 1u)) >> 16;
  return (ushort_t)u;
}
__device__ __forceinline__ float b2f(ushort_t u){
  unsigned int v = ((unsigned int)u) << 16;
  return __builtin_bit_cast(float, v);
}
__device__ __forceinline__ uint2 pk4(float a, float b, float c, float d){
  uint2 p; p.x = (unsigned)f2b(a) | ((unsigned)f2b(b)<<16);
  p.y = (unsigned)f2b(c) | ((unsigned)f2b(d)<<16); return p;
}
__device__ __forceinline__ uint2 z2(){ return uint2{0u,0u}; }

// ---------------- A generators: load4p(r, k, K) -> 4 packed bf16 ----------------
struct AgF32 { const float* A; int lda;
  __device__ uint2 load4p(int r, int k, int K) const {
    const float* p = &A[(size_t)r*lda + k];
    if (k+3 < K) { float4 v = *(const float4*)p; return pk4(v.x,v.y,v.z,v.w); }
    float a=0,b=0,c=0,d=0;
    if (k   < K) a = p[0];
    if (k+1 < K) b = p[1];
    if (k+2 < K) c = p[2];
    if (k+3 < K) d = p[3];
    return pk4(a,b,c,d); } };
struct AgBf16p { const ushort_t* A; int lda;
  __device__ uint2 load4p(int r, int k, int K) const {
    const ushort_t* p = &A[(size_t)r*lda + k];
    if (k+3 < K) return *(const uint2*)p;
    ushort_t a=0,b=0,c=0,d=0;
    if (k   < K) a = p[0];
    if (k+1 < K) b = p[1];
    if (k+2 < K) c = p[2];
    if (k+3 < K) d = p[3];
    uint2 q; q.x = (unsigned)a | ((unsigned)b<<16); q.y = (unsigned)c | ((unsigned)d<<16);
    return q; } };
struct AgXrow { const float* x;  // row=bt*500+n, k=c : x[bt,c,n]
  __device__ uint2 load4p(int r, int k, int K) const {
    int bt = r/500, n = r - bt*500;
    const float* p = x + (size_t)bt*32000 + n;
    float a=0,b=0,c=0,d=0;
    if (k   < K) a = p[(size_t)k*500];
    if (k+1 < K) b = p[(size_t)(k+1)*500];
    if (k+2 < K) c = p[(size_t)(k+2)*500];
    if (k+3 < K) d = p[(size_t)(k+3)*500];
    return pk4(a,b,c,d); } };
// flex: kp = kc*8 + d (d-inner); one load4p covers one kc, d0..d0+3
struct AgFlex0v { const ushort_t* Xn; const ushort_t* XG1; const ushort_t* XG2; const float* ne;
  __device__ uint2 load4p(int r, int k4, int) const {
    int d0 = k4 & 7; int kc = k4 >> 3; int k = kc >> 6; int c = kc & 63;
    int bt = r/500, n = r - bt*500;
    const ushort_t* s = (k==0)? Xn : (k==1)? XG1 : XG2;
    float v = b2f(s[(size_t)n*12288 + bt*64 + c]);
    float4 ne4 = *(const float4*)&ne[(size_t)r*8 + d0];
    return pk4(v*ne4.x, v*ne4.y, v*ne4.z, v*ne4.w); } };
struct AgFlex1v { const ushort_t* Y0; const ushort_t* XG1; const ushort_t* XG2; const float* ne;
  __device__ uint2 load4p(int r, int k4, int) const {
    int d0 = k4 & 7; int kc = k4 >> 3; int k = kc >> 7; int c = kc & 127;
    int bt = r/500, n = r - bt*500;
    const ushort_t* s = (k==0)? Y0 : (k==1)? XG1 : XG2;
    float v = b2f(s[(size_t)n*24576 + bt*128 + c]);
    float4 ne4 = *(const float4*)&ne[(size_t)r*8 + d0];
    return pk4(v*ne4.x, v*ne4.y, v*ne4.z, v*ne4.w); } };
struct AgConv { const float* hs; // rows bn*24+t, k = dt*128+c; 4 consecutive c same dt
  __device__ uint2 load4p(int r, int k, int) const {
    int t = r % 24; int dt = k >> 7; int c = k & 127; int t2 = t + dt - 1;
    if (t2 < 0 || t2 >= 24) return z2();
    float4 v = *(const float4*)&hs[(size_t)(r + (t2 - t))*128 + c];
    return pk4(v.x,v.y,v.z,v.w); } };
struct AgTeAdd { const float* o2f; const float* te;
  __device__ uint2 load4p(int r, int k, int) const {
    float4 a = *(const float4*)&o2f[(size_t)r*128 + k];
    float4 b = *(const float4*)&te[(size_t)(r/500)*128 + k];
    return pk4(a.x+b.x, a.y+b.y, a.z+b.z, a.w+b.w); } };

// ---------------- B generators: load4p(c, k, K) ----------------
struct BgPk { const ushort_t* B; int ldb;   // packed bf16 [N][K], k-contiguous
  __device__ uint2 load4p(int c, int k, int K) const {
    const ushort_t* p = &B[(size_t)c*ldb + k];
    if (k+3 < K) return *(const uint2*)p;
    ushort_t a=0,b=0,cc=0,d=0;
    if (k   < K) a = p[0];
    if (k+1 < K) b = p[1];
    if (k+2 < K) cc = p[2];
    if (k+3 < K) d = p[3];
    uint2 q; q.x = (unsigned)a | ((unsigned)b<<16); q.y = (unsigned)cc | ((unsigned)d<<16);
    return q; } };
struct BgXTv { const float* x;   // B[k][c]=x[c*500+k] (c=bt*64+cin), k-contiguous
  __device__ uint2 load4p(int c, int k, int K) const {
    const float* p = x + (size_t)c*500 + k;
    if (k+3 < K) { float4 v = *(const float4*)p; return pk4(v.x,v.y,v.z,v.w); }
    float a=0,b=0,cc=0,d=0;
    if (k   < K) a = p[0];
    if (k+1 < K) b = p[1];
    if (k+2 < K) cc = p[2];
    if (k+3 < K) d = p[3];
    return pk4(a,b,cc,d); } };
struct BgAdjB { const float* adj;   // B[k][c]=adj[k*500+c]
  __device__ uint2 load4p(int c, int k, int K) const {
    float a=0,b=0,cc=0,d=0;
    if (k   < K) a = adj[(size_t)k*500 + c];
    if (k+1 < K) b = adj[(size_t)(k+1)*500 + c];
    if (k+2 < K) cc = adj[(size_t)(k+2)*500 + c];
    if (k+3 < K) d = adj[(size_t)(k+3)*500 + c];
    return pk4(a,b,cc,d); } };

// ---------------- epilogues ----------------
struct EpNone { __device__ float operator()(int, int, float a) const { return a; } };
struct EpS2   { __device__ float operator()(int r, int c, float a) const { return 2.f*a - (r==c ? 1.f : 0.f); } };
struct EpBias { const float* b;
  __device__ float operator()(int, int c, float a) const { return a + b[c]; } };
struct EpNeBias { const float* ne; const float* bp;
  __device__ float operator()(int r, int c, float a) const {
    float s = a;
    #pragma unroll
    for (int d=0; d<8; ++d) s += ne[(size_t)r*8 + d]*bp[d*128 + c];
    return s; } };
struct EpRes1 { const ushort_t* out1; const float* st; const float *g, *bb, *rb; float invM;
  __device__ float operator()(int r, int c, float a) const {
    float mean = st[c]*invM; float var = st[128+c]*invM - mean*mean;
    float rstd = rsqrtf(var + 1e-5f);
    float y = (b2f(out1[(size_t)r*128 + c]) - mean)*rstd*g[c] + bb[c];
    y = fmaxf(y, 0.f);
    return a + rb[c] + y; } };
struct EpRes2 { const float *r2b, *rw, *rcb;
  __device__ float operator()(int, int c, float a) const {
    float s = 0.f;
    #pragma unroll
    for (int t=0; t<24; ++t) s += rw[t];
    return a + s*r2b[c] + rcb[0]; } };

// ---------------- pipelined MFMA generator GEMM (symmetric uint2 staging) ----------------
template<bool BOUT, class AG, class BG, class EP>
__global__ __launch_bounds__(256)
void gemm_mfma(AG ag, BG bg, EP ep, void* Cv, int M, int N, int K, int ldc) {
  constexpr int LDA = 40;
  __shared__ ushort_t As[128*LDA];
  __shared__ ushort_t Bs[128*LDA];
  int tid = threadIdx.x;
  int lane = tid & 63, wave = tid >> 6;
  int wr = (wave >> 1) * 64, wc = (wave & 1) * 64;
  int q = lane >> 4, r16 = lane & 15;
  int row0 = blockIdx.y*128, col0 = blockIdx.x*128;
  int am = tid >> 3, ak = (tid & 7) * 4;
  uint2 ua[4], ub[4];
  int nK = (K + 31) / 32;
  #pragma unroll
  for (int s=0;s<4;++s){
    int gr = row0 + am + 32*s;
    ua[s] = (gr < M) ? ag.load4p(gr, ak, K) : z2();
    int gc = col0 + am + 32*s;
    ub[s] = (gc < N) ? bg.load4p(gc, ak, K) : z2();
  }
  f32x4 acc[4][4] = {};
  for (int t=0; t<nK; ++t) {
    #pragma unroll
    for (int s=0;s<4;++s){
      *(uint2*)&As[(am + 32*s)*LDA + ak] = ua[s];
      *(uint2*)&Bs[(am + 32*s)*LDA + ak] = ub[s];
    }
    __syncthreads();
    if (t+1 < nK) {
      int k0 = (t+1)*32;
      #pragma unroll
      for (int s=0;s<4;++s){
        int gr = row0 + am + 32*s;
        ua[s] = (gr < M) ? ag.load4p(gr, k0+ak, K) : z2();
        int gc = col0 + am + 32*s;
        ub[s] = (gc < N) ? bg.load4p(gc, k0+ak, K) : z2();
      }
    }
    short8 a[4], b[4];
    #pragma unroll
    for (int it=0;it<4;++it) a[it] = *(const short8*)&As[(wr + it*16 + r16)*LDA + q*8];
    #pragma unroll
    for (int jt=0;jt<4;++jt) b[jt] = *(const short8*)&Bs[(wc + jt*16 + r16)*LDA + q*8];
    #pragma unroll
    for (int it=0;it<4;++it)
      #pragma unroll
      for (int jt=0;jt<4;++jt)
        acc[it][jt] = __builtin_amdgcn_mfma_f32_16x16x32_bf16(a[it], b[jt], acc[it][jt], 0, 0, 0);
    __syncthreads();
  }
  #pragma unroll
  for (int it=0;it<4;++it) {
    #pragma unroll
    for (int v=0;v<4;++v) {
      int rr = row0 + wr + it*16 + q*4 + v;
      if (rr >= M) continue;
      #pragma unroll
      for (int jt=0;jt<4;++jt) {
        int c = col0 + wc + jt*16 + r16;
        if (c >= N) continue;
        float val = ep(rr, c, acc[it][jt][v]);
        if (BOUT) ((ushort_t*)Cv)[(size_t)rr*ldc + c] = f2b(val);
        else      ((float*)Cv)[(size_t)rr*ldc + c] = val;
      }
    }
  }
}

// ---------------- packing kernels ----------------
__global__ void k_pack_bf(const float* s, ushort_t* d, int n){
  int i = blockIdx.x*256 + threadIdx.x; if (i < n) d[i] = f2b(s[i]); }
__global__ void k_pack_wp(const float* wp, ushort_t* d, int C, int K){
  // d[o*K + kp], kp = kc*8+d_, kc = kk*C+cin; wp[(d_*3+kk)*C+cin][o]
  int i = blockIdx.x*256 + threadIdx.x; int total = 128*K; if (i >= total) return;
  int o = i / K; int kp = i - o*K; int dd = kp & 7; int kc = kp >> 3;
  int kk = kc / C; int cin = kc - kk*C;
  d[i] = f2b(wp[(((size_t)dd*3 + kk)*C + cin)*128 + o]); }
__global__ void k_pack_convw(const float* w, ushort_t* d){
  // d[o*384 + dt*128 + cin] = w[(o*128+cin)*3 + dt]
  int i = blockIdx.x*256 + threadIdx.x; if (i >= 49152) return;
  int o = i / 384; int r = i - o*384; int dt = r >> 7; int cin = r & 127;
  d[i] = f2b(w[((size_t)o*128 + cin)*3 + dt]); }

// ---------------- small kernels ----------------
__global__ void k_transpose_bf(const float* src, ushort_t* dst, int R, int Cc) {
  __shared__ float tile[32][33];
  int c0 = blockIdx.x*32, r0 = blockIdx.y*32;
  int tx = threadIdx.x, ty = threadIdx.y;
  for (int i = ty; i < 32; i += 8) {
    int r = r0+i, c = c0+tx;
    if (r < R && c < Cc) tile[i][tx] = src[(size_t)r*Cc + c];
  }
  __syncthreads();
  for (int i = ty; i < 32; i += 8) {
    int dr = c0 + i, dc = r0 + tx;
    if (dr < Cc && dc < R) dst[(size_t)dr*R + dc] = f2b(tile[tx][i]);
  }
}

__global__ void k_copyY4(const float* out0, ushort_t* Y) { // Y[n*24576+bt*128+o], 4 o per thread
  int i = blockIdx.x*256 + threadIdx.x;
  if (i >= 3072000) return;
  int i4 = i*4;
  int o = i4 & 127; int r = i4 >> 7; int btl = r % 192; int n = r / 192;
  float4 v = *(const float4*)&out0[((size_t)btl*500 + n)*128 + o];
  *(uint2*)&Y[i4] = pk4(v.x,v.y,v.z,v.w);
}

__global__ void k_copyYT_bf(const float* out0, ushort_t* YT) { // YT[(bt*128+o)*500+n]
  __shared__ float tile[32][33];
  int bt = blockIdx.z; int n0 = blockIdx.x*32; int o0 = blockIdx.y*32;
  int tx = threadIdx.x, ty = threadIdx.y;
  for (int i = ty; i < 32; i += 8) {
    int n = n0 + i;
    if (n < 500) tile[i][tx] = out0[((size_t)bt*500 + n)*128 + o0 + tx];
  }
  __syncthreads();
  for (int i = ty; i < 32; i += 8) {
    int o = o0 + i; int n = n0 + tx;
    if (n < 500) YT[((size_t)bt*128 + o)*500 + n] = f2b(tile[tx][i]);
  }
}

__global__ void k_pool0(const float* x, float* pooled) {
  int bt = blockIdx.x; int c = threadIdx.x;
  const float* p = x + (size_t)bt*32000 + (size_t)c*500;
  float s = 0.f;
  for (int n=0;n<500;++n) s += p[n];
  pooled[bt*64 + c] = s*(1.f/500.f);
}
__global__ void k_pool1(const float* src, float* pooled) {
  int bt = blockIdx.x; int o = threadIdx.x;
  float s = 0.f;
  for (int n=0;n<500;++n) s += src[((size_t)bt*500 + n)*128 + o];
  pooled[bt*128 + o] = s*(1.f/500.f);
}

__global__ void k_mlp(const float* pooled, int F, const float* f1w, const float* f1b,
                      const float* f2w, const float* f2b, float* aout) {
  int bt = threadIdx.x;
  if (bt >= 192) return;
  float h[8];
  for (int k=0;k<8;++k){
    float s = f1b[k];
    for (int c=0;c<F;++c) s += pooled[bt*F + c]*f1w[k*F + c];
    h[k] = fmaxf(s, 0.f);
  }
  float z[8]; float m = -1e30f;
  for (int k2=0;k2<8;++k2){
    float s = f2b[k2];
    for (int k=0;k<8;++k) s += h[k]*f2w[k2*8 + k];
    z[k2] = s; m = fmaxf(m, s);
  }
  float den = 0.f;
  for (int k2=0;k2<8;++k2){ z[k2] = expf(z[k2]-m); den += z[k2]; }
  float inv = 1.f/den;
  for (int k2=0;k2<8;++k2) aout[bt*8 + k2] = z[k2]*inv;
}

__global__ void k_ne(const float* a, const float* emb, float* ne) {
  int i = blockIdx.x*256 + threadIdx.x;
  if (i >= 768000) return;
  int d = i & 7; int rem = i >> 3; int n = rem % 500; int bt = rem / 500;
  float s = 0.f;
  #pragma unroll
  for (int k=0;k<8;++k) s += a[bt*8 + k]*emb[((size_t)k*500 + n)*8 + d];
  ne[i] = s;
}

__global__ void k_bn_stats(const float* src, float* stats, int M, int rpb) {
  int col = threadIdx.x & 127; int seg = threadIdx.x >> 7;
  int r0 = blockIdx.x * rpb; int r1 = r0 + rpb; if (r1 > M) r1 = M;
  float s = 0.f, q = 0.f;
  for (int r = r0 + seg; r < r1; r += 2) {
    float v = src[(size_t)r*128 + col];
    s += v; q += v*v;
  }
  atomicAdd(&stats[col], s);
  atomicAdd(&stats[128+col], q);
}
__global__ void k_bn_stats_bf(const ushort_t* src, float* stats, int M, int rpb) {
  int col = threadIdx.x & 127; int seg = threadIdx.x >> 7;
  int r0 = blockIdx.x * rpb; int r1 = r0 + rpb; if (r1 > M) r1 = M;
  float s = 0.f, q = 0.f;
  for (int r = r0 + seg; r < r1; r += 2) {
    float v = b2f(src[(size_t)r*128 + col]);
    s += v; q += v*v;
  }
  atomicAdd(&stats[col], s);
  atomicAdd(&stats[128+col], q);
}

__global__ void k_bn_apply4(float* dst, const float* src, const float* st,
                            const float* g, const float* b, int total4, float invM, int relu, int addd) {
  int i = blockIdx.x*256 + threadIdx.x;
  if (i >= total4) return;
  int i4 = i*4; int c = i4 & 127;
  float4 sm = *(const float4*)&st[c];
  float4 sq = *(const float4*)&st[128+c];
  float4 g4 = *(const float4*)&g[c];
  float4 b4 = *(const float4*)&b[c];
  float4 v = *(const float4*)&src[i4];
  float4 y;
  {
    float mean = sm.x*invM; float var = sq.x*invM - mean*mean;
    y.x = (v.x-mean)*rsqrtf(var+1e-5f)*g4.x + b4.x;
    mean = sm.y*invM; var = sq.y*invM - mean*mean;
    y.y = (v.y-mean)*rsqrtf(var+1e-5f)*g4.y + b4.y;
    mean = sm.z*invM; var = sq.z*invM - mean*mean;
    y.z = (v.z-mean)*rsqrtf(var+1e-5f)*g4.z + b4.z;
    mean = sm.w*invM; var = sq.w*invM - mean*mean;
    y.w = (v.w-mean)*rsqrtf(var+1e-5f)*g4.w + b4.w;
  }
  if (relu){ y.x=fmaxf(y.x,0.f); y.y=fmaxf(y.y,0.f); y.z=fmaxf(y.z,0.f); y.w=fmaxf(y.w,0.f); }
  if (addd){ float4 d0 = *(const float4*)&dst[i4]; y.x+=d0.x; y.y+=d0.y; y.z+=d0.z; y.w+=d0.w; }
  *(float4*)&dst[i4] = y;
}

// recurrent-only GRU: gi precomputed (bf16); 500 blocks x 8 bn
__global__ __launch_bounds__(384) void k_gru3(const ushort_t* gi, const float* whh,
    const float* bhh, float* hs) {
  __shared__ float h[8][132];
  __shared__ float uh[8][388];
  int tid = threadIdx.x;
  int bn0 = blockIdx.x*8;
  for (int i=tid;i<1024;i+=384) h[i>>7][i&127] = 0.f;
  __syncthreads();
  int j = tid;
  float bh = bhh[j];
  const float* wh = whh + (size_t)j*128;
  for (int t=0;t<24;++t) {
    float ah[8];
    #pragma unroll
    for (int r=0;r<8;++r) ah[r]=bh;
    for (int c=0;c<128;c+=4){
      float4 w4h = *(const float4*)&wh[c];
      #pragma unroll
      for (int r=0;r<8;++r){
        float4 hv = *(const float4*)&h[r][c];
        ah[r] += hv.x*w4h.x + hv.y*w4h.y + hv.z*w4h.z + hv.w*w4h.w;
      }
    }
    #pragma unroll
    for (int r=0;r<8;++r) uh[r][j]=ah[r];
    __syncthreads();
    for (int i=tid;i<1024;i+=384){
      int r=i>>7, u=i&127;
      int bnn = bn0 + r; int b = bnn/500, n = bnn - b*500;
      size_t gbase = ((size_t)(b*24 + t)*500 + n)*384;
      float ir=b2f(gi[gbase+u]), iz=b2f(gi[gbase+128+u]), inn=b2f(gi[gbase+256+u]);
      float hr=uh[r][u], hz=uh[r][128+u], hn=uh[r][256+u];
      float rg = 1.f/(1.f+expf(-(ir+hr)));
      float zg = 1.f/(1.f+expf(-(iz+hz)));
      float ng = tanhf(inn + rg*hn);
      float hnew = (1.f-zg)*ng + zg*h[r][u];
      h[r][u] = hnew;
      hs[((size_t)bnn*24 + t)*128 + u] = hnew;
    }
    __syncthreads();
  }
}

// attention-only, 44.5 KB LDS (A1=Q/xa, A2=K/V, Sc)
__global__ __launch_bounds__(256) void k_attn3(const ushort_t* Q, const ushort_t* K, const ushort_t* V,
    const float* ow, const float* ob, const float* fcw, const float* fcb, float* out2f) {
  __shared__ float A1[24][132];
  __shared__ float A2[24][132];
  __shared__ float Sc[8][24][25];
  int bn = blockIdx.x; int tid = threadIdx.x;
  size_t base = (size_t)bn*3072;
  for (int i=tid;i<3072;i+=256){
    int t=i>>7, c=i&127;
    A1[t][c]=b2f(Q[base+i]); A2[t][c]=b2f(K[base+i]);
  }
  __syncthreads();
  for (int i=tid;i<4608;i+=256){
    int hh = i/576; int r = i - hh*576; int t = r/24; int s_ = r - t*24;
    float d = 0.f;
    #pragma unroll
    for (int dd=0;dd<16;++dd) d += A1[t][hh*16+dd]*A2[s_][hh*16+dd];
    Sc[hh][t][s_] = d*0.25f;
  }
  __syncthreads();
  // V load (K dead) + softmax, independent
  for (int i=tid;i<3072;i+=256){ int t=i>>7, c=i&127; A2[t][c]=b2f(V[base+i]); }
  if (tid < 192) {
    int hh = tid/24, t = tid - (tid/24)*24;
    float m = -1e30f;
    for (int s_=0;s_<24;++s_) m = fmaxf(m, Sc[hh][t][s_]);
    float den = 0.f;
    for (int s_=0;s_<24;++s_){ float e = expf(Sc[hh][t][s_]-m); Sc[hh][t][s_] = e; den += e; }
    float inv = 1.f/den;
    for (int s_=0;s_<24;++s_) Sc[hh][t][s_] *= inv;
  }
  __syncthreads();
  for (int i=tid;i<3072;i+=256){
    int t = i >> 7; int o = i & 127; int hh = o >> 4;
    float s = 0.f;
    #pragma unroll
    for (int s_=0;s_<24;++s_) s += Sc[hh][t][s_]*A2[s_][o];
    A1[t][o] = s;   // xa overwrites Q
  }
  __syncthreads();
  float* xbar = &Sc[0][0][0];
  if (tid < 128) {
    float s = 0.f;
    for (int t=0;t<24;++t) s += fcw[t]*A1[t][tid];
    xbar[tid] = s;
  }
  __syncthreads();
  if (tid < 128) {
    int o = tid;
    float s = 0.f;
    for (int c=0;c<128;++c) s += xbar[c]*ow[o*128 + c];
    float sfc = 0.f;
    for (int t=0;t<24;++t) sfc += fcw[t];
    out2f[(size_t)bn*128 + o] = s + sfc*ob[o] + fcb[0];
  }
}

__global__ void k_rbar(const float* out2, const float* rw, float* rbar) {
  int i = blockIdx.x*256 + threadIdx.x;
  if (i >= 512000) return;
  int c = i & 127; int bnn = i >> 7; int b = bnn/500, n = bnn - b*500;
  float s = 0.f;
  #pragma unroll
  for (int t=0;t<24;++t) s += rw[t] * out2[((size_t)(b*24 + t)*500 + n)*128 + c];
  rbar[i] = s;
}

__global__ void k_te(const float* tt, const float* w1, const float* b1,
                     const float* w2, const float* b2, float* te) {
  __shared__ float h1[128];
  int b = blockIdx.x; int o = threadIdx.x;
  float s = b1[o];
  for (int c=0;c<32;++c) s += tt[b*32 + c]*w1[o*32 + c];
  h1[o] = fmaxf(s, 0.f);
  __syncthreads();
  float s2 = b2[o];
  for (int c=0;c<128;++c) s2 += h1[c]*w2[o*128 + c];
  te[b*128 + o] = s2;
}

__global__ void k_grid(const float* gnm, const float* fin, float* out) {
  int e = threadIdx.x & 63; int gq = threadIdx.x >> 6;
  int g = blockIdx.x*4 + gq; int b = blockIdx.y;
  float s = 0.f;
  const float* gr = gnm + (size_t)g*500;
  const float* fb = fin + (size_t)b*500*64 + e;
  for (int n=0;n<500;++n) s += gr[n] * fb[(size_t)n*64];
  out[(size_t)b*32000 + (size_t)e*500 + g] = s;
}

// ---------------- launch ----------------
extern "C" void kernel_launch(void* const* d_in, const int* in_sizes, int n_in,
                              void* d_out, int out_size, void* d_ws, size_t ws_size,
                              hipStream_t stream) {
  const float* adj   = (const float*)d_in[0];
  const float* x     = (const float*)d_in[1];
  const float* gnm   = (const float*)d_in[2];
  const float* ttime = (const float*)d_in[3];
  const float* emb   = (const float*)d_in[4];
  const float* wp0   = (const float*)d_in[5];
  const float* bp0   = (const float*)d_in[6];
  const float* a0f1w = (const float*)d_in[7];
  const float* a0f1b = (const float*)d_in[8];
  const float* a0f2w = (const float*)d_in[9];
  const float* a0f2b = (const float*)d_in[10];
  const float* wp1   = (const float*)d_in[11];
  const float* bp1   = (const float*)d_in[12];
  const float* a1f1w = (const float*)d_in[13];
  const float* a1f1b = (const float*)d_in[14];
  const float* a1f2w = (const float*)d_in[15];
  const float* a1f2b = (const float*)d_in[16];
  const float* bn0g  = (const float*)d_in[17];
  const float* bn0b  = (const float*)d_in[18];
  const float* bn1g  = (const float*)d_in[19];
  const float* bn1b  = (const float*)d_in[20];
  const float* wih   = (const float*)d_in[21];
  const float* whh   = (const float*)d_in[22];
  const float* bih   = (const float*)d_in[23];
  const float* bhh   = (const float*)d_in[24];
  const float* bgg   = (const float*)d_in[25];
  const float* bgb   = (const float*)d_in[26];
  const float* cqw   = (const float*)d_in[27];
  const float* cqb   = (const float*)d_in[28];
  const float* ckw   = (const float*)d_in[29];
  const float* ckb   = (const float*)d_in[30];
  const float* vw    = (const float*)d_in[31];
  const float* vb    = (const float*)d_in[32];
  const float* ow    = (const float*)d_in[33];
  const float* ob    = (const float*)d_in[34];
  const float* r1w   = (const float*)d_in[35];
  const float* r1b   = (const float*)d_in[36];
  const float* fcw   = (const float*)d_in[37];
  const float* fcb   = (const float*)d_in[38];
  const float* rcw   = (const float*)d_in[39];
  const float* rcb   = (const float*)d_in[40];
  const float* r2w   = (const float*)d_in[41];
  const float* r2b   = (const float*)d_in[42];
  const float* bnrg  = (const float*)d_in[43];
  const float* bnrb  = (const float*)d_in[44];
  const float* te1w  = (const float*)d_in[45];
  const float* te1b  = (const float*)d_in[46];
  const float* te2w  = (const float*)d_in[47];
  const float* te2b  = (const float*)d_in[48];
  const float* finw  = (const float*)d_in[49];
  const float* finb  = (const float*)d_in[50];
  float* dout = (float*)d_out;
  float* W = (float*)d_ws;

  size_t off = 0;
  auto alloc = [&](size_t n){ size_t r = off; off += (n + 255) & ~(size_t)255; return r; };
  size_t oStats = alloc(512);
  size_t oPool  = alloc(24576);
  size_t oAmix  = alloc(1536);
  size_t oTe    = alloc(1024);
  size_t oO2f   = alloc(512000);
  size_t oRbar  = alloc(512000);
  size_t oRes   = alloc(512000);
  size_t oFin   = alloc(256000);
  size_t oNe0   = alloc(768000);
  size_t oNe1   = alloc(768000);
  size_t oS2    = alloc(125000);     // bf16 [500][500]
  size_t oWp0p  = alloc(98304);      // bf16 [128][1536]
  size_t oWp1p  = alloc(196608);     // bf16 [128][3072]
  size_t oR1wp  = alloc(4096);       // bf16 [128][64]
  size_t oWihp  = alloc(24576);      // bf16 [384][128]
  size_t oVwp   = alloc(8192);       // bf16 [128][128]
  size_t oCqwp  = alloc(24576);      // bf16 [128][384]
  size_t oCkwp  = alloc(24576);      // bf16 [128][384]
  size_t oR2wp  = alloc(8192);       // bf16 [128][128]
  size_t oFinwp = alloc(4096);       // bf16 [64][128]
  size_t oR1    = alloc(12288000);   // out0 -> out2 -> hs
  size_t oR2    = alloc(12288000);   // XG pairs -> gi(low) -> Q,K   (must precede R4, contiguous)
  size_t oR4    = alloc(6144000);    // Xn -> Y0bf -> gi(high) -> V
  size_t oOut1  = alloc(6144000);    // YT -> out1
  (void)n_in; (void)in_sizes; (void)out_size;
  if (ws_size < off * sizeof(float)) return;

  float* stats = W + oStats;
  float* pooled= W + oPool;
  float* amix  = W + oAmix;
  float* teb   = W + oTe;
  float* out2f = W + oO2f;
  float* rbar  = W + oRbar;
  float* resout= W + oRes;
  float* fin   = W + oFin;
  float* ne0   = W + oNe0;
  float* ne1   = W + oNe1;
  ushort_t* S2bf  = (ushort_t*)(W + oS2);
  ushort_t* wp0p  = (ushort_t*)(W + oWp0p);
  ushort_t* wp1p  = (ushort_t*)(W + oWp1p);
  ushort_t* r1wp  = (ushort_t*)(W + oR1wp);
  ushort_t* wihp  = (ushort_t*)(W + oWihp);
  ushort_t* vwp   = (ushort_t*)(W + oVwp);
  ushort_t* cqwp  = (ushort_t*)(W + oCqwp);
  ushort_t* ckwp  = (ushort_t*)(W + oCkwp);
  ushort_t* r2wp  = (ushort_t*)(W + oR2wp);
  ushort_t* finwp = (ushort_t*)(W + oFinwp);
  float* out0  = W + oR1;
  float* out2  = W + oR1;
  float* hs    = W + oR1;
  ushort_t* XG1n = (ushort_t*)(W + oR2);
  ushort_t* XG2n = XG1n + 6144000;
  ushort_t* XGB1 = (ushort_t*)(W + oR2);
  ushort_t* XGB2 = XGB1 + 12288000;
  ushort_t* gi16 = (ushort_t*)(W + oR2);     // spans R2+R4 (contiguous)
  ushort_t* Qbf  = (ushort_t*)(W + oR2);
  ushort_t* Kbf  = Qbf + 12288000;
  ushort_t* Vbf  = Kbf + 12288000;           // = start of R4
  ushort_t* Xnbf = (ushort_t*)(W + oR4);
  ushort_t* Y0bf = (ushort_t*)(W + oR4);
  ushort_t* YT   = (ushort_t*)(W + oOut1);   // dead before out1 written
  ushort_t* out1 = (ushort_t*)(W + oOut1);

  // ---- weight packing (independent) ----
  k_pack_wp<<<768, 256, 0, stream>>>(wp0, wp0p, 64, 1536);
  k_pack_wp<<<1536, 256, 0, stream>>>(wp1, wp1p, 128, 3072);
  k_pack_bf<<<32, 256, 0, stream>>>(r1w, r1wp, 8192);
  k_pack_bf<<<192, 256, 0, stream>>>(wih, wihp, 49152);
  k_pack_bf<<<64, 256, 0, stream>>>(vw, vwp, 16384);
  k_pack_bf<<<64, 256, 0, stream>>>(r2w, r2wp, 16384);
  k_pack_bf<<<32, 256, 0, stream>>>(finw, finwp, 8192);
  k_pack_convw<<<192, 256, 0, stream>>>(cqw, cqwp);
  k_pack_convw<<<192, 256, 0, stream>>>(ckw, ckwp);

  // ---- Phase A ----
  k_transpose_bf<<<dim3(16,384), dim3(32,8), 0, stream>>>(x, Xnbf, 12288, 500);
  gemm_mfma<true><<<dim3(4,4), 256, 0, stream>>>(
      AgF32{adj,500}, BgAdjB{adj}, EpS2{}, (void*)S2bf, 500, 500, 500, 500);
  gemm_mfma<true><<<dim3(96,4), 256, 0, stream>>>(
      AgF32{adj,500}, BgXTv{x}, EpNone{}, (void*)XG1n, 500, 12288, 500, 12288);
  gemm_mfma<true><<<dim3(96,4), 256, 0, stream>>>(
      AgBf16p{S2bf,500}, BgXTv{x}, EpNone{}, (void*)XG2n, 500, 12288, 500, 12288);
  k_pool0<<<192, 64, 0, stream>>>(x, pooled);
  k_mlp<<<1, 192, 0, stream>>>(pooled, 64, a0f1w, a0f1b, a0f2w, a0f2b, amix);
  k_ne<<<3000, 256, 0, stream>>>(amix, emb, ne0);
  gemm_mfma<false><<<dim3(1,750), 256, 0, stream>>>(
      AgFlex0v{Xnbf, XG1n, XG2n, ne0}, BgPk{wp0p,1536}, EpNeBias{ne0, bp0},
      (void*)out0, 96000, 128, 1536, 128);
  hipMemsetAsync((void*)stats, 0, 256*sizeof(float), stream);
  k_bn_stats<<<768, 256, 0, stream>>>(out0, stats, 96000, 125);
  k_bn_apply4<<<12000, 256, 0, stream>>>(out0, out0, stats, bn0g, bn0b, 3072000, 1.f/96000.f, 1, 0);

  // ---- Phase B ----
  k_pool1<<<192, 128, 0, stream>>>(out0, pooled);
  k_mlp<<<1, 192, 0, stream>>>(pooled, 128, a1f1w, a1f1b, a1f2w, a1f2b, amix);
  k_ne<<<3000, 256, 0, stream>>>(amix, emb, ne1);
  k_copyY4<<<12000, 256, 0, stream>>>(out0, Y0bf);
  k_copyYT_bf<<<dim3(16,4,192), dim3(32,8), 0, stream>>>(out0, YT);
  gemm_mfma<true><<<dim3(192,4), 256, 0, stream>>>(
      AgF32{adj,500}, BgPk{YT,500}, EpNone{}, (void*)XGB1, 500, 24576, 500, 24576);
  gemm_mfma<true><<<dim3(192,4), 256, 0, stream>>>(
      AgBf16p{S2bf,500}, BgPk{YT,500}, EpNone{}, (void*)XGB2, 500, 24576, 500, 24576);
  gemm_mfma<true><<<dim3(1,750), 256, 0, stream>>>(
      AgFlex1v{Y0bf, XGB1, XGB2, ne1}, BgPk{wp1p,3072}, EpNeBias{ne1, bp1},
      (void*)out1, 96000, 128, 3072, 128);
  hipMemsetAsync((void*)stats, 0, 256*sizeof(float), stream);
  k_bn_stats_bf<<<768, 256, 0, stream>>>(out1, stats, 96000, 125);
  gemm_mfma<false><<<dim3(1,750), 256, 0, stream>>>(
      AgXrow{x}, BgPk{r1wp,64}, EpRes1{out1, stats, bn1g, bn1b, r1b, 1.f/96000.f},
      (void*)out2, 96000, 128, 64, 128);

  // ---- Phase E-part1 (consumes out2 early) ----
  k_rbar<<<2000, 256, 0, stream>>>(out2, rcw, rbar);
  gemm_mfma<false><<<dim3(1,32), 256, 0, stream>>>(
      AgF32{rbar,128}, BgPk{r2wp,128}, EpRes2{r2b, rcw, rcb}, (void*)resout, 4000, 128, 128, 128);
  hipMemsetAsync((void*)stats, 0, 256*sizeof(float), stream);
  k_bn_stats<<<32, 256, 0, stream>>>(resout, stats, 4000, 125);

  // ---- Phase C: gi on MFMA + recurrent GRU ----
  gemm_mfma<true><<<dim3(3,750), 256, 0, stream>>>(
      AgF32{out2,128}, BgPk{wihp,128}, EpBias{bih}, (void*)gi16, 96000, 384, 128, 384);
  k_gru3<<<500, 384, 0, stream>>>(gi16, whh, bhh, hs);
  hipMemsetAsync((void*)(stats+256), 0, 256*sizeof(float), stream);
  k_bn_stats<<<768, 256, 0, stream>>>(hs, stats+256, 96000, 125);
  k_bn_apply4<<<12000, 256, 0, stream>>>(hs, hs, stats+256, bgg, bgb, 3072000, 1.f/96000.f, 1, 0);

  // ---- Phase D ----
  gemm_mfma<true><<<dim3(1,750), 256, 0, stream>>>(
      AgConv{hs}, BgPk{cqwp,384}, EpBias{cqb}, (void*)Qbf, 96000, 128, 384, 128);
  gemm_mfma<true><<<dim3(1,750), 256, 0, stream>>>(
      AgConv{hs}, BgPk{ckwp,384}, EpBias{ckb}, (void*)Kbf, 96000, 128, 384, 128);
  gemm_mfma<true><<<dim3(1,750), 256, 0, stream>>>(
      AgF32{hs,128}, BgPk{vwp,128}, EpBias{vb}, (void*)Vbf, 96000, 128, 128, 128);
  k_attn3<<<4000, 256, 0, stream>>>(Qbf, Kbf, Vbf, ow, ob, fcw, fcb, out2f);

  // ---- Phase E-part2 ----
  k_bn_apply4<<<500, 256, 0, stream>>>(out2f, resout, stats, bnrg, bnrb, 128000, 1.f/4000.f, 0, 1);
  k_te<<<8, 128, 0, stream>>>(ttime, te1w, te1b, te2w, te2b, teb);
  gemm_mfma<false><<<dim3(1,32), 256, 0, stream>>>(
      AgTeAdd{out2f, teb}, BgPk{finwp,128}, EpBias{finb}, (void*)fin, 4000, 64, 128, 64);
  k_grid<<<dim3(125,8), 256, 0, stream>>>(gnm, fin, dout);
}

// Round 10
// 1821.634 us; speedup vs baseline: 6.0399x; 1.1616x over previous
//
#include <hip/hip_runtime.h>
#include <math.h>

using short8 = __attribute__((ext_vector_type(8))) short;
using f32x4  = __attribute__((ext_vector_type(4))) float;
using ushort_t = unsigned short;

__device__ __forceinline__ ushort_t f2b(float f){
  unsigned int u = __builtin_bit_cast(unsigned int, f);
  u = (u + 0x7fffu + ((u >> 16) & 1u)) >> 16;
  return (ushort_t)u;
}
__device__ __forceinline__ float b2f(ushort_t u){
  unsigned int v = ((unsigned int)u) << 16;
  return __builtin_bit_cast(float, v);
}
__device__ __forceinline__ uint2 pk4(float a, float b, float c, float d){
  uint2 p; p.x = (unsigned)f2b(a) | ((unsigned)f2b(b)<<16);
  p.y = (unsigned)f2b(c) | ((unsigned)f2b(d)<<16); return p;
}
__device__ __forceinline__ uint2 z2(){ return uint2{0u,0u}; }

// ---------------- A generators: load4p(r, k, K) -> 4 packed bf16 ----------------
struct AgF32 { const float* A; int lda;
  __device__ uint2 load4p(int r, int k, int K) const {
    const float* p = &A[(size_t)r*lda + k];
    if (k+3 < K) { float4 v = *(const float4*)p; return pk4(v.x,v.y,v.z,v.w); }
    float a=0,b=0,c=0,d=0;
    if (k   < K) a = p[0];
    if (k+1 < K) b = p[1];
    if (k+2 < K) c = p[2];
    if (k+3 < K) d = p[3];
    return pk4(a,b,c,d); } };
struct AgBf16p { const ushort_t* A; int lda;
  __device__ uint2 load4p(int r, int k, int K) const {
    const ushort_t* p = &A[(size_t)r*lda + k];
    if (k+3 < K) return *(const uint2*)p;
    ushort_t a=0,b=0,c=0,d=0;
    if (k   < K) a = p[0];
    if (k+1 < K) b = p[1];
    if (k+2 < K) c = p[2];
    if (k+3 < K) d = p[3];
    uint2 q; q.x = (unsigned)a | ((unsigned)b<<16); q.y = (unsigned)c | ((unsigned)d<<16);
    return q; } };
struct AgStackA { const float* adj; const ushort_t* s2;   // rows<500: adj f32; >=500: S2 bf16
  __device__ uint2 load4p(int r, int k, int K) const {
    if (r < 500) {
      float a=0,b=0,c=0,d=0;
      const float* p = adj + (size_t)r*500 + k;
      if (k+3 < K) { float4 v = *(const float4*)p; return pk4(v.x,v.y,v.z,v.w); }
      if (k   < K) a = p[0];
      if (k+1 < K) b = p[1];
      if (k+2 < K) c = p[2];
      if (k+3 < K) d = p[3];
      return pk4(a,b,c,d);
    }
    const ushort_t* p = s2 + (size_t)(r-500)*500 + k;
    if (k+3 < K) return *(const uint2*)p;
    ushort_t a=0,b=0,c=0,d=0;
    if (k   < K) a = p[0];
    if (k+1 < K) b = p[1];
    if (k+2 < K) c = p[2];
    if (k+3 < K) d = p[3];
    uint2 q; q.x = (unsigned)a | ((unsigned)b<<16); q.y = (unsigned)c | ((unsigned)d<<16);
    return q; } };
struct AgXrow { const float* x;  // row=bt*500+n, k=c : x[bt,c,n]
  __device__ uint2 load4p(int r, int k, int K) const {
    int bt = r/500, n = r - bt*500;
    const float* p = x + (size_t)bt*32000 + n;
    float a=0,b=0,c=0,d=0;
    if (k   < K) a = p[(size_t)k*500];
    if (k+1 < K) b = p[(size_t)(k+1)*500];
    if (k+2 < K) c = p[(size_t)(k+2)*500];
    if (k+3 < K) d = p[(size_t)(k+3)*500];
    return pk4(a,b,c,d); } };
struct AgFlex0v { const ushort_t* Xn; const ushort_t* XG1; const ushort_t* XG2; const float* ne;
  __device__ uint2 load4p(int r, int k4, int) const {
    int d0 = k4 & 7; int kc = k4 >> 3; int k = kc >> 6; int c = kc & 63;
    int bt = r/500, n = r - bt*500;
    const ushort_t* s = (k==0)? Xn : (k==1)? XG1 : XG2;
    float v = b2f(s[(size_t)n*12288 + bt*64 + c]);
    float4 ne4 = *(const float4*)&ne[(size_t)r*8 + d0];
    return pk4(v*ne4.x, v*ne4.y, v*ne4.z, v*ne4.w); } };
struct AgFlex1v { const ushort_t* Y0; const ushort_t* XG1; const ushort_t* XG2; const float* ne;
  __device__ uint2 load4p(int r, int k4, int) const {
    int d0 = k4 & 7; int kc = k4 >> 3; int k = kc >> 7; int c = kc & 127;
    int bt = r/500, n = r - bt*500;
    const ushort_t* s = (k==0)? Y0 : (k==1)? XG1 : XG2;
    float v = b2f(s[(size_t)n*24576 + bt*128 + c]);
    float4 ne4 = *(const float4*)&ne[(size_t)r*8 + d0];
    return pk4(v*ne4.x, v*ne4.y, v*ne4.z, v*ne4.w); } };
struct AgConvB { const ushort_t* hs; // bf16 hs; rows bn*24+t, k = dt*128+c
  __device__ uint2 load4p(int r, int k, int) const {
    int t = r % 24; int dt = k >> 7; int c = k & 127; int t2 = t + dt - 1;
    if (t2 < 0 || t2 >= 24) return z2();
    return *(const uint2*)&hs[(size_t)(r + (t2 - t))*128 + c]; } };
struct AgTeAdd { const float* o2f; const float* te;
  __device__ uint2 load4p(int r, int k, int) const {
    float4 a = *(const float4*)&o2f[(size_t)r*128 + k];
    float4 b = *(const float4*)&te[(size_t)(r/500)*128 + k];
    return pk4(a.x+b.x, a.y+b.y, a.z+b.z, a.w+b.w); } };

// ---------------- B generators: load4p(c, k, K) ----------------
struct BgPk { const ushort_t* B; int ldb;   // packed bf16 [N][K], k-contiguous
  __device__ uint2 load4p(int c, int k, int K) const {
    const ushort_t* p = &B[(size_t)c*ldb + k];
    if (k+3 < K) return *(const uint2*)p;
    ushort_t a=0,b=0,cc=0,d=0;
    if (k   < K) a = p[0];
    if (k+1 < K) b = p[1];
    if (k+2 < K) cc = p[2];
    if (k+3 < K) d = p[3];
    uint2 q; q.x = (unsigned)a | ((unsigned)b<<16); q.y = (unsigned)cc | ((unsigned)d<<16);
    return q; } };
struct BgXTv { const float* x;   // B[k][c]=x[c*500+k]
  __device__ uint2 load4p(int c, int k, int K) const {
    const float* p = x + (size_t)c*500 + k;
    if (k+3 < K) { float4 v = *(const float4*)p; return pk4(v.x,v.y,v.z,v.w); }
    float a=0,b=0,cc=0,d=0;
    if (k   < K) a = p[0];
    if (k+1 < K) b = p[1];
    if (k+2 < K) cc = p[2];
    if (k+3 < K) d = p[3];
    return pk4(a,b,cc,d); } };
struct BgAdjB { const float* adj;   // B[k][c]=adj[k*500+c]
  __device__ uint2 load4p(int c, int k, int K) const {
    float a=0,b=0,cc=0,d=0;
    if (k   < K) a = adj[(size_t)k*500 + c];
    if (k+1 < K) b = adj[(size_t)(k+1)*500 + c];
    if (k+2 < K) cc = adj[(size_t)(k+2)*500 + c];
    if (k+3 < K) d = adj[(size_t)(k+3)*500 + c];
    return pk4(a,b,cc,d); } };

// ---------------- epilogues ----------------
struct EpNone { __device__ float operator()(int, int, float a) const { return a; } };
struct EpS2   { __device__ float operator()(int r, int c, float a) const { return 2.f*a - (r==c ? 1.f : 0.f); } };
struct EpBias { const float* b;
  __device__ float operator()(int, int c, float a) const { return a + b[c]; } };
struct EpNeBias { const float* ne; const float* bp;
  __device__ float operator()(int r, int c, float a) const {
    float s = a;
    #pragma unroll
    for (int d=0; d<8; ++d) s += ne[(size_t)r*8 + d]*bp[d*128 + c];
    return s; } };
struct EpRes1 { const ushort_t* out1; const float* st; const float *g, *bb, *rb; float invM;
  __device__ float operator()(int r, int c, float a) const {
    float mean = st[c]*invM; float var = st[128+c]*invM - mean*mean;
    float rstd = rsqrtf(var + 1e-5f);
    float y = (b2f(out1[(size_t)r*128 + c]) - mean)*rstd*g[c] + bb[c];
    y = fmaxf(y, 0.f);
    return a + rb[c] + y; } };
struct EpRes2 { const float *r2b, *rw, *rcb;
  __device__ float operator()(int, int c, float a) const {
    float s = 0.f;
    #pragma unroll
    for (int t=0; t<24; ++t) s += rw[t];
    return a + s*r2b[c] + rcb[0]; } };

// ---------------- pipelined MFMA generator GEMM ----------------
template<bool BOUT, class AG, class BG, class EP>
__global__ __launch_bounds__(256)
void gemm_mfma(AG ag, BG bg, EP ep, void* Cv, int M, int N, int K, int ldc) {
  constexpr int LDA = 40;
  __shared__ ushort_t As[128*LDA];
  __shared__ ushort_t Bs[128*LDA];
  int tid = threadIdx.x;
  int lane = tid & 63, wave = tid >> 6;
  int wr = (wave >> 1) * 64, wc = (wave & 1) * 64;
  int q = lane >> 4, r16 = lane & 15;
  int row0 = blockIdx.y*128, col0 = blockIdx.x*128;
  int am = tid >> 3, ak = (tid & 7) * 4;
  uint2 ua[4], ub[4];
  int nK = (K + 31) / 32;
  #pragma unroll
  for (int s=0;s<4;++s){
    int gr = row0 + am + 32*s;
    ua[s] = (gr < M) ? ag.load4p(gr, ak, K) : z2();
    int gc = col0 + am + 32*s;
    ub[s] = (gc < N) ? bg.load4p(gc, ak, K) : z2();
  }
  f32x4 acc[4][4] = {};
  for (int t=0; t<nK; ++t) {
    #pragma unroll
    for (int s=0;s<4;++s){
      *(uint2*)&As[(am + 32*s)*LDA + ak] = ua[s];
      *(uint2*)&Bs[(am + 32*s)*LDA + ak] = ub[s];
    }
    __syncthreads();
    if (t+1 < nK) {
      int k0 = (t+1)*32;
      #pragma unroll
      for (int s=0;s<4;++s){
        int gr = row0 + am + 32*s;
        ua[s] = (gr < M) ? ag.load4p(gr, k0+ak, K) : z2();
        int gc = col0 + am + 32*s;
        ub[s] = (gc < N) ? bg.load4p(gc, k0+ak, K) : z2();
      }
    }
    short8 a[4], b[4];
    #pragma unroll
    for (int it=0;it<4;++it) a[it] = *(const short8*)&As[(wr + it*16 + r16)*LDA + q*8];
    #pragma unroll
    for (int jt=0;jt<4;++jt) b[jt] = *(const short8*)&Bs[(wc + jt*16 + r16)*LDA + q*8];
    #pragma unroll
    for (int it=0;it<4;++it)
      #pragma unroll
      for (int jt=0;jt<4;++jt)
        acc[it][jt] = __builtin_amdgcn_mfma_f32_16x16x32_bf16(a[it], b[jt], acc[it][jt], 0, 0, 0);
    __syncthreads();
  }
  #pragma unroll
  for (int it=0;it<4;++it) {
    #pragma unroll
    for (int v=0;v<4;++v) {
      int rr = row0 + wr + it*16 + q*4 + v;
      if (rr >= M) continue;
      #pragma unroll
      for (int jt=0;jt<4;++jt) {
        int c = col0 + wc + jt*16 + r16;
        if (c >= N) continue;
        float val = ep(rr, c, acc[it][jt][v]);
        if (BOUT) ((ushort_t*)Cv)[(size_t)rr*ldc + c] = f2b(val);
        else      ((float*)Cv)[(size_t)rr*ldc + c] = val;
      }
    }
  }
}

// ---------------- packing kernels ----------------
__global__ void k_pack_bf(const float* s, ushort_t* d, int n){
  int i = blockIdx.x*256 + threadIdx.x; if (i < n) d[i] = f2b(s[i]); }
__global__ void k_pack_wp(const float* wp, ushort_t* d, int C, int K){
  int i = blockIdx.x*256 + threadIdx.x; int total = 128*K; if (i >= total) return;
  int o = i / K; int kp = i - o*K; int dd = kp & 7; int kc = kp >> 3;
  int kk = kc / C; int cin = kc - kk*C;
  d[i] = f2b(wp[(((size_t)dd*3 + kk)*C + cin)*128 + o]); }
__global__ void k_pack_qkvw(const float* cqw, const float* ckw, const float* vw, ushort_t* d){
  // d[o*384 + dt*128 + cin]; o<128: cq, o<256: ck, else vw at dt==1
  int i = blockIdx.x*256 + threadIdx.x; if (i >= 147456) return;
  int o = i / 384; int r = i - o*384; int dt = r >> 7; int cin = r & 127;
  float v;
  if (o < 128) v = cqw[((size_t)o*128 + cin)*3 + dt];
  else if (o < 256) v = ckw[((size_t)(o-128)*128 + cin)*3 + dt];
  else v = (dt==1) ? vw[(size_t)(o-256)*128 + cin] : 0.f;
  d[i] = f2b(v); }
__global__ void k_pack_qkvb(const float* cqb, const float* ckb, const float* vb, float* d){
  int i = threadIdx.x; // 384
  d[i] = (i<128) ? cqb[i] : (i<256) ? ckb[i-128] : vb[i-256]; }

// ---------------- small kernels ----------------
__global__ void k_transpose_bf(const float* src, ushort_t* dst, int R, int Cc) {
  __shared__ float tile[32][33];
  int c0 = blockIdx.x*32, r0 = blockIdx.y*32;
  int tx = threadIdx.x, ty = threadIdx.y;
  for (int i = ty; i < 32; i += 8) {
    int r = r0+i, c = c0+tx;
    if (r < R && c < Cc) tile[i][tx] = src[(size_t)r*Cc + c];
  }
  __syncthreads();
  for (int i = ty; i < 32; i += 8) {
    int dr = c0 + i, dc = r0 + tx;
    if (dr < Cc && dc < R) dst[(size_t)dr*R + dc] = f2b(tile[tx][i]);
  }
}

__global__ void k_copyY4(const float* out0, ushort_t* Y) {
  int i = blockIdx.x*256 + threadIdx.x;
  if (i >= 3072000) return;
  int i4 = i*4;
  int o = i4 & 127; int r = i4 >> 7; int btl = r % 192; int n = r / 192;
  float4 v = *(const float4*)&out0[((size_t)btl*500 + n)*128 + o];
  *(uint2*)&Y[i4] = pk4(v.x,v.y,v.z,v.w);
}

__global__ void k_copyYT_bf(const float* out0, ushort_t* YT) {
  __shared__ float tile[32][33];
  int bt = blockIdx.z; int n0 = blockIdx.x*32; int o0 = blockIdx.y*32;
  int tx = threadIdx.x, ty = threadIdx.y;
  for (int i = ty; i < 32; i += 8) {
    int n = n0 + i;
    if (n < 500) tile[i][tx] = out0[((size_t)bt*500 + n)*128 + o0 + tx];
  }
  __syncthreads();
  for (int i = ty; i < 32; i += 8) {
    int o = o0 + i; int n = n0 + tx;
    if (n < 500) YT[((size_t)bt*128 + o)*500 + n] = f2b(tile[tx][i]);
  }
}

__global__ void k_pool0(const float* x, float* pooled) {
  int bt = blockIdx.x; int c = threadIdx.x;
  const float* p = x + (size_t)bt*32000 + (size_t)c*500;
  float s = 0.f;
  for (int n=0;n<500;++n) s += p[n];
  pooled[bt*64 + c] = s*(1.f/500.f);
}
__global__ void k_pool1(const float* src, float* pooled) {
  int bt = blockIdx.x; int o = threadIdx.x;
  float s = 0.f;
  for (int n=0;n<500;++n) s += src[((size_t)bt*500 + n)*128 + o];
  pooled[bt*128 + o] = s*(1.f/500.f);
}

__global__ void k_mlp(const float* pooled, int F, const float* f1w, const float* f1b,
                      const float* f2w, const float* f2b, float* aout) {
  int bt = threadIdx.x;
  if (bt >= 192) return;
  float h[8];
  for (int k=0;k<8;++k){
    float s = f1b[k];
    for (int c=0;c<F;++c) s += pooled[bt*F + c]*f1w[k*F + c];
    h[k] = fmaxf(s, 0.f);
  }
  float z[8]; float m = -1e30f;
  for (int k2=0;k2<8;++k2){
    float s = f2b[k2];
    for (int k=0;k<8;++k) s += h[k]*f2w[k2*8 + k];
    z[k2] = s; m = fmaxf(m, s);
  }
  float den = 0.f;
  for (int k2=0;k2<8;++k2){ z[k2] = expf(z[k2]-m); den += z[k2]; }
  float inv = 1.f/den;
  for (int k2=0;k2<8;++k2) aout[bt*8 + k2] = z[k2]*inv;
}

__global__ void k_ne(const float* a, const float* emb, float* ne) {
  int i = blockIdx.x*256 + threadIdx.x;
  if (i >= 768000) return;
  int d = i & 7; int rem = i >> 3; int n = rem % 500; int bt = rem / 500;
  float s = 0.f;
  #pragma unroll
  for (int k=0;k<8;++k) s += a[bt*8 + k]*emb[((size_t)k*500 + n)*8 + d];
  ne[i] = s;
}

__global__ void k_bn_stats(const float* src, float* stats, int M, int rpb) {
  int col = threadIdx.x & 127; int seg = threadIdx.x >> 7;
  int r0 = blockIdx.x * rpb; int r1 = r0 + rpb; if (r1 > M) r1 = M;
  float s = 0.f, q = 0.f;
  for (int r = r0 + seg; r < r1; r += 2) {
    float v = src[(size_t)r*128 + col];
    s += v; q += v*v;
  }
  atomicAdd(&stats[col], s);
  atomicAdd(&stats[128+col], q);
}
__global__ void k_bn_stats_bf(const ushort_t* src, float* stats, int M, int rpb) {
  int col = threadIdx.x & 127; int seg = threadIdx.x >> 7;
  int r0 = blockIdx.x * rpb; int r1 = r0 + rpb; if (r1 > M) r1 = M;
  float s = 0.f, q = 0.f;
  for (int r = r0 + seg; r < r1; r += 2) {
    float v = b2f(src[(size_t)r*128 + col]);
    s += v; q += v*v;
  }
  atomicAdd(&stats[col], s);
  atomicAdd(&stats[128+col], q);
}

__global__ void k_bn_apply4(float* dst, const float* src, const float* st,
                            const float* g, const float* b, int total4, float invM, int relu, int addd) {
  int i = blockIdx.x*256 + threadIdx.x;
  if (i >= total4) return;
  int i4 = i*4; int c = i4 & 127;
  float4 sm = *(const float4*)&st[c];
  float4 sq = *(const float4*)&st[128+c];
  float4 g4 = *(const float4*)&g[c];
  float4 b4 = *(const float4*)&b[c];
  float4 v = *(const float4*)&src[i4];
  float4 y;
  {
    float mean = sm.x*invM; float var = sq.x*invM - mean*mean;
    y.x = (v.x-mean)*rsqrtf(var+1e-5f)*g4.x + b4.x;
    mean = sm.y*invM; var = sq.y*invM - mean*mean;
    y.y = (v.y-mean)*rsqrtf(var+1e-5f)*g4.y + b4.y;
    mean = sm.z*invM; var = sq.z*invM - mean*mean;
    y.z = (v.z-mean)*rsqrtf(var+1e-5f)*g4.z + b4.z;
    mean = sm.w*invM; var = sq.w*invM - mean*mean;
    y.w = (v.w-mean)*rsqrtf(var+1e-5f)*g4.w + b4.w;
  }
  if (relu){ y.x=fmaxf(y.x,0.f); y.y=fmaxf(y.y,0.f); y.z=fmaxf(y.z,0.f); y.w=fmaxf(y.w,0.f); }
  if (addd){ float4 d0 = *(const float4*)&dst[i4]; y.x+=d0.x; y.y+=d0.y; y.z+=d0.z; y.w+=d0.w; }
  *(float4*)&dst[i4] = y;
}

// BN apply + relu, f32 src -> bf16 dst
__global__ void k_bn_apply_bf(ushort_t* dst, const float* src, const float* st,
                              const float* g, const float* b, int total4, float invM) {
  int i = blockIdx.x*256 + threadIdx.x;
  if (i >= total4) return;
  int i4 = i*4; int c = i4 & 127;
  float4 sm = *(const float4*)&st[c];
  float4 sq = *(const float4*)&st[128+c];
  float4 g4 = *(const float4*)&g[c];
  float4 b4 = *(const float4*)&b[c];
  float4 v = *(const float4*)&src[i4];
  float4 y;
  float mean = sm.x*invM; float var = sq.x*invM - mean*mean;
  y.x = (v.x-mean)*rsqrtf(var+1e-5f)*g4.x + b4.x;
  mean = sm.y*invM; var = sq.y*invM - mean*mean;
  y.y = (v.y-mean)*rsqrtf(var+1e-5f)*g4.y + b4.y;
  mean = sm.z*invM; var = sq.z*invM - mean*mean;
  y.z = (v.z-mean)*rsqrtf(var+1e-5f)*g4.z + b4.z;
  mean = sm.w*invM; var = sq.w*invM - mean*mean;
  y.w = (v.w-mean)*rsqrtf(var+1e-5f)*g4.w + b4.w;
  y.x=fmaxf(y.x,0.f); y.y=fmaxf(y.y,0.f); y.z=fmaxf(y.z,0.f); y.w=fmaxf(y.w,0.f);
  *(uint2*)&dst[i4] = pk4(y.x,y.y,y.z,y.w);
}

// recurrent-only GRU
__global__ __launch_bounds__(384) void k_gru3(const ushort_t* gi, const float* whh,
    const float* bhh, float* hs) {
  __shared__ float h[8][132];
  __shared__ float uh[8][388];
  int tid = threadIdx.x;
  int bn0 = blockIdx.x*8;
  for (int i=tid;i<1024;i+=384) h[i>>7][i&127] = 0.f;
  __syncthreads();
  int j = tid;
  float bh = bhh[j];
  const float* wh = whh + (size_t)j*128;
  for (int t=0;t<24;++t) {
    float ah[8];
    #pragma unroll
    for (int r=0;r<8;++r) ah[r]=bh;
    for (int c=0;c<128;c+=4){
      float4 w4h = *(const float4*)&wh[c];
      #pragma unroll
      for (int r=0;r<8;++r){
        float4 hv = *(const float4*)&h[r][c];
        ah[r] += hv.x*w4h.x + hv.y*w4h.y + hv.z*w4h.z + hv.w*w4h.w;
      }
    }
    #pragma unroll
    for (int r=0;r<8;++r) uh[r][j]=ah[r];
    __syncthreads();
    for (int i=tid;i<1024;i+=384){
      int r=i>>7, u=i&127;
      int bnn = bn0 + r; int b = bnn/500, n = bnn - b*500;
      size_t gbase = ((size_t)(b*24 + t)*500 + n)*384;
      float ir=b2f(gi[gbase+u]), iz=b2f(gi[gbase+128+u]), inn=b2f(gi[gbase+256+u]);
      float hr=uh[r][u], hz=uh[r][128+u], hn=uh[r][256+u];
      float rg = 1.f/(1.f+expf(-(ir+hr)));
      float zg = 1.f/(1.f+expf(-(iz+hz)));
      float ng = tanhf(inn + rg*hn);
      float hnew = (1.f-zg)*ng + zg*h[r][u];
      h[r][u] = hnew;
      hs[((size_t)bnn*24 + t)*128 + u] = hnew;
    }
    __syncthreads();
  }
}

// attention over interleaved QKV [r][384]
__global__ __launch_bounds__(256) void k_attn3(const ushort_t* QKV,
    const float* ow, const float* ob, const float* fcw, const float* fcb, float* out2f) {
  __shared__ float A1[24][132];
  __shared__ float A2[24][132];
  __shared__ float Sc[8][24][25];
  int bn = blockIdx.x; int tid = threadIdx.x;
  size_t base = (size_t)bn*9216;   // 24*384
  for (int i=tid;i<3072;i+=256){
    int t=i>>7, c=i&127;
    A1[t][c]=b2f(QKV[base + (size_t)t*384 + c]);
    A2[t][c]=b2f(QKV[base + (size_t)t*384 + 128 + c]);
  }
  __syncthreads();
  for (int i=tid;i<4608;i+=256){
    int hh = i/576; int r = i - hh*576; int t = r/24; int s_ = r - t*24;
    float d = 0.f;
    #pragma unroll
    for (int dd=0;dd<16;++dd) d += A1[t][hh*16+dd]*A2[s_][hh*16+dd];
    Sc[hh][t][s_] = d*0.25f;
  }
  __syncthreads();
  for (int i=tid;i<3072;i+=256){ int t=i>>7, c=i&127;
    A2[t][c]=b2f(QKV[base + (size_t)t*384 + 256 + c]); }
  if (tid < 192) {
    int hh = tid/24, t = tid - (tid/24)*24;
    float m = -1e30f;
    for (int s_=0;s_<24;++s_) m = fmaxf(m, Sc[hh][t][s_]);
    float den = 0.f;
    for (int s_=0;s_<24;++s_){ float e = expf(Sc[hh][t][s_]-m); Sc[hh][t][s_] = e; den += e; }
    float inv = 1.f/den;
    for (int s_=0;s_<24;++s_) Sc[hh][t][s_] *= inv;
  }
  __syncthreads();
  for (int i=tid;i<3072;i+=256){
    int t = i >> 7; int o = i & 127; int hh = o >> 4;
    float s = 0.f;
    #pragma unroll
    for (int s_=0;s_<24;++s_) s += Sc[hh][t][s_]*A2[s_][o];
    A1[t][o] = s;
  }
  __syncthreads();
  float* xbar = &Sc[0][0][0];
  if (tid < 128) {
    float s = 0.f;
    for (int t=0;t<24;++t) s += fcw[t]*A1[t][tid];
    xbar[tid] = s;
  }
  __syncthreads();
  if (tid < 128) {
    int o = tid;
    float s = 0.f;
    for (int c=0;c<128;++c) s += xbar[c]*ow[o*128 + c];
    float sfc = 0.f;
    for (int t=0;t<24;++t) sfc += fcw[t];
    out2f[(size_t)bn*128 + o] = s + sfc*ob[o] + fcb[0];
  }
}

__global__ void k_rbar_bf(const ushort_t* out2, const float* rw, float* rbar) {
  int i = blockIdx.x*256 + threadIdx.x;
  if (i >= 512000) return;
  int c = i & 127; int bnn = i >> 7; int b = bnn/500, n = bnn - b*500;
  float s = 0.f;
  #pragma unroll
  for (int t=0;t<24;++t) s += rw[t] * b2f(out2[((size_t)(b*24 + t)*500 + n)*128 + c]);
  rbar[i] = s;
}

__global__ void k_te(const float* tt, const float* w1, const float* b1,
                     const float* w2, const float* b2, float* te) {
  __shared__ float h1[128];
  int b = blockIdx.x; int o = threadIdx.x;
  float s = b1[o];
  for (int c=0;c<32;++c) s += tt[b*32 + c]*w1[o*32 + c];
  h1[o] = fmaxf(s, 0.f);
  __syncthreads();
  float s2 = b2[o];
  for (int c=0;c<128;++c) s2 += h1[c]*w2[o*128 + c];
  te[b*128 + o] = s2;
}

__global__ void k_grid(const float* gnm, const float* fin, float* out) {
  int e = threadIdx.x & 63; int gq = threadIdx.x >> 6;
  int g = blockIdx.x*4 + gq; int b = blockIdx.y;
  float s = 0.f;
  const float* gr = gnm + (size_t)g*500;
  const float* fb = fin + (size_t)b*500*64 + e;
  for (int n=0;n<500;++n) s += gr[n] * fb[(size_t)n*64];
  out[(size_t)b*32000 + (size_t)e*500 + g] = s;
}

// ---------------- launch ----------------
extern "C" void kernel_launch(void* const* d_in, const int* in_sizes, int n_in,
                              void* d_out, int out_size, void* d_ws, size_t ws_size,
                              hipStream_t stream) {
  const float* adj   = (const float*)d_in[0];
  const float* x     = (const float*)d_in[1];
  const float* gnm   = (const float*)d_in[2];
  const float* ttime = (const float*)d_in[3];
  const float* emb   = (const float*)d_in[4];
  const float* wp0   = (const float*)d_in[5];
  const float* bp0   = (const float*)d_in[6];
  const float* a0f1w = (const float*)d_in[7];
  const float* a0f1b = (const float*)d_in[8];
  const float* a0f2w = (const float*)d_in[9];
  const float* a0f2b = (const float*)d_in[10];
  const float* wp1   = (const float*)d_in[11];
  const float* bp1   = (const float*)d_in[12];
  const float* a1f1w = (const float*)d_in[13];
  const float* a1f1b = (const float*)d_in[14];
  const float* a1f2w = (const float*)d_in[15];
  const float* a1f2b = (const float*)d_in[16];
  const float* bn0g  = (const float*)d_in[17];
  const float* bn0b  = (const float*)d_in[18];
  const float* bn1g  = (const float*)d_in[19];
  const float* bn1b  = (const float*)d_in[20];
  const float* wih   = (const float*)d_in[21];
  const float* whh   = (const float*)d_in[22];
  const float* bih   = (const float*)d_in[23];
  const float* bhh   = (const float*)d_in[24];
  const float* bgg   = (const float*)d_in[25];
  const float* bgb   = (const float*)d_in[26];
  const float* cqw   = (const float*)d_in[27];
  const float* cqb   = (const float*)d_in[28];
  const float* ckw   = (const float*)d_in[29];
  const float* ckb   = (const float*)d_in[30];
  const float* vw    = (const float*)d_in[31];
  const float* vb    = (const float*)d_in[32];
  const float* ow    = (const float*)d_in[33];
  const float* ob    = (const float*)d_in[34];
  const float* r1w   = (const float*)d_in[35];
  const float* r1b   = (const float*)d_in[36];
  const float* fcw   = (const float*)d_in[37];
  const float* fcb   = (const float*)d_in[38];
  const float* rcw   = (const float*)d_in[39];
  const float* rcb   = (const float*)d_in[40];
  const float* r2w   = (const float*)d_in[41];
  const float* r2b   = (const float*)d_in[42];
  const float* bnrg  = (const float*)d_in[43];
  const float* bnrb  = (const float*)d_in[44];
  const float* te1w  = (const float*)d_in[45];
  const float* te1b  = (const float*)d_in[46];
  const float* te2w  = (const float*)d_in[47];
  const float* te2b  = (const float*)d_in[48];
  const float* finw  = (const float*)d_in[49];
  const float* finb  = (const float*)d_in[50];
  float* dout = (float*)d_out;
  float* W = (float*)d_ws;

  size_t off = 0;
  auto alloc = [&](size_t n){ size_t r = off; off += (n + 255) & ~(size_t)255; return r; };
  size_t oStats = alloc(512);
  size_t oPool  = alloc(24576);
  size_t oAmix  = alloc(1536);
  size_t oTe    = alloc(1024);
  size_t oO2f   = alloc(512000);
  size_t oRbar  = alloc(512000);
  size_t oRes   = alloc(512000);
  size_t oFin   = alloc(256000);
  size_t oNe0   = alloc(768000);
  size_t oNe1   = alloc(768000);
  size_t oS2    = alloc(125000);     // bf16 [500][500]
  size_t oWp0p  = alloc(98304);      // bf16 [128][1536]
  size_t oWp1p  = alloc(196608);     // bf16 [128][3072]
  size_t oR1wp  = alloc(4096);       // bf16 [128][64]
  size_t oWihp  = alloc(24576);      // bf16 [384][128]
  size_t oQkvw  = alloc(73728);      // bf16 [384][384]
  size_t oQkvb  = alloc(384);
  size_t oR2wp  = alloc(8192);
  size_t oFinwp = alloc(4096);
  size_t oR1    = alloc(12288000);   // out0 -> out2b -> hs
  size_t oR2    = alloc(12288000);   // XG/XGB pairs -> gi(low) -> QKV(low)
  size_t oR4    = alloc(6144000);    // Xn -> Y0bf -> gi(high) -> QKV(high)
  size_t oOut1  = alloc(6144000);    // YT -> out1 -> hsbf
  (void)n_in; (void)in_sizes; (void)out_size;
  if (ws_size < off * sizeof(float)) return;

  float* stats = W + oStats;
  float* pooled= W + oPool;
  float* amix  = W + oAmix;
  float* teb   = W + oTe;
  float* out2f = W + oO2f;
  float* rbar  = W + oRbar;
  float* resout= W + oRes;
  float* fin   = W + oFin;
  float* ne0   = W + oNe0;
  float* ne1   = W + oNe1;
  ushort_t* S2bf  = (ushort_t*)(W + oS2);
  ushort_t* wp0p  = (ushort_t*)(W + oWp0p);
  ushort_t* wp1p  = (ushort_t*)(W + oWp1p);
  ushort_t* r1wp  = (ushort_t*)(W + oR1wp);
  ushort_t* wihp  = (ushort_t*)(W + oWihp);
  ushort_t* qkvwp = (ushort_t*)(W + oQkvw);
  float*    qkvb  = W + oQkvb;
  ushort_t* r2wp  = (ushort_t*)(W + oR2wp);
  ushort_t* finwp = (ushort_t*)(W + oFinwp);
  float* out0  = W + oR1;
  ushort_t* out2b = (ushort_t*)(W + oR1);
  float* hs    = W + oR1;
  ushort_t* XG1n = (ushort_t*)(W + oR2);     // [500][12288]; XG2n contiguous after
  ushort_t* XGB1 = (ushort_t*)(W + oR2);     // [500][24576]; XGB2 contiguous after
  ushort_t* gi16 = (ushort_t*)(W + oR2);     // [96000][384] spans R2+R4
  ushort_t* qkv16= (ushort_t*)(W + oR2);     // [96000][384] same span (gi dead)
  ushort_t* Xnbf = (ushort_t*)(W + oR4);
  ushort_t* Y0bf = (ushort_t*)(W + oR4);
  ushort_t* YT   = (ushort_t*)(W + oOut1);
  ushort_t* out1 = (ushort_t*)(W + oOut1);
  ushort_t* hsbf = (ushort_t*)(W + oOut1);   // after out1 dead

  // ---- weight packing ----
  k_pack_wp<<<768, 256, 0, stream>>>(wp0, wp0p, 64, 1536);
  k_pack_wp<<<1536, 256, 0, stream>>>(wp1, wp1p, 128, 3072);
  k_pack_bf<<<32, 256, 0, stream>>>(r1w, r1wp, 8192);
  k_pack_bf<<<192, 256, 0, stream>>>(wih, wihp, 49152);
  k_pack_bf<<<64, 256, 0, stream>>>(r2w, r2wp, 16384);
  k_pack_bf<<<32, 256, 0, stream>>>(finw, finwp, 8192);
  k_pack_qkvw<<<576, 256, 0, stream>>>(cqw, ckw, vw, qkvwp);
  k_pack_qkvb<<<1, 384, 0, stream>>>(cqb, ckb, vb, qkvb);

  // ---- Phase A ----
  k_transpose_bf<<<dim3(16,384), dim3(32,8), 0, stream>>>(x, Xnbf, 12288, 500);
  gemm_mfma<true><<<dim3(4,4), 256, 0, stream>>>(
      AgF32{adj,500}, BgAdjB{adj}, EpS2{}, (void*)S2bf, 500, 500, 500, 500);
  gemm_mfma<true><<<dim3(96,8), 256, 0, stream>>>(
      AgStackA{adj, S2bf}, BgXTv{x}, EpNone{}, (void*)XG1n, 1000, 12288, 500, 12288);
  k_pool0<<<192, 64, 0, stream>>>(x, pooled);
  k_mlp<<<1, 192, 0, stream>>>(pooled, 64, a0f1w, a0f1b, a0f2w, a0f2b, amix);
  k_ne<<<3000, 256, 0, stream>>>(amix, emb, ne0);
  gemm_mfma<false><<<dim3(1,750), 256, 0, stream>>>(
      AgFlex0v{Xnbf, XG1n, XG1n + 6144000, ne0}, BgPk{wp0p,1536}, EpNeBias{ne0, bp0},
      (void*)out0, 96000, 128, 1536, 128);
  hipMemsetAsync((void*)stats, 0, 256*sizeof(float), stream);
  k_bn_stats<<<768, 256, 0, stream>>>(out0, stats, 96000, 125);
  k_bn_apply4<<<12000, 256, 0, stream>>>(out0, out0, stats, bn0g, bn0b, 3072000, 1.f/96000.f, 1, 0);

  // ---- Phase B ----
  k_pool1<<<192, 128, 0, stream>>>(out0, pooled);
  k_mlp<<<1, 192, 0, stream>>>(pooled, 128, a1f1w, a1f1b, a1f2w, a1f2b, amix);
  k_ne<<<3000, 256, 0, stream>>>(amix, emb, ne1);
  k_copyY4<<<12000, 256, 0, stream>>>(out0, Y0bf);
  k_copyYT_bf<<<dim3(16,4,192), dim3(32,8), 0, stream>>>(out0, YT);
  gemm_mfma<true><<<dim3(192,8), 256, 0, stream>>>(
      AgStackA{adj, S2bf}, BgPk{YT,500}, EpNone{}, (void*)XGB1, 1000, 24576, 500, 24576);
  gemm_mfma<true><<<dim3(1,750), 256, 0, stream>>>(
      AgFlex1v{Y0bf, XGB1, XGB1 + 12288000, ne1}, BgPk{wp1p,3072}, EpNeBias{ne1, bp1},
      (void*)out1, 96000, 128, 3072, 128);
  hipMemsetAsync((void*)stats, 0, 256*sizeof(float), stream);
  k_bn_stats_bf<<<768, 256, 0, stream>>>(out1, stats, 96000, 125);
  gemm_mfma<true><<<dim3(1,750), 256, 0, stream>>>(
      AgXrow{x}, BgPk{r1wp,64}, EpRes1{out1, stats, bn1g, bn1b, r1b, 1.f/96000.f},
      (void*)out2b, 96000, 128, 64, 128);

  // ---- Phase E-part1 (consumes out2b early) ----
  k_rbar_bf<<<2000, 256, 0, stream>>>(out2b, rcw, rbar);
  gemm_mfma<false><<<dim3(1,32), 256, 0, stream>>>(
      AgF32{rbar,128}, BgPk{r2wp,128}, EpRes2{r2b, rcw, rcb}, (void*)resout, 4000, 128, 128, 128);
  hipMemsetAsync((void*)stats, 0, 256*sizeof(float), stream);
  k_bn_stats<<<32, 256, 0, stream>>>(resout, stats, 4000, 125);

  // ---- Phase C: gi on MFMA + recurrent GRU ----
  gemm_mfma<true><<<dim3(3,750), 256, 0, stream>>>(
      AgBf16p{out2b,128}, BgPk{wihp,128}, EpBias{bih}, (void*)gi16, 96000, 384, 128, 384);
  k_gru3<<<500, 384, 0, stream>>>(gi16, whh, bhh, hs);
  hipMemsetAsync((void*)(stats+256), 0, 256*sizeof(float), stream);
  k_bn_stats<<<768, 256, 0, stream>>>(hs, stats+256, 96000, 125);
  k_bn_apply_bf<<<12000, 256, 0, stream>>>(hsbf, hs, stats+256, bgg, bgb, 3072000, 1.f/96000.f);

  // ---- Phase D: one QKV GEMM + attention ----
  gemm_mfma<true><<<dim3(3,750), 256, 0, stream>>>(
      AgConvB{hsbf}, BgPk{qkvwp,384}, EpBias{qkvb}, (void*)qkv16, 96000, 384, 384, 384);
  k_attn3<<<4000, 256, 0, stream>>>(qkv16, ow, ob, fcw, fcb, out2f);

  // ---- Phase E-part2 ----
  k_bn_apply4<<<500, 256, 0, stream>>>(out2f, resout, stats, bnrg, bnrb, 128000, 1.f/4000.f, 0, 1);
  k_te<<<8, 128, 0, stream>>>(ttime, te1w, te1b, te2w, te2b, teb);
  gemm_mfma<false><<<dim3(1,32), 256, 0, stream>>>(
      AgTeAdd{out2f, teb}, BgPk{finwp,128}, EpBias{finb}, (void*)fin, 4000, 64, 128, 64);
  k_grid<<<dim3(125,8), 256, 0, stream>>>(gnm, fin, dout);
}